// Round 1
// baseline (8341.906 us; speedup 1.0000x reference)
//
#include <hip/hip_runtime.h>
#include <hip/hip_bf16.h>

// ---------------------------------------------------------------------------
// Transformer decoder layer, fp32 correctness-first baseline.
// B=4, L=1024, D=1024, H=16, depth=64, DFF=4096. M = B*L = 4096 rows.
// ---------------------------------------------------------------------------

#define BM 64
#define BN 64
#define BK 16

// C[M,N] = A[M,K] @ W[K,N] + bias[N] (+ res[M,N]) (+ relu)
template<int RELU>
__global__ __launch_bounds__(256) void gemm_kernel(
        const float* __restrict__ A, const float* __restrict__ W,
        const float* __restrict__ bias, const float* __restrict__ res,
        float* __restrict__ C, int M, int N, int K)
{
    __shared__ float As[BK][BM + 1];
    __shared__ float Ws[BK][BN + 1];

    const int tid = threadIdx.x;           // 0..255
    const int tx  = tid & 15;              // 0..15 -> 4 cols each
    const int ty  = tid >> 4;              // 0..15 -> 4 rows each
    const int bx  = blockIdx.x;            // N tiles
    const int by  = blockIdx.y;            // M tiles

    const int arow = tid >> 2;             // 0..63
    const int ak   = (tid & 3) * 4;        // 0,4,8,12
    const int wk   = tid >> 4;             // 0..15
    const int wc   = (tid & 15) * 4;       // 0..60

    const float* Aptr = A + (size_t)(by * BM + arow) * K + ak;
    const float* Wptr = W + (size_t)wk * N + (size_t)bx * BN + wc;

    float acc[4][4] = {};

    for (int kt = 0; kt < K; kt += BK) {
        float4 av = *(const float4*)(Aptr + kt);
        float4 wv = *(const float4*)(Wptr + (size_t)kt * N);

        As[ak + 0][arow] = av.x;
        As[ak + 1][arow] = av.y;
        As[ak + 2][arow] = av.z;
        As[ak + 3][arow] = av.w;
        Ws[wk][wc + 0] = wv.x;
        Ws[wk][wc + 1] = wv.y;
        Ws[wk][wc + 2] = wv.z;
        Ws[wk][wc + 3] = wv.w;
        __syncthreads();

        #pragma unroll
        for (int kk = 0; kk < BK; ++kk) {
            float a0 = As[kk][ty * 4 + 0];
            float a1 = As[kk][ty * 4 + 1];
            float a2 = As[kk][ty * 4 + 2];
            float a3 = As[kk][ty * 4 + 3];
            float b0 = Ws[kk][tx * 4 + 0];
            float b1 = Ws[kk][tx * 4 + 1];
            float b2 = Ws[kk][tx * 4 + 2];
            float b3 = Ws[kk][tx * 4 + 3];
            acc[0][0] += a0 * b0; acc[0][1] += a0 * b1; acc[0][2] += a0 * b2; acc[0][3] += a0 * b3;
            acc[1][0] += a1 * b0; acc[1][1] += a1 * b1; acc[1][2] += a1 * b2; acc[1][3] += a1 * b3;
            acc[2][0] += a2 * b0; acc[2][1] += a2 * b1; acc[2][2] += a2 * b2; acc[2][3] += a2 * b3;
            acc[3][0] += a3 * b0; acc[3][1] += a3 * b1; acc[3][2] += a3 * b2; acc[3][3] += a3 * b3;
        }
        __syncthreads();
    }

    const int row0 = by * BM + ty * 4;
    const int col0 = bx * BN + tx * 4;
    #pragma unroll
    for (int i = 0; i < 4; ++i) {
        float4 o;
        o.x = acc[i][0] + bias[col0 + 0];
        o.y = acc[i][1] + bias[col0 + 1];
        o.z = acc[i][2] + bias[col0 + 2];
        o.w = acc[i][3] + bias[col0 + 3];
        if (res) {
            const float4 r = *(const float4*)(res + (size_t)(row0 + i) * N + col0);
            o.x += r.x; o.y += r.y; o.z += r.z; o.w += r.w;
        }
        if (RELU) {
            o.x = fmaxf(o.x, 0.f); o.y = fmaxf(o.y, 0.f);
            o.z = fmaxf(o.z, 0.f); o.w = fmaxf(o.w, 0.f);
        }
        *(float4*)(C + (size_t)(row0 + i) * N + col0) = o;
    }
}

// ---------------------------------------------------------------------------
// Attention: Q,K,V are [B*L, 1024] with head h in cols [h*64, h*64+64).
// One wave per q-row; 4 waves (4 q-rows) per block. Grid: (B*H, L/4).
// ---------------------------------------------------------------------------
template<int CAUSAL>
__global__ __launch_bounds__(256) void attn_kernel(
        const float* __restrict__ Q, const float* __restrict__ Km,
        const float* __restrict__ V, float* __restrict__ O)
{
    __shared__ float sc[4][1024];
    __shared__ float qs[4][64];

    const int lane = threadIdx.x & 63;
    const int wave = threadIdx.x >> 6;
    const int bh = blockIdx.x;             // 0..63
    const int b = bh >> 4, h = bh & 15;
    const int q = blockIdx.y * 4 + wave;   // 0..1023

    const size_t headoff = (size_t)b * 1024 * 1024 + (size_t)h * 64;
    const float* Qh = Q + headoff;
    const float* Kh = Km + headoff;
    const float* Vh = V + headoff;

    qs[wave][lane] = Qh[(size_t)q * 1024 + lane] * 0.125f;  // 1/sqrt(64)
    __syncthreads();

    // Pass 1: scores
    for (int kc = 0; kc < 16; ++kc) {
        const int k = kc * 64 + lane;
        const float* Kr = Kh + (size_t)k * 1024;
        float s = 0.f;
        #pragma unroll
        for (int d = 0; d < 64; ++d) s += qs[wave][d] * Kr[d];
        if (CAUSAL && k > q) s = -1e9f;
        sc[wave][k] = s;
    }
    __syncthreads();

    // Softmax over 1024 scores (wave-parallel)
    float m = -3.4e38f;
    #pragma unroll
    for (int i = 0; i < 16; ++i) m = fmaxf(m, sc[wave][i * 64 + lane]);
    #pragma unroll
    for (int off = 32; off; off >>= 1) m = fmaxf(m, __shfl_xor(m, off));

    float sum = 0.f;
    #pragma unroll
    for (int i = 0; i < 16; ++i) {
        const float e = __expf(sc[wave][i * 64 + lane] - m);
        sc[wave][i * 64 + lane] = e;
        sum += e;
    }
    #pragma unroll
    for (int off = 32; off; off >>= 1) sum += __shfl_xor(sum, off);
    const float inv = 1.f / sum;
    __syncthreads();

    // Pass 2: O = P @ V   (lane == d, coalesced V reads)
    float o = 0.f;
    #pragma unroll 8
    for (int k = 0; k < 1024; ++k) o += sc[wave][k] * Vh[(size_t)k * 1024 + lane];
    O[headoff + (size_t)q * 1024 + lane] = o * inv;
}

// ---------------------------------------------------------------------------
// LayerNorm over last dim (1024). One block per row. Supports Y == X.
// ---------------------------------------------------------------------------
__global__ __launch_bounds__(256) void ln_kernel(
        const float* X, const float* __restrict__ g,
        const float* __restrict__ bta, float* Y)
{
    __shared__ float red[4];
    const int row = blockIdx.x;
    const int tid = threadIdx.x;
    const int wave = tid >> 6, lane = tid & 63;

    const float4 v = ((const float4*)(X + (size_t)row * 1024))[tid];

    float s = v.x + v.y + v.z + v.w;
    #pragma unroll
    for (int off = 32; off; off >>= 1) s += __shfl_xor(s, off);
    if (lane == 0) red[wave] = s;
    __syncthreads();
    const float mu = (red[0] + red[1] + red[2] + red[3]) * (1.f / 1024.f);
    __syncthreads();

    const float dx = v.x - mu, dy = v.y - mu, dz = v.z - mu, dw = v.w - mu;
    float s2 = dx * dx + dy * dy + dz * dz + dw * dw;
    #pragma unroll
    for (int off = 32; off; off >>= 1) s2 += __shfl_xor(s2, off);
    if (lane == 0) red[wave] = s2;
    __syncthreads();
    const float var = (red[0] + red[1] + red[2] + red[3]) * (1.f / 1024.f);
    const float rs = rsqrtf(var + 1e-5f);

    const float4 gg = ((const float4*)g)[tid];
    const float4 bb = ((const float4*)bta)[tid];
    float4 o;
    o.x = dx * rs * gg.x + bb.x;
    o.y = dy * rs * gg.y + bb.y;
    o.z = dz * rs * gg.z + bb.z;
    o.w = dw * rs * gg.w + bb.w;
    ((float4*)(Y + (size_t)row * 1024))[tid] = o;
}

// ---------------------------------------------------------------------------
extern "C" void kernel_launch(void* const* d_in, const int* in_sizes, int n_in,
                              void* d_out, int out_size, void* d_ws, size_t ws_size,
                              hipStream_t stream)
{
    const float* tgt    = (const float*)d_in[0];
    const float* mem    = (const float*)d_in[1];
    // d_in[2] = tgt_mask (always tril; causal hardcoded)
    const float* sa_wq  = (const float*)d_in[3];
    const float* sa_bq  = (const float*)d_in[4];
    const float* sa_wk  = (const float*)d_in[5];
    const float* sa_bk  = (const float*)d_in[6];
    const float* sa_wv  = (const float*)d_in[7];
    const float* sa_bv  = (const float*)d_in[8];
    const float* sa_wo  = (const float*)d_in[9];
    const float* sa_bo  = (const float*)d_in[10];
    const float* ca_wq  = (const float*)d_in[11];
    const float* ca_bq  = (const float*)d_in[12];
    const float* ca_wk  = (const float*)d_in[13];
    const float* ca_bk  = (const float*)d_in[14];
    const float* ca_wv  = (const float*)d_in[15];
    const float* ca_bv  = (const float*)d_in[16];
    const float* ca_wo  = (const float*)d_in[17];
    const float* ca_bo  = (const float*)d_in[18];
    const float* ffn_w1 = (const float*)d_in[19];
    const float* ffn_b1 = (const float*)d_in[20];
    const float* ffn_w2 = (const float*)d_in[21];
    const float* ffn_b2 = (const float*)d_in[22];
    const float* ln1_g  = (const float*)d_in[23];
    const float* ln1_b  = (const float*)d_in[24];
    const float* ln2_g  = (const float*)d_in[25];
    const float* ln2_b  = (const float*)d_in[26];
    const float* ln3_g  = (const float*)d_in[27];
    const float* ln3_b  = (const float*)d_in[28];

    float* out = (float*)d_out;
    float* ws  = (float*)d_ws;
    const size_t S = (size_t)4096 * 1024;
    float* s0 = ws;
    float* s1 = ws + S;
    float* s2 = ws + 2 * S;
    float* s3 = ws + 3 * S;
    float* s4 = ws + 4 * S;

    const dim3 blk(256);
    const dim3 g1024(1024 / BN, 4096 / BM);   // N=1024 GEMMs
    const dim3 g4096(4096 / BN, 4096 / BM);   // FFN1
    const dim3 ga(64, 256);                   // attention
    const dim3 gln(4096);

    // ---- self-attention ----
    gemm_kernel<0><<<g1024, blk, 0, stream>>>(tgt, sa_wq, sa_bq, nullptr, s0, 4096, 1024, 1024);
    gemm_kernel<0><<<g1024, blk, 0, stream>>>(tgt, sa_wk, sa_bk, nullptr, s1, 4096, 1024, 1024);
    gemm_kernel<0><<<g1024, blk, 0, stream>>>(tgt, sa_wv, sa_bv, nullptr, s2, 4096, 1024, 1024);
    attn_kernel<1><<<ga, blk, 0, stream>>>(s0, s1, s2, s3);
    gemm_kernel<0><<<g1024, blk, 0, stream>>>(s3, sa_wo, sa_bo, tgt, s0, 4096, 1024, 1024);
    ln_kernel<<<gln, blk, 0, stream>>>(s0, ln1_g, ln1_b, s1);          // x1 = s1

    // ---- cross-attention ----
    gemm_kernel<0><<<g1024, blk, 0, stream>>>(s1, ca_wq, ca_bq, nullptr, s0, 4096, 1024, 1024);
    gemm_kernel<0><<<g1024, blk, 0, stream>>>(mem, ca_wk, ca_bk, nullptr, s2, 4096, 1024, 1024);
    gemm_kernel<0><<<g1024, blk, 0, stream>>>(mem, ca_wv, ca_bv, nullptr, s3, 4096, 1024, 1024);
    attn_kernel<0><<<ga, blk, 0, stream>>>(s0, s2, s3, s4);
    gemm_kernel<0><<<g1024, blk, 0, stream>>>(s4, ca_wo, ca_bo, s1, s0, 4096, 1024, 1024);
    ln_kernel<<<gln, blk, 0, stream>>>(s0, ln2_g, ln2_b, s4);          // x2 = s4

    // ---- FFN ----  hidden = relu(x2 @ w1 + b1) in s0..s3 (contiguous 4S)
    gemm_kernel<1><<<g4096, blk, 0, stream>>>(s4, ffn_w1, ffn_b1, nullptr, s0, 4096, 4096, 1024);
    gemm_kernel<0><<<g1024, blk, 0, stream>>>(s0, ffn_w2, ffn_b2, s4, out, 4096, 1024, 4096);
    ln_kernel<<<gln, blk, 0, stream>>>(out, ln3_g, ln3_b, out);        // in-place final LN
}

// Round 2
// 3361.480 us; speedup vs baseline: 2.4816x; 2.4816x over previous
//
#include <hip/hip_runtime.h>
#include <hip/hip_bf16.h>

// ---------------------------------------------------------------------------
// Transformer decoder layer. fp32, flash-attention tiled. B=4, L=1024,
// D=1024, H=16, depth=64, DFF=4096. M = B*L = 4096 rows.
// ---------------------------------------------------------------------------

#define BM 64
#define BN 64
#define BK 16

// C[M,N] = A[M,K] @ W[K,N] + bias[N] (+ res[M,N]) (+ relu)
template<int RELU>
__global__ __launch_bounds__(256) void gemm_kernel(
        const float* __restrict__ A, const float* __restrict__ W,
        const float* __restrict__ bias, const float* __restrict__ res,
        float* __restrict__ C, int M, int N, int K)
{
    __shared__ float As[BK][BM + 1];
    __shared__ float Ws[BK][BN + 1];

    const int tid = threadIdx.x;           // 0..255
    const int tx  = tid & 15;              // 0..15 -> 4 cols each
    const int ty  = tid >> 4;              // 0..15 -> 4 rows each
    const int bx  = blockIdx.x;            // N tiles
    const int by  = blockIdx.y;            // M tiles

    const int arow = tid >> 2;             // 0..63
    const int ak   = (tid & 3) * 4;        // 0,4,8,12
    const int wk   = tid >> 4;             // 0..15
    const int wc   = (tid & 15) * 4;       // 0..60

    const float* Aptr = A + (size_t)(by * BM + arow) * K + ak;
    const float* Wptr = W + (size_t)wk * N + (size_t)bx * BN + wc;

    float acc[4][4] = {};

    for (int kt = 0; kt < K; kt += BK) {
        float4 av = *(const float4*)(Aptr + kt);
        float4 wv = *(const float4*)(Wptr + (size_t)kt * N);

        As[ak + 0][arow] = av.x;
        As[ak + 1][arow] = av.y;
        As[ak + 2][arow] = av.z;
        As[ak + 3][arow] = av.w;
        Ws[wk][wc + 0] = wv.x;
        Ws[wk][wc + 1] = wv.y;
        Ws[wk][wc + 2] = wv.z;
        Ws[wk][wc + 3] = wv.w;
        __syncthreads();

        #pragma unroll
        for (int kk = 0; kk < BK; ++kk) {
            float a0 = As[kk][ty * 4 + 0];
            float a1 = As[kk][ty * 4 + 1];
            float a2 = As[kk][ty * 4 + 2];
            float a3 = As[kk][ty * 4 + 3];
            float b0 = Ws[kk][tx * 4 + 0];
            float b1 = Ws[kk][tx * 4 + 1];
            float b2 = Ws[kk][tx * 4 + 2];
            float b3 = Ws[kk][tx * 4 + 3];
            acc[0][0] += a0 * b0; acc[0][1] += a0 * b1; acc[0][2] += a0 * b2; acc[0][3] += a0 * b3;
            acc[1][0] += a1 * b0; acc[1][1] += a1 * b1; acc[1][2] += a1 * b2; acc[1][3] += a1 * b3;
            acc[2][0] += a2 * b0; acc[2][1] += a2 * b1; acc[2][2] += a2 * b2; acc[2][3] += a2 * b3;
            acc[3][0] += a3 * b0; acc[3][1] += a3 * b1; acc[3][2] += a3 * b2; acc[3][3] += a3 * b3;
        }
        __syncthreads();
    }

    const int row0 = by * BM + ty * 4;
    const int col0 = bx * BN + tx * 4;
    #pragma unroll
    for (int i = 0; i < 4; ++i) {
        float4 o;
        o.x = acc[i][0] + bias[col0 + 0];
        o.y = acc[i][1] + bias[col0 + 1];
        o.z = acc[i][2] + bias[col0 + 2];
        o.w = acc[i][3] + bias[col0 + 3];
        if (res) {
            const float4 r = *(const float4*)(res + (size_t)(row0 + i) * N + col0);
            o.x += r.x; o.y += r.y; o.z += r.z; o.w += r.w;
        }
        if (RELU) {
            o.x = fmaxf(o.x, 0.f); o.y = fmaxf(o.y, 0.f);
            o.z = fmaxf(o.z, 0.f); o.w = fmaxf(o.w, 0.f);
        }
        *(float4*)(C + (size_t)(row0 + i) * N + col0) = o;
    }
}

// ---------------------------------------------------------------------------
// Flash attention. Q,K,V are [B*L, 1024], head h in cols [h*64, h*64+64).
// Block = 256 threads = one (b,h) x 64 q-rows. Grid: (64, 16).
// K-tiles of 64 streamed through LDS; online softmax; P reuses Ks storage.
// Thread (ty,tx): q-rows ty*4..+4, k-cols / d-cols tx*4..+4.
// ---------------------------------------------------------------------------
template<int CAUSAL>
__global__ __launch_bounds__(256) void fattn_kernel(
        const float* __restrict__ Q, const float* __restrict__ Km,
        const float* __restrict__ V, float* __restrict__ O)
{
    __shared__ float Qs[64][65];
    __shared__ float Ks[64][65];   // holds K-tile, then reused to hold P
    __shared__ float Vs[64][65];

    const int tid = threadIdx.x;
    const int tx = tid & 15;
    const int ty = tid >> 4;
    const int b = blockIdx.x >> 4, h = blockIdx.x & 15;
    const int qt = blockIdx.y;
    const int q0 = qt * 64;

    const size_t base = (size_t)b * (1024 * 1024) + (size_t)h * 64;

    // load Q tile, pre-scaled by 1/sqrt(64)
    {
        const int r = tid >> 2, c0 = (tid & 3) * 16;
        const float* src = Q + base + (size_t)(q0 + r) * 1024 + c0;
        #pragma unroll
        for (int j = 0; j < 16; j += 4) {
            const float4 v = *(const float4*)(src + j);
            Qs[r][c0 + j + 0] = v.x * 0.125f;
            Qs[r][c0 + j + 1] = v.y * 0.125f;
            Qs[r][c0 + j + 2] = v.z * 0.125f;
            Qs[r][c0 + j + 3] = v.w * 0.125f;
        }
    }

    float m_i[4] = {-1e30f, -1e30f, -1e30f, -1e30f};
    float l_i[4] = {0.f, 0.f, 0.f, 0.f};
    float o_acc[4][4] = {};

    const int ktmax = CAUSAL ? qt : 15;
    for (int kt = 0; kt <= ktmax; ++kt) {
        __syncthreads();   // prev PV done (and Q load visible on first iter)
        {
            const int r = tid >> 2, c0 = (tid & 3) * 16;
            const float* ksrc = Km + base + (size_t)(kt * 64 + r) * 1024 + c0;
            const float* vsrc = V  + base + (size_t)(kt * 64 + r) * 1024 + c0;
            #pragma unroll
            for (int j = 0; j < 16; j += 4) {
                const float4 kv = *(const float4*)(ksrc + j);
                Ks[r][c0 + j + 0] = kv.x;
                Ks[r][c0 + j + 1] = kv.y;
                Ks[r][c0 + j + 2] = kv.z;
                Ks[r][c0 + j + 3] = kv.w;
                const float4 vv = *(const float4*)(vsrc + j);
                Vs[r][c0 + j + 0] = vv.x;
                Vs[r][c0 + j + 1] = vv.y;
                Vs[r][c0 + j + 2] = vv.z;
                Vs[r][c0 + j + 3] = vv.w;
            }
        }
        __syncthreads();

        // S = Q @ K^T  (4x4 micro-tile per thread)
        float s[4][4] = {};
        #pragma unroll 8
        for (int d = 0; d < 64; ++d) {
            const float a0 = Qs[ty * 4 + 0][d];
            const float a1 = Qs[ty * 4 + 1][d];
            const float a2 = Qs[ty * 4 + 2][d];
            const float a3 = Qs[ty * 4 + 3][d];
            const float b0 = Ks[tx * 4 + 0][d];
            const float b1 = Ks[tx * 4 + 1][d];
            const float b2 = Ks[tx * 4 + 2][d];
            const float b3 = Ks[tx * 4 + 3][d];
            s[0][0] += a0 * b0; s[0][1] += a0 * b1; s[0][2] += a0 * b2; s[0][3] += a0 * b3;
            s[1][0] += a1 * b0; s[1][1] += a1 * b1; s[1][2] += a1 * b2; s[1][3] += a1 * b3;
            s[2][0] += a2 * b0; s[2][1] += a2 * b1; s[2][2] += a2 * b2; s[2][3] += a2 * b3;
            s[3][0] += a3 * b0; s[3][1] += a3 * b1; s[3][2] += a3 * b2; s[3][3] += a3 * b3;
        }

        if (CAUSAL && kt == qt) {
            #pragma unroll
            for (int i = 0; i < 4; ++i)
                #pragma unroll
                for (int j = 0; j < 4; ++j)
                    if (tx * 4 + j > ty * 4 + i) s[i][j] = -1e9f;
        }

        // online softmax (rows shared by the 16 lanes with equal ty)
        #pragma unroll
        for (int i = 0; i < 4; ++i) {
            float tmax = fmaxf(fmaxf(s[i][0], s[i][1]), fmaxf(s[i][2], s[i][3]));
            tmax = fmaxf(tmax, __shfl_xor(tmax, 1));
            tmax = fmaxf(tmax, __shfl_xor(tmax, 2));
            tmax = fmaxf(tmax, __shfl_xor(tmax, 4));
            tmax = fmaxf(tmax, __shfl_xor(tmax, 8));
            const float mn = fmaxf(m_i[i], tmax);
            const float alpha = __expf(m_i[i] - mn);
            m_i[i] = mn;
            float rs = 0.f;
            #pragma unroll
            for (int j = 0; j < 4; ++j) { s[i][j] = __expf(s[i][j] - mn); rs += s[i][j]; }
            rs += __shfl_xor(rs, 1);
            rs += __shfl_xor(rs, 2);
            rs += __shfl_xor(rs, 4);
            rs += __shfl_xor(rs, 8);
            l_i[i] = l_i[i] * alpha + rs;
            o_acc[i][0] *= alpha; o_acc[i][1] *= alpha;
            o_acc[i][2] *= alpha; o_acc[i][3] *= alpha;
        }

        __syncthreads();   // all S-reads of Ks complete
        #pragma unroll
        for (int i = 0; i < 4; ++i)
            #pragma unroll
            for (int j = 0; j < 4; ++j)
                Ks[ty * 4 + i][tx * 4 + j] = s[i][j];
        __syncthreads();

        // O += P @ V
        #pragma unroll 8
        for (int kk = 0; kk < 64; ++kk) {
            const float p0 = Ks[ty * 4 + 0][kk];
            const float p1 = Ks[ty * 4 + 1][kk];
            const float p2 = Ks[ty * 4 + 2][kk];
            const float p3 = Ks[ty * 4 + 3][kk];
            const float v0 = Vs[kk][tx * 4 + 0];
            const float v1 = Vs[kk][tx * 4 + 1];
            const float v2 = Vs[kk][tx * 4 + 2];
            const float v3 = Vs[kk][tx * 4 + 3];
            o_acc[0][0] += p0 * v0; o_acc[0][1] += p0 * v1; o_acc[0][2] += p0 * v2; o_acc[0][3] += p0 * v3;
            o_acc[1][0] += p1 * v0; o_acc[1][1] += p1 * v1; o_acc[1][2] += p1 * v2; o_acc[1][3] += p1 * v3;
            o_acc[2][0] += p2 * v0; o_acc[2][1] += p2 * v1; o_acc[2][2] += p2 * v2; o_acc[2][3] += p2 * v3;
            o_acc[3][0] += p3 * v0; o_acc[3][1] += p3 * v1; o_acc[3][2] += p3 * v2; o_acc[3][3] += p3 * v3;
        }
    }

    #pragma unroll
    for (int i = 0; i < 4; ++i) {
        const float inv = 1.f / l_i[i];
        float4 o;
        o.x = o_acc[i][0] * inv;
        o.y = o_acc[i][1] * inv;
        o.z = o_acc[i][2] * inv;
        o.w = o_acc[i][3] * inv;
        *(float4*)(O + base + (size_t)(q0 + ty * 4 + i) * 1024 + tx * 4) = o;
    }
}

// ---------------------------------------------------------------------------
// LayerNorm over last dim (1024). One block per row. Supports Y == X.
// ---------------------------------------------------------------------------
__global__ __launch_bounds__(256) void ln_kernel(
        const float* X, const float* __restrict__ g,
        const float* __restrict__ bta, float* Y)
{
    __shared__ float red[4];
    const int row = blockIdx.x;
    const int tid = threadIdx.x;
    const int wave = tid >> 6, lane = tid & 63;

    const float4 v = ((const float4*)(X + (size_t)row * 1024))[tid];

    float s = v.x + v.y + v.z + v.w;
    #pragma unroll
    for (int off = 32; off; off >>= 1) s += __shfl_xor(s, off);
    if (lane == 0) red[wave] = s;
    __syncthreads();
    const float mu = (red[0] + red[1] + red[2] + red[3]) * (1.f / 1024.f);
    __syncthreads();

    const float dx = v.x - mu, dy = v.y - mu, dz = v.z - mu, dw = v.w - mu;
    float s2 = dx * dx + dy * dy + dz * dz + dw * dw;
    #pragma unroll
    for (int off = 32; off; off >>= 1) s2 += __shfl_xor(s2, off);
    if (lane == 0) red[wave] = s2;
    __syncthreads();
    const float var = (red[0] + red[1] + red[2] + red[3]) * (1.f / 1024.f);
    const float rs = rsqrtf(var + 1e-5f);

    const float4 gg = ((const float4*)g)[tid];
    const float4 bb = ((const float4*)bta)[tid];
    float4 o;
    o.x = dx * rs * gg.x + bb.x;
    o.y = dy * rs * gg.y + bb.y;
    o.z = dz * rs * gg.z + bb.z;
    o.w = dw * rs * gg.w + bb.w;
    ((float4*)(Y + (size_t)row * 1024))[tid] = o;
}

// ---------------------------------------------------------------------------
extern "C" void kernel_launch(void* const* d_in, const int* in_sizes, int n_in,
                              void* d_out, int out_size, void* d_ws, size_t ws_size,
                              hipStream_t stream)
{
    const float* tgt    = (const float*)d_in[0];
    const float* mem    = (const float*)d_in[1];
    // d_in[2] = tgt_mask (always tril; causal hardcoded)
    const float* sa_wq  = (const float*)d_in[3];
    const float* sa_bq  = (const float*)d_in[4];
    const float* sa_wk  = (const float*)d_in[5];
    const float* sa_bk  = (const float*)d_in[6];
    const float* sa_wv  = (const float*)d_in[7];
    const float* sa_bv  = (const float*)d_in[8];
    const float* sa_wo  = (const float*)d_in[9];
    const float* sa_bo  = (const float*)d_in[10];
    const float* ca_wq  = (const float*)d_in[11];
    const float* ca_bq  = (const float*)d_in[12];
    const float* ca_wk  = (const float*)d_in[13];
    const float* ca_bk  = (const float*)d_in[14];
    const float* ca_wv  = (const float*)d_in[15];
    const float* ca_bv  = (const float*)d_in[16];
    const float* ca_wo  = (const float*)d_in[17];
    const float* ca_bo  = (const float*)d_in[18];
    const float* ffn_w1 = (const float*)d_in[19];
    const float* ffn_b1 = (const float*)d_in[20];
    const float* ffn_w2 = (const float*)d_in[21];
    const float* ffn_b2 = (const float*)d_in[22];
    const float* ln1_g  = (const float*)d_in[23];
    const float* ln1_b  = (const float*)d_in[24];
    const float* ln2_g  = (const float*)d_in[25];
    const float* ln2_b  = (const float*)d_in[26];
    const float* ln3_g  = (const float*)d_in[27];
    const float* ln3_b  = (const float*)d_in[28];

    float* out = (float*)d_out;
    float* ws  = (float*)d_ws;
    const size_t S = (size_t)4096 * 1024;
    float* s0 = ws;
    float* s1 = ws + S;
    float* s2 = ws + 2 * S;
    float* s3 = ws + 3 * S;
    float* s4 = ws + 4 * S;

    const dim3 blk(256);
    const dim3 g1024(1024 / BN, 4096 / BM);   // N=1024 GEMMs
    const dim3 g4096(4096 / BN, 4096 / BM);   // FFN1
    const dim3 ga(64, 16);                    // flash attention
    const dim3 gln(4096);

    // ---- self-attention ----
    gemm_kernel<0><<<g1024, blk, 0, stream>>>(tgt, sa_wq, sa_bq, nullptr, s0, 4096, 1024, 1024);
    gemm_kernel<0><<<g1024, blk, 0, stream>>>(tgt, sa_wk, sa_bk, nullptr, s1, 4096, 1024, 1024);
    gemm_kernel<0><<<g1024, blk, 0, stream>>>(tgt, sa_wv, sa_bv, nullptr, s2, 4096, 1024, 1024);
    fattn_kernel<1><<<ga, blk, 0, stream>>>(s0, s1, s2, s3);
    gemm_kernel<0><<<g1024, blk, 0, stream>>>(s3, sa_wo, sa_bo, tgt, s0, 4096, 1024, 1024);
    ln_kernel<<<gln, blk, 0, stream>>>(s0, ln1_g, ln1_b, s1);          // x1 = s1

    // ---- cross-attention ----
    gemm_kernel<0><<<g1024, blk, 0, stream>>>(s1, ca_wq, ca_bq, nullptr, s0, 4096, 1024, 1024);
    gemm_kernel<0><<<g1024, blk, 0, stream>>>(mem, ca_wk, ca_bk, nullptr, s2, 4096, 1024, 1024);
    gemm_kernel<0><<<g1024, blk, 0, stream>>>(mem, ca_wv, ca_bv, nullptr, s3, 4096, 1024, 1024);
    fattn_kernel<0><<<ga, blk, 0, stream>>>(s0, s2, s3, s4);
    gemm_kernel<0><<<g1024, blk, 0, stream>>>(s4, ca_wo, ca_bo, s1, s0, 4096, 1024, 1024);
    ln_kernel<<<gln, blk, 0, stream>>>(s0, ln2_g, ln2_b, s4);          // x2 = s4

    // ---- FFN ----  hidden = relu(x2 @ w1 + b1) in s0..s3 (contiguous 4S)
    gemm_kernel<1><<<g4096, blk, 0, stream>>>(s4, ffn_w1, ffn_b1, nullptr, s0, 4096, 4096, 1024);
    gemm_kernel<0><<<g1024, blk, 0, stream>>>(s0, ffn_w2, ffn_b2, s4, out, 4096, 1024, 4096);
    ln_kernel<<<gln, blk, 0, stream>>>(out, ln3_g, ln3_b, out);        // in-place final LN
}

// Round 3
// 1021.651 us; speedup vs baseline: 8.1651x; 3.2902x over previous
//
#include <hip/hip_runtime.h>
#include <hip/hip_bf16.h>

typedef unsigned short u16;
typedef __attribute__((ext_vector_type(8))) short bf16x8;
typedef __attribute__((ext_vector_type(4))) float floatx4;

__device__ inline float u2f(unsigned u) { union { unsigned i; float f; } x; x.i = u; return x.f; }
__device__ inline float bflo(unsigned p) { return u2f(p << 16); }
__device__ inline float bfhi(unsigned p) { return u2f(p & 0xffff0000u); }
__device__ inline u16 f2bf(float f) {
    union { __hip_bfloat16 h; u16 u; } x;
    x.h = __float2bfloat16(f);
    return x.u;
}

#define GLDS(g, l) __builtin_amdgcn_global_load_lds( \
    (const __attribute__((address_space(1))) void*)(g), \
    (__attribute__((address_space(3))) void*)(l), 16, 0, 0)

// ---------------------------------------------------------------------------
// bf16 MFMA GEMM: C[M,N] = A[M,K] @ Bt[N,K]^T + bias (+res) (+relu)
// 128x128 tile, 4 waves (2x2), 16x16x32 MFMA, BK=32, global_load_lds staging
// with XOR k-slot swizzle (both sides).
// EPI: 0 = bf16 out, 1 = bf16 out + relu, 2 = bf16 out + bf16 res,
//      3 = f32 out + bf16 res
// ---------------------------------------------------------------------------
template<int EPI>
__global__ __launch_bounds__(256) void gemm_mfma(
        const u16* __restrict__ A, const u16* __restrict__ Bt,
        const float* __restrict__ bias, const u16* __restrict__ res,
        void* __restrict__ Cv, int N, int K)
{
    __shared__ u16 Als[128 * 32];
    __shared__ u16 Bls[128 * 32];

    const int tid = threadIdx.x;
    const int lane = tid & 63, wv = tid >> 6;
    const int wr = wv >> 1, wc = wv & 1;
    const int row0 = blockIdx.y * 128, col0 = blockIdx.x * 128;

    // staging: linear LDS dest, inverse-swizzled global source (16B/lane x2)
    const u16* pa[2];
    const u16* pb[2];
    int ldst[2];
    #pragma unroll
    for (int i = 0; i < 2; ++i) {
        const int idx = i * 256 + tid;               // 0..511
        const int r = idx >> 2;                      // tile row 0..127
        const int kob = (idx & 3) << 4;              // byte off in 64B row
        const int sw = kob ^ (((r >> 1) & 3) << 4);  // swizzled byte off
        pa[i] = A  + (size_t)(row0 + r) * K + (sw >> 1);
        pb[i] = Bt + (size_t)(col0 + r) * K + (sw >> 1);
        ldst[i] = idx * 8;                           // u16 elements
    }

    // fragment read offsets (swizzled)
    int offa[4], offb[4];
    const int rsel = lane & 15, slot = lane >> 4;
    #pragma unroll
    for (int m = 0; m < 4; ++m) {
        const int ra = wr * 64 + m * 16 + rsel;
        offa[m] = ra * 32 + (((slot << 4) ^ (((ra >> 1) & 3) << 4)) >> 1);
        const int rb = wc * 64 + m * 16 + rsel;
        offb[m] = rb * 32 + (((slot << 4) ^ (((rb >> 1) & 3) << 4)) >> 1);
    }

    floatx4 acc[4][4] = {};

    for (int kt = 0; kt < K; kt += 32) {
        __syncthreads();
        #pragma unroll
        for (int i = 0; i < 2; ++i) {
            GLDS(pa[i] + kt, &Als[ldst[i]]);
            GLDS(pb[i] + kt, &Bls[ldst[i]]);
        }
        __syncthreads();

        bf16x8 af[4], bfr[4];
        #pragma unroll
        for (int m = 0; m < 4; ++m) af[m] = *(const bf16x8*)&Als[offa[m]];
        #pragma unroll
        for (int n = 0; n < 4; ++n) bfr[n] = *(const bf16x8*)&Bls[offb[n]];
        #pragma unroll
        for (int m = 0; m < 4; ++m)
            #pragma unroll
            for (int n = 0; n < 4; ++n)
                acc[m][n] = __builtin_amdgcn_mfma_f32_16x16x32_bf16(
                        af[m], bfr[n], acc[m][n], 0, 0, 0);
    }

    // epilogue: C/D layout col=lane&15, row=(lane>>4)*4+reg (m89-verified)
    const int cr4 = (lane >> 4) * 4;
    const int cc = lane & 15;
    #pragma unroll
    for (int n = 0; n < 4; ++n) {
        const int col = col0 + wc * 64 + n * 16 + cc;
        const float bv = bias[col];
        #pragma unroll
        for (int m = 0; m < 4; ++m) {
            const int rowb = row0 + wr * 64 + m * 16 + cr4;
            #pragma unroll
            for (int r = 0; r < 4; ++r) {
                float v = acc[m][n][r] + bv;
                const size_t o = (size_t)(rowb + r) * N + col;
                if (EPI == 2 || EPI == 3) v += u2f((unsigned)res[o] << 16);
                if (EPI == 1) v = fmaxf(v, 0.f);
                if (EPI == 3) ((float*)Cv)[o] = v;
                else          ((u16*)Cv)[o] = f2bf(v);
            }
        }
    }
}

// ---------------------------------------------------------------------------
// Weight convert+transpose: W[K,N] f32 -> Wt[N,K] bf16. Grid (N/64, K/64).
// ---------------------------------------------------------------------------
__global__ __launch_bounds__(256) void trw_kernel(
        const float* __restrict__ W, u16* __restrict__ Wt, int K, int N)
{
    __shared__ float ts[64][65];
    const int tid = threadIdx.x;
    const int n0 = blockIdx.x * 64, k0 = blockIdx.y * 64;
    const int tr = tid >> 4, tc4 = (tid & 15) * 4;
    #pragma unroll
    for (int i = 0; i < 4; ++i) {
        const float4 v = *(const float4*)(W + (size_t)(k0 + tr + i * 16) * N + n0 + tc4);
        ts[tr + i * 16][tc4 + 0] = v.x;
        ts[tr + i * 16][tc4 + 1] = v.y;
        ts[tr + i * 16][tc4 + 2] = v.z;
        ts[tr + i * 16][tc4 + 3] = v.w;
    }
    __syncthreads();
    #pragma unroll
    for (int i = 0; i < 4; ++i) {
        const int nr = tr + i * 16;
        ushort4 o;
        o.x = f2bf(ts[tc4 + 0][nr]);
        o.y = f2bf(ts[tc4 + 1][nr]);
        o.z = f2bf(ts[tc4 + 2][nr]);
        o.w = f2bf(ts[tc4 + 3][nr]);
        *(ushort4*)(Wt + (size_t)(n0 + nr) * K + k0 + tc4) = o;
    }
}

// fp32 -> bf16 elementwise (n4 = count/4)
__global__ __launch_bounds__(256) void cvt_kernel(
        const float* __restrict__ in, u16* __restrict__ out, int n4)
{
    for (int i = blockIdx.x * 256 + threadIdx.x; i < n4; i += gridDim.x * 256) {
        const float4 v = ((const float4*)in)[i];
        ushort4 o;
        o.x = f2bf(v.x); o.y = f2bf(v.y); o.z = f2bf(v.z); o.w = f2bf(v.w);
        ((ushort4*)out)[i] = o;
    }
}

// ---------------------------------------------------------------------------
// Flash attention, bf16 in/out, fp32 LDS compute. Grid (64, 16), block 256.
// ---------------------------------------------------------------------------
template<int CAUSAL>
__global__ __launch_bounds__(256) void fattn_kernel(
        const u16* __restrict__ Q, const u16* __restrict__ Km,
        const u16* __restrict__ V, u16* __restrict__ O)
{
    __shared__ float Qs[64][65];
    __shared__ float Ks[64][65];
    __shared__ float Vs[64][65];

    const int tid = threadIdx.x;
    const int tx = tid & 15;
    const int ty = tid >> 4;
    const int b = blockIdx.x >> 4, h = blockIdx.x & 15;
    const int qt = blockIdx.y;
    const int q0 = qt * 64;

    const size_t base = (size_t)b * (1024 * 1024) + (size_t)h * 64;
    const int lr = tid >> 2, lc0 = (tid & 3) * 16;

    {
        const u16* src = Q + base + (size_t)(q0 + lr) * 1024 + lc0;
        #pragma unroll
        for (int hh = 0; hh < 2; ++hh) {
            const uint4 v = *(const uint4*)(src + hh * 8);
            float* d = &Qs[lr][lc0 + hh * 8];
            d[0] = bflo(v.x) * 0.125f; d[1] = bfhi(v.x) * 0.125f;
            d[2] = bflo(v.y) * 0.125f; d[3] = bfhi(v.y) * 0.125f;
            d[4] = bflo(v.z) * 0.125f; d[5] = bfhi(v.z) * 0.125f;
            d[6] = bflo(v.w) * 0.125f; d[7] = bfhi(v.w) * 0.125f;
        }
    }

    float m_i[4] = {-1e30f, -1e30f, -1e30f, -1e30f};
    float l_i[4] = {0.f, 0.f, 0.f, 0.f};
    float o_acc[4][4] = {};

    const int ktmax = CAUSAL ? qt : 15;
    for (int kt = 0; kt <= ktmax; ++kt) {
        __syncthreads();
        {
            const u16* ksrc = Km + base + (size_t)(kt * 64 + lr) * 1024 + lc0;
            const u16* vsrc = V  + base + (size_t)(kt * 64 + lr) * 1024 + lc0;
            #pragma unroll
            for (int hh = 0; hh < 2; ++hh) {
                const uint4 kv = *(const uint4*)(ksrc + hh * 8);
                float* kd = &Ks[lr][lc0 + hh * 8];
                kd[0] = bflo(kv.x); kd[1] = bfhi(kv.x);
                kd[2] = bflo(kv.y); kd[3] = bfhi(kv.y);
                kd[4] = bflo(kv.z); kd[5] = bfhi(kv.z);
                kd[6] = bflo(kv.w); kd[7] = bfhi(kv.w);
                const uint4 vv = *(const uint4*)(vsrc + hh * 8);
                float* vd = &Vs[lr][lc0 + hh * 8];
                vd[0] = bflo(vv.x); vd[1] = bfhi(vv.x);
                vd[2] = bflo(vv.y); vd[3] = bfhi(vv.y);
                vd[4] = bflo(vv.z); vd[5] = bfhi(vv.z);
                vd[6] = bflo(vv.w); vd[7] = bfhi(vv.w);
            }
        }
        __syncthreads();

        float s[4][4] = {};
        #pragma unroll 8
        for (int d = 0; d < 64; ++d) {
            const float a0 = Qs[ty * 4 + 0][d];
            const float a1 = Qs[ty * 4 + 1][d];
            const float a2 = Qs[ty * 4 + 2][d];
            const float a3 = Qs[ty * 4 + 3][d];
            const float b0 = Ks[tx * 4 + 0][d];
            const float b1 = Ks[tx * 4 + 1][d];
            const float b2 = Ks[tx * 4 + 2][d];
            const float b3 = Ks[tx * 4 + 3][d];
            s[0][0] += a0 * b0; s[0][1] += a0 * b1; s[0][2] += a0 * b2; s[0][3] += a0 * b3;
            s[1][0] += a1 * b0; s[1][1] += a1 * b1; s[1][2] += a1 * b2; s[1][3] += a1 * b3;
            s[2][0] += a2 * b0; s[2][1] += a2 * b1; s[2][2] += a2 * b2; s[2][3] += a2 * b3;
            s[3][0] += a3 * b0; s[3][1] += a3 * b1; s[3][2] += a3 * b2; s[3][3] += a3 * b3;
        }

        if (CAUSAL && kt == qt) {
            #pragma unroll
            for (int i = 0; i < 4; ++i)
                #pragma unroll
                for (int j = 0; j < 4; ++j)
                    if (tx * 4 + j > ty * 4 + i) s[i][j] = -1e9f;
        }

        #pragma unroll
        for (int i = 0; i < 4; ++i) {
            float tmax = fmaxf(fmaxf(s[i][0], s[i][1]), fmaxf(s[i][2], s[i][3]));
            tmax = fmaxf(tmax, __shfl_xor(tmax, 1));
            tmax = fmaxf(tmax, __shfl_xor(tmax, 2));
            tmax = fmaxf(tmax, __shfl_xor(tmax, 4));
            tmax = fmaxf(tmax, __shfl_xor(tmax, 8));
            const float mn = fmaxf(m_i[i], tmax);
            const float alpha = __expf(m_i[i] - mn);
            m_i[i] = mn;
            float rs = 0.f;
            #pragma unroll
            for (int j = 0; j < 4; ++j) { s[i][j] = __expf(s[i][j] - mn); rs += s[i][j]; }
            rs += __shfl_xor(rs, 1);
            rs += __shfl_xor(rs, 2);
            rs += __shfl_xor(rs, 4);
            rs += __shfl_xor(rs, 8);
            l_i[i] = l_i[i] * alpha + rs;
            o_acc[i][0] *= alpha; o_acc[i][1] *= alpha;
            o_acc[i][2] *= alpha; o_acc[i][3] *= alpha;
        }

        __syncthreads();
        #pragma unroll
        for (int i = 0; i < 4; ++i)
            #pragma unroll
            for (int j = 0; j < 4; ++j)
                Ks[ty * 4 + i][tx * 4 + j] = s[i][j];
        __syncthreads();

        #pragma unroll 8
        for (int kk = 0; kk < 64; ++kk) {
            const float p0 = Ks[ty * 4 + 0][kk];
            const float p1 = Ks[ty * 4 + 1][kk];
            const float p2 = Ks[ty * 4 + 2][kk];
            const float p3 = Ks[ty * 4 + 3][kk];
            const float v0 = Vs[kk][tx * 4 + 0];
            const float v1 = Vs[kk][tx * 4 + 1];
            const float v2 = Vs[kk][tx * 4 + 2];
            const float v3 = Vs[kk][tx * 4 + 3];
            o_acc[0][0] += p0 * v0; o_acc[0][1] += p0 * v1; o_acc[0][2] += p0 * v2; o_acc[0][3] += p0 * v3;
            o_acc[1][0] += p1 * v0; o_acc[1][1] += p1 * v1; o_acc[1][2] += p1 * v2; o_acc[1][3] += p1 * v3;
            o_acc[2][0] += p2 * v0; o_acc[2][1] += p2 * v1; o_acc[2][2] += p2 * v2; o_acc[2][3] += p2 * v3;
            o_acc[3][0] += p3 * v0; o_acc[3][1] += p3 * v1; o_acc[3][2] += p3 * v2; o_acc[3][3] += p3 * v3;
        }
    }

    #pragma unroll
    for (int i = 0; i < 4; ++i) {
        const float inv = 1.f / l_i[i];
        ushort4 ov;
        ov.x = f2bf(o_acc[i][0] * inv);
        ov.y = f2bf(o_acc[i][1] * inv);
        ov.z = f2bf(o_acc[i][2] * inv);
        ov.w = f2bf(o_acc[i][3] * inv);
        *(ushort4*)(O + base + (size_t)(q0 + ty * 4 + i) * 1024 + tx * 4) = ov;
    }
}

// ---------------------------------------------------------------------------
// LayerNorm, bf16 in/out, fp32 stats. One block (256) per row of 1024.
// ---------------------------------------------------------------------------
__global__ __launch_bounds__(256) void ln_bf16_kernel(
        const u16* __restrict__ X, const float* __restrict__ g,
        const float* __restrict__ bta, u16* __restrict__ Y)
{
    __shared__ float red[4];
    const int row = blockIdx.x, tid = threadIdx.x;
    const int wave = tid >> 6, lane = tid & 63;

    const uint2 u = *(const uint2*)(X + (size_t)row * 1024 + tid * 4);
    const float x0 = bflo(u.x), x1 = bfhi(u.x), x2 = bflo(u.y), x3 = bfhi(u.y);

    float s = x0 + x1 + x2 + x3;
    #pragma unroll
    for (int off = 32; off; off >>= 1) s += __shfl_xor(s, off);
    if (lane == 0) red[wave] = s;
    __syncthreads();
    const float mu = (red[0] + red[1] + red[2] + red[3]) * (1.f / 1024.f);
    __syncthreads();

    const float d0 = x0 - mu, d1 = x1 - mu, d2 = x2 - mu, d3 = x3 - mu;
    float s2 = d0 * d0 + d1 * d1 + d2 * d2 + d3 * d3;
    #pragma unroll
    for (int off = 32; off; off >>= 1) s2 += __shfl_xor(s2, off);
    if (lane == 0) red[wave] = s2;
    __syncthreads();
    const float var = (red[0] + red[1] + red[2] + red[3]) * (1.f / 1024.f);
    const float rs = rsqrtf(var + 1e-5f);

    const float4 gg = ((const float4*)g)[tid];
    const float4 bb = ((const float4*)bta)[tid];
    ushort4 o;
    o.x = f2bf(d0 * rs * gg.x + bb.x);
    o.y = f2bf(d1 * rs * gg.y + bb.y);
    o.z = f2bf(d2 * rs * gg.z + bb.z);
    o.w = f2bf(d3 * rs * gg.w + bb.w);
    *(ushort4*)(Y + (size_t)row * 1024 + tid * 4) = o;
}

// fp32 in-place LayerNorm (final output)
__global__ __launch_bounds__(256) void ln_kernel(
        const float* X, const float* __restrict__ g,
        const float* __restrict__ bta, float* Y)
{
    __shared__ float red[4];
    const int row = blockIdx.x;
    const int tid = threadIdx.x;
    const int wave = tid >> 6, lane = tid & 63;

    const float4 v = ((const float4*)(X + (size_t)row * 1024))[tid];

    float s = v.x + v.y + v.z + v.w;
    #pragma unroll
    for (int off = 32; off; off >>= 1) s += __shfl_xor(s, off);
    if (lane == 0) red[wave] = s;
    __syncthreads();
    const float mu = (red[0] + red[1] + red[2] + red[3]) * (1.f / 1024.f);
    __syncthreads();

    const float dx = v.x - mu, dy = v.y - mu, dz = v.z - mu, dw = v.w - mu;
    float s2 = dx * dx + dy * dy + dz * dz + dw * dw;
    #pragma unroll
    for (int off = 32; off; off >>= 1) s2 += __shfl_xor(s2, off);
    if (lane == 0) red[wave] = s2;
    __syncthreads();
    const float var = (red[0] + red[1] + red[2] + red[3]) * (1.f / 1024.f);
    const float rs = rsqrtf(var + 1e-5f);

    const float4 gg = ((const float4*)g)[tid];
    const float4 bb = ((const float4*)bta)[tid];
    float4 o;
    o.x = dx * rs * gg.x + bb.x;
    o.y = dy * rs * gg.y + bb.y;
    o.z = dz * rs * gg.z + bb.z;
    o.w = dw * rs * gg.w + bb.w;
    ((float4*)(Y + (size_t)row * 1024))[tid] = o;
}

// ---------------------------------------------------------------------------
extern "C" void kernel_launch(void* const* d_in, const int* in_sizes, int n_in,
                              void* d_out, int out_size, void* d_ws, size_t ws_size,
                              hipStream_t stream)
{
    const float* tgt    = (const float*)d_in[0];
    const float* mem    = (const float*)d_in[1];
    const float* sa_wq  = (const float*)d_in[3];
    const float* sa_bq  = (const float*)d_in[4];
    const float* sa_wk  = (const float*)d_in[5];
    const float* sa_bk  = (const float*)d_in[6];
    const float* sa_wv  = (const float*)d_in[7];
    const float* sa_bv  = (const float*)d_in[8];
    const float* sa_wo  = (const float*)d_in[9];
    const float* sa_bo  = (const float*)d_in[10];
    const float* ca_wq  = (const float*)d_in[11];
    const float* ca_bq  = (const float*)d_in[12];
    const float* ca_wk  = (const float*)d_in[13];
    const float* ca_bk  = (const float*)d_in[14];
    const float* ca_wv  = (const float*)d_in[15];
    const float* ca_bv  = (const float*)d_in[16];
    const float* ca_wo  = (const float*)d_in[17];
    const float* ca_bo  = (const float*)d_in[18];
    const float* ffn_w1 = (const float*)d_in[19];
    const float* ffn_b1 = (const float*)d_in[20];
    const float* ffn_w2 = (const float*)d_in[21];
    const float* ffn_b2 = (const float*)d_in[22];
    const float* ln1_g  = (const float*)d_in[23];
    const float* ln1_b  = (const float*)d_in[24];
    const float* ln2_g  = (const float*)d_in[25];
    const float* ln2_b  = (const float*)d_in[26];
    const float* ln3_g  = (const float*)d_in[27];
    const float* ln3_b  = (const float*)d_in[28];

    float* out = (float*)d_out;
    u16* wsb = (u16*)d_ws;
    const size_t M1 = 1024 * 1024;

    // weights (bf16, transposed [N][K]): 16M elems = 32 MB
    u16* Wsq = wsb + 0 * M1;
    u16* Wsk = wsb + 1 * M1;
    u16* Wsv = wsb + 2 * M1;
    u16* Wso = wsb + 3 * M1;
    u16* Wcq = wsb + 4 * M1;
    u16* Wck = wsb + 5 * M1;
    u16* Wcv = wsb + 6 * M1;
    u16* Wco = wsb + 7 * M1;
    u16* Wf1 = wsb + 8 * M1;    // [4096][1024]
    u16* Wf2 = wsb + 12 * M1;   // [1024][4096]

    // activation slots (bf16 [4096][1024] = 4M elems each): 6 slots = 48 MB
    u16* sl = wsb + 16 * M1;
    u16* s0 = sl + 0 * 4 * M1;
    u16* s1 = sl + 4 * M1;
    u16* s2 = sl + 8 * M1;
    u16* s3 = sl + 12 * M1;
    u16* s4 = sl + 16 * M1;
    u16* s5 = sl + 20 * M1;
    u16* H  = s0;               // FFN hidden [4096][4096] aliases s0..s3 (dead)

    const dim3 blk(256);
    const dim3 gw11(16, 16);    // 1024x1024 weight transpose
    const dim3 g1(8, 32);       // N=1024 GEMM
    const dim3 g4(32, 32);      // N=4096 GEMM (FFN1)
    const dim3 ga(64, 16);      // attention
    const dim3 gln(4096);

    // weight conversion + transpose
    trw_kernel<<<gw11, blk, 0, stream>>>(sa_wq, Wsq, 1024, 1024);
    trw_kernel<<<gw11, blk, 0, stream>>>(sa_wk, Wsk, 1024, 1024);
    trw_kernel<<<gw11, blk, 0, stream>>>(sa_wv, Wsv, 1024, 1024);
    trw_kernel<<<gw11, blk, 0, stream>>>(sa_wo, Wso, 1024, 1024);
    trw_kernel<<<gw11, blk, 0, stream>>>(ca_wq, Wcq, 1024, 1024);
    trw_kernel<<<gw11, blk, 0, stream>>>(ca_wk, Wck, 1024, 1024);
    trw_kernel<<<gw11, blk, 0, stream>>>(ca_wv, Wcv, 1024, 1024);
    trw_kernel<<<gw11, blk, 0, stream>>>(ca_wo, Wco, 1024, 1024);
    trw_kernel<<<dim3(64, 16), blk, 0, stream>>>(ffn_w1, Wf1, 1024, 4096);
    trw_kernel<<<dim3(16, 64), blk, 0, stream>>>(ffn_w2, Wf2, 4096, 1024);

    // activation conversion
    cvt_kernel<<<2048, blk, 0, stream>>>(tgt, s0, 1024 * 1024);
    cvt_kernel<<<2048, blk, 0, stream>>>(mem, s1, 1024 * 1024);

    // ---- self-attention ----
    gemm_mfma<0><<<g1, blk, 0, stream>>>(s0, Wsq, sa_bq, nullptr, s2, 1024, 1024);
    gemm_mfma<0><<<g1, blk, 0, stream>>>(s0, Wsk, sa_bk, nullptr, s3, 1024, 1024);
    gemm_mfma<0><<<g1, blk, 0, stream>>>(s0, Wsv, sa_bv, nullptr, s4, 1024, 1024);
    fattn_kernel<1><<<ga, blk, 0, stream>>>(s2, s3, s4, s5);
    gemm_mfma<2><<<g1, blk, 0, stream>>>(s5, Wso, sa_bo, s0, s2, 1024, 1024);
    ln_bf16_kernel<<<gln, blk, 0, stream>>>(s2, ln1_g, ln1_b, s3);     // x1 = s3

    // ---- cross-attention ----
    gemm_mfma<0><<<g1, blk, 0, stream>>>(s3, Wcq, ca_bq, nullptr, s2, 1024, 1024);
    gemm_mfma<0><<<g1, blk, 0, stream>>>(s1, Wck, ca_bk, nullptr, s4, 1024, 1024);
    gemm_mfma<0><<<g1, blk, 0, stream>>>(s1, Wcv, ca_bv, nullptr, s5, 1024, 1024);
    fattn_kernel<0><<<ga, blk, 0, stream>>>(s2, s4, s5, s0);
    gemm_mfma<2><<<g1, blk, 0, stream>>>(s0, Wco, ca_bo, s3, s2, 1024, 1024);
    ln_bf16_kernel<<<gln, blk, 0, stream>>>(s2, ln2_g, ln2_b, s4);     // x2 = s4

    // ---- FFN ----
    gemm_mfma<1><<<g4, blk, 0, stream>>>(s4, Wf1, ffn_b1, nullptr, H, 4096, 1024);
    gemm_mfma<3><<<g1, blk, 0, stream>>>(H, Wf2, ffn_b2, s4, out, 1024, 4096);
    ln_kernel<<<gln, blk, 0, stream>>>(out, ln3_g, ln3_b, out);
}

// Round 4
// 520.246 us; speedup vs baseline: 16.0346x; 1.9638x over previous
//
#include <hip/hip_runtime.h>
#include <hip/hip_bf16.h>

typedef unsigned short u16;
typedef __attribute__((ext_vector_type(8))) short bf16x8;
typedef __attribute__((ext_vector_type(4))) float floatx4;

__device__ inline float u2f(unsigned u) { union { unsigned i; float f; } x; x.i = u; return x.f; }
__device__ inline float bflo(unsigned p) { return u2f(p << 16); }
__device__ inline float bfhi(unsigned p) { return u2f(p & 0xffff0000u); }
__device__ inline u16 f2bf(float f) {
    union { __hip_bfloat16 h; u16 u; } x;
    x.h = __float2bfloat16(f);
    return x.u;
}

#define GLDS(g, l) __builtin_amdgcn_global_load_lds( \
    (const __attribute__((address_space(1))) void*)(g), \
    (__attribute__((address_space(3))) void*)(l), 16, 0, 0)

// ---------------------------------------------------------------------------
// bf16 MFMA GEMM: C[M,N] = A[M,K] @ Bt[N,K]^T + bias (+res) (+relu)
// 128x128 tile, 4 waves (2x2), 16x16x32 MFMA, BK=32.
// EPI: 0 = bf16 out, 1 = bf16 out + relu, 2 = bf16 out + bf16 res,
//      3 = f32 out + bf16 res, 4 = bf16 transposed-per-head V out
// ---------------------------------------------------------------------------
template<int EPI>
__global__ __launch_bounds__(256) void gemm_mfma(
        const u16* __restrict__ A, const u16* __restrict__ Bt,
        const float* __restrict__ bias, const u16* __restrict__ res,
        void* __restrict__ Cv, int N, int K)
{
    __shared__ u16 Als[128 * 32];
    __shared__ u16 Bls[128 * 32];

    const int tid = threadIdx.x;
    const int lane = tid & 63, wv = tid >> 6;
    const int wr = wv >> 1, wc = wv & 1;
    const int row0 = blockIdx.y * 128, col0 = blockIdx.x * 128;

    // staging: linear LDS dest, inverse-swizzled global source (16B/lane x2)
    const u16* pa[2];
    const u16* pb[2];
    int ldst[2];
    #pragma unroll
    for (int i = 0; i < 2; ++i) {
        const int idx = i * 256 + tid;               // 0..511
        const int r = idx >> 2;                      // tile row 0..127
        const int kob = (idx & 3) << 4;              // byte off in 64B row
        const int sw = kob ^ (((r >> 1) & 3) << 4);  // swizzled byte off
        pa[i] = A  + (size_t)(row0 + r) * K + (sw >> 1);
        pb[i] = Bt + (size_t)(col0 + r) * K + (sw >> 1);
        ldst[i] = idx * 8;                           // u16 elements
    }

    // fragment read offsets (swizzled)
    int offa[4], offb[4];
    const int rsel = lane & 15, slot = lane >> 4;
    #pragma unroll
    for (int m = 0; m < 4; ++m) {
        const int ra = wr * 64 + m * 16 + rsel;
        offa[m] = ra * 32 + (((slot << 4) ^ (((ra >> 1) & 3) << 4)) >> 1);
        const int rb = wc * 64 + m * 16 + rsel;
        offb[m] = rb * 32 + (((slot << 4) ^ (((rb >> 1) & 3) << 4)) >> 1);
    }

    floatx4 acc[4][4] = {};

    for (int kt = 0; kt < K; kt += 32) {
        __syncthreads();
        #pragma unroll
        for (int i = 0; i < 2; ++i) {
            GLDS(pa[i] + kt, &Als[ldst[i]]);
            GLDS(pb[i] + kt, &Bls[ldst[i]]);
        }
        __syncthreads();

        bf16x8 af[4], bfr[4];
        #pragma unroll
        for (int m = 0; m < 4; ++m) af[m] = *(const bf16x8*)&Als[offa[m]];
        #pragma unroll
        for (int n = 0; n < 4; ++n) bfr[n] = *(const bf16x8*)&Bls[offb[n]];
        #pragma unroll
        for (int m = 0; m < 4; ++m)
            #pragma unroll
            for (int n = 0; n < 4; ++n)
                acc[m][n] = __builtin_amdgcn_mfma_f32_16x16x32_bf16(
                        af[m], bfr[n], acc[m][n], 0, 0, 0);
    }

    // epilogue: C/D layout col=lane&15, row=(lane>>4)*4+reg
    const int cr4 = (lane >> 4) * 4;
    const int cc = lane & 15;

    if (EPI == 4) {
        // transposed per-head V: Vt[b*16+h][d][t], t fast. 4 regs = 4 tokens.
        #pragma unroll
        for (int n = 0; n < 4; ++n) {
            const int col = col0 + wc * 64 + n * 16 + cc;     // 0..1023
            const float bv = bias[col];
            const int h = col >> 6, d = col & 63;
            #pragma unroll
            for (int m = 0; m < 4; ++m) {
                const int t = row0 + wr * 64 + m * 16 + cr4;  // token
                const int b = t >> 10;
                ushort4 o4;
                o4.x = f2bf(acc[m][n][0] + bv);
                o4.y = f2bf(acc[m][n][1] + bv);
                o4.z = f2bf(acc[m][n][2] + bv);
                o4.w = f2bf(acc[m][n][3] + bv);
                *(ushort4*)((u16*)Cv +
                    (((size_t)(b * 16 + h) * 64 + d) * 1024 + (t & 1023))) = o4;
            }
        }
        return;
    }

    #pragma unroll
    for (int n = 0; n < 4; ++n) {
        const int col = col0 + wc * 64 + n * 16 + cc;
        const float bv = bias[col];
        #pragma unroll
        for (int m = 0; m < 4; ++m) {
            const int rowb = row0 + wr * 64 + m * 16 + cr4;
            #pragma unroll
            for (int r = 0; r < 4; ++r) {
                float v = acc[m][n][r] + bv;
                const size_t o = (size_t)(rowb + r) * N + col;
                if (EPI == 2 || EPI == 3) v += u2f((unsigned)res[o] << 16);
                if (EPI == 1) v = fmaxf(v, 0.f);
                if (EPI == 3) ((float*)Cv)[o] = v;
                else          ((u16*)Cv)[o] = f2bf(v);
            }
        }
    }
}

// ---------------------------------------------------------------------------
// Weight convert+transpose: W[K,N] f32 -> Wt[N,K] bf16. Grid (N/64, K/64).
// ---------------------------------------------------------------------------
__global__ __launch_bounds__(256) void trw_kernel(
        const float* __restrict__ W, u16* __restrict__ Wt, int K, int N)
{
    __shared__ float ts[64][65];
    const int tid = threadIdx.x;
    const int n0 = blockIdx.x * 64, k0 = blockIdx.y * 64;
    const int tr = tid >> 4, tc4 = (tid & 15) * 4;
    #pragma unroll
    for (int i = 0; i < 4; ++i) {
        const float4 v = *(const float4*)(W + (size_t)(k0 + tr + i * 16) * N + n0 + tc4);
        ts[tr + i * 16][tc4 + 0] = v.x;
        ts[tr + i * 16][tc4 + 1] = v.y;
        ts[tr + i * 16][tc4 + 2] = v.z;
        ts[tr + i * 16][tc4 + 3] = v.w;
    }
    __syncthreads();
    #pragma unroll
    for (int i = 0; i < 4; ++i) {
        const int nr = tr + i * 16;
        ushort4 o;
        o.x = f2bf(ts[tc4 + 0][nr]);
        o.y = f2bf(ts[tc4 + 1][nr]);
        o.z = f2bf(ts[tc4 + 2][nr]);
        o.w = f2bf(ts[tc4 + 3][nr]);
        *(ushort4*)(Wt + (size_t)(n0 + nr) * K + k0 + tc4) = o;
    }
}

// fp32 -> bf16 elementwise (n4 = count/4)
__global__ __launch_bounds__(256) void cvt_kernel(
        const float* __restrict__ in, u16* __restrict__ out, int n4)
{
    for (int i = blockIdx.x * 256 + threadIdx.x; i < n4; i += gridDim.x * 256) {
        const float4 v = ((const float4*)in)[i];
        ushort4 o;
        o.x = f2bf(v.x); o.y = f2bf(v.y); o.z = f2bf(v.z); o.w = f2bf(v.w);
        ((ushort4*)out)[i] = o;
    }
}

// ---------------------------------------------------------------------------
// MFMA flash attention. Q,K: [4096][1024] bf16 (head h at cols h*64..+64).
// Vt: [b*16+h][64 d][1024 t] bf16 (transposed, from gemm EPI=4).
// Block = 256 thr (4 waves), one (b,h) x 64 q-rows. Grid (64, 16).
// All LDS tiles 64x64 bf16, swizzled: byte = r*128 + ((c*2) ^ ((r&7)<<4)).
// ---------------------------------------------------------------------------
template<int CAUSAL>
__global__ __launch_bounds__(256) void fattn_mfma(
        const u16* __restrict__ Q, const u16* __restrict__ K,
        const u16* __restrict__ Vt, u16* __restrict__ O)
{
    __shared__ u16 Qs[64 * 64];
    __shared__ u16 Ks[64 * 64];
    __shared__ u16 Ps[64 * 64];
    __shared__ u16 Vs[64 * 64];

    const int tid = threadIdx.x;
    const int lane = tid & 63, wv = tid >> 6;
    const int bh = blockIdx.x;
    const int b = bh >> 4, h = bh & 15;
    const int qt = blockIdx.y, q0 = qt * 64;

    const size_t qkbase = (size_t)b * (1024 * 1024) + (size_t)h * 64;
    const size_t vtbase = (size_t)bh * 64 * 1024;

    // stage Q (swizzled)
    #pragma unroll
    for (int i = 0; i < 2; ++i) {
        const int idx = i * 256 + tid, r = idx >> 3, s = idx & 7;
        const uint4 v = *(const uint4*)(Q + qkbase + (size_t)(q0 + r) * 1024 + s * 8);
        *(uint4*)((char*)Qs + r * 128 + ((s ^ (r & 7)) << 4)) = v;
    }
    __syncthreads();

    // hoist Q a-frags (each wave owns rows wv*16..+16)
    bf16x8 qf[2];
    #pragma unroll
    for (int ks = 0; ks < 2; ++ks) {
        const int r = wv * 16 + (lane & 15);
        const int slot = ks * 4 + (lane >> 4);
        qf[ks] = *(const bf16x8*)((char*)Qs + r * 128 + ((slot ^ (r & 7)) << 4));
    }

    float m_i[4] = {-1e30f, -1e30f, -1e30f, -1e30f};
    float l_i[4] = {0.f, 0.f, 0.f, 0.f};
    floatx4 o_acc[4] = {};   // [n = d-tile]; rows via C/D mapping

    const int ktmax = CAUSAL ? qt : 15;
    for (int kt = 0; kt <= ktmax; ++kt) {
        __syncthreads();   // prev-iter PV done; safe to restage
        #pragma unroll
        for (int i = 0; i < 2; ++i) {
            const int idx = i * 256 + tid, r = idx >> 3, s = idx & 7;
            const uint4 kv = *(const uint4*)(K + qkbase + (size_t)(kt * 64 + r) * 1024 + s * 8);
            *(uint4*)((char*)Ks + r * 128 + ((s ^ (r & 7)) << 4)) = kv;
            const uint4 vv = *(const uint4*)(Vt + vtbase + (size_t)r * 1024 + kt * 64 + s * 8);
            *(uint4*)((char*)Vs + r * 128 + ((s ^ (r & 7)) << 4)) = vv;
        }
        __syncthreads();

        // S = Q @ K^T
        floatx4 sa[4] = {};
        #pragma unroll
        for (int ks = 0; ks < 2; ++ks) {
            #pragma unroll
            for (int n = 0; n < 4; ++n) {
                const int r = n * 16 + (lane & 15);
                const int slot = ks * 4 + (lane >> 4);
                const bf16x8 bf = *(const bf16x8*)((char*)Ks + r * 128 + ((slot ^ (r & 7)) << 4));
                sa[n] = __builtin_amdgcn_mfma_f32_16x16x32_bf16(qf[ks], bf, sa[n], 0, 0, 0);
            }
        }

        // scale + mask
        float p[4][4];   // [n][reg]
        #pragma unroll
        for (int n = 0; n < 4; ++n)
            #pragma unroll
            for (int r = 0; r < 4; ++r) {
                float v = sa[n][r] * 0.125f;
                if (CAUSAL && kt == qt) {
                    const int ql = wv * 16 + (lane >> 4) * 4 + r;
                    const int kl = n * 16 + (lane & 15);
                    if (kl > ql) v = -1e30f;
                }
                p[n][r] = v;
            }

        // online softmax (row r lives in the 16 lanes of a quarter)
        #pragma unroll
        for (int r = 0; r < 4; ++r) {
            float mx = fmaxf(fmaxf(p[0][r], p[1][r]), fmaxf(p[2][r], p[3][r]));
            mx = fmaxf(mx, __shfl_xor(mx, 1));
            mx = fmaxf(mx, __shfl_xor(mx, 2));
            mx = fmaxf(mx, __shfl_xor(mx, 4));
            mx = fmaxf(mx, __shfl_xor(mx, 8));
            const float mn = fmaxf(m_i[r], mx);
            const float al = __expf(m_i[r] - mn);
            m_i[r] = mn;
            float rs = 0.f;
            #pragma unroll
            for (int n = 0; n < 4; ++n) { p[n][r] = __expf(p[n][r] - mn); rs += p[n][r]; }
            rs += __shfl_xor(rs, 1);
            rs += __shfl_xor(rs, 2);
            rs += __shfl_xor(rs, 4);
            rs += __shfl_xor(rs, 8);
            l_i[r] = l_i[r] * al + rs;
            o_acc[0][r] *= al; o_acc[1][r] *= al;
            o_acc[2][r] *= al; o_acc[3][r] *= al;
        }

        // write P to own wave's LDS rows (no barrier needed: same-wave RAW)
        #pragma unroll
        for (int n = 0; n < 4; ++n)
            #pragma unroll
            for (int r = 0; r < 4; ++r) {
                const int qr = wv * 16 + (lane >> 4) * 4 + r;
                const int k2 = (n * 16 + (lane & 15)) * 2;
                *(u16*)((char*)Ps + qr * 128 + (k2 ^ ((qr & 7) << 4))) = f2bf(p[n][r]);
            }

        // O += P @ V
        #pragma unroll
        for (int ks = 0; ks < 2; ++ks) {
            const int ra = wv * 16 + (lane & 15);
            const int slot = ks * 4 + (lane >> 4);
            const bf16x8 af = *(const bf16x8*)((char*)Ps + ra * 128 + ((slot ^ (ra & 7)) << 4));
            #pragma unroll
            for (int n = 0; n < 4; ++n) {
                const int rv = n * 16 + (lane & 15);
                const bf16x8 bf = *(const bf16x8*)((char*)Vs + rv * 128 + ((slot ^ (rv & 7)) << 4));
                o_acc[n] = __builtin_amdgcn_mfma_f32_16x16x32_bf16(af, bf, o_acc[n], 0, 0, 0);
            }
        }
    }

    #pragma unroll
    for (int r = 0; r < 4; ++r) {
        const float inv = 1.f / l_i[r];
        const int qg = q0 + wv * 16 + (lane >> 4) * 4 + r;
        #pragma unroll
        for (int n = 0; n < 4; ++n) {
            const int d = n * 16 + (lane & 15);
            O[qkbase + (size_t)qg * 1024 + d] = f2bf(o_acc[n][r] * inv);
        }
    }
}

// ---------------------------------------------------------------------------
// LayerNorm, bf16 in/out, fp32 stats. One block (256) per row of 1024.
// ---------------------------------------------------------------------------
__global__ __launch_bounds__(256) void ln_bf16_kernel(
        const u16* __restrict__ X, const float* __restrict__ g,
        const float* __restrict__ bta, u16* __restrict__ Y)
{
    __shared__ float red[4];
    const int row = blockIdx.x, tid = threadIdx.x;
    const int wave = tid >> 6, lane = tid & 63;

    const uint2 u = *(const uint2*)(X + (size_t)row * 1024 + tid * 4);
    const float x0 = bflo(u.x), x1 = bfhi(u.x), x2 = bflo(u.y), x3 = bfhi(u.y);

    float s = x0 + x1 + x2 + x3;
    #pragma unroll
    for (int off = 32; off; off >>= 1) s += __shfl_xor(s, off);
    if (lane == 0) red[wave] = s;
    __syncthreads();
    const float mu = (red[0] + red[1] + red[2] + red[3]) * (1.f / 1024.f);
    __syncthreads();

    const float d0 = x0 - mu, d1 = x1 - mu, d2 = x2 - mu, d3 = x3 - mu;
    float s2 = d0 * d0 + d1 * d1 + d2 * d2 + d3 * d3;
    #pragma unroll
    for (int off = 32; off; off >>= 1) s2 += __shfl_xor(s2, off);
    if (lane == 0) red[wave] = s2;
    __syncthreads();
    const float var = (red[0] + red[1] + red[2] + red[3]) * (1.f / 1024.f);
    const float rs = rsqrtf(var + 1e-5f);

    const float4 gg = ((const float4*)g)[tid];
    const float4 bb = ((const float4*)bta)[tid];
    ushort4 o;
    o.x = f2bf(d0 * rs * gg.x + bb.x);
    o.y = f2bf(d1 * rs * gg.y + bb.y);
    o.z = f2bf(d2 * rs * gg.z + bb.z);
    o.w = f2bf(d3 * rs * gg.w + bb.w);
    *(ushort4*)(Y + (size_t)row * 1024 + tid * 4) = o;
}

// fp32 in-place LayerNorm (final output)
__global__ __launch_bounds__(256) void ln_kernel(
        const float* X, const float* __restrict__ g,
        const float* __restrict__ bta, float* Y)
{
    __shared__ float red[4];
    const int row = blockIdx.x;
    const int tid = threadIdx.x;
    const int wave = tid >> 6, lane = tid & 63;

    const float4 v = ((const float4*)(X + (size_t)row * 1024))[tid];

    float s = v.x + v.y + v.z + v.w;
    #pragma unroll
    for (int off = 32; off; off >>= 1) s += __shfl_xor(s, off);
    if (lane == 0) red[wave] = s;
    __syncthreads();
    const float mu = (red[0] + red[1] + red[2] + red[3]) * (1.f / 1024.f);
    __syncthreads();

    const float dx = v.x - mu, dy = v.y - mu, dz = v.z - mu, dw = v.w - mu;
    float s2 = dx * dx + dy * dy + dz * dz + dw * dw;
    #pragma unroll
    for (int off = 32; off; off >>= 1) s2 += __shfl_xor(s2, off);
    if (lane == 0) red[wave] = s2;
    __syncthreads();
    const float var = (red[0] + red[1] + red[2] + red[3]) * (1.f / 1024.f);
    const float rs = rsqrtf(var + 1e-5f);

    const float4 gg = ((const float4*)g)[tid];
    const float4 bb = ((const float4*)bta)[tid];
    float4 o;
    o.x = dx * rs * gg.x + bb.x;
    o.y = dy * rs * gg.y + bb.y;
    o.z = dz * rs * gg.z + bb.z;
    o.w = dw * rs * gg.w + bb.w;
    ((float4*)(Y + (size_t)row * 1024))[tid] = o;
}

// ---------------------------------------------------------------------------
extern "C" void kernel_launch(void* const* d_in, const int* in_sizes, int n_in,
                              void* d_out, int out_size, void* d_ws, size_t ws_size,
                              hipStream_t stream)
{
    const float* tgt    = (const float*)d_in[0];
    const float* mem    = (const float*)d_in[1];
    const float* sa_wq  = (const float*)d_in[3];
    const float* sa_bq  = (const float*)d_in[4];
    const float* sa_wk  = (const float*)d_in[5];
    const float* sa_bk  = (const float*)d_in[6];
    const float* sa_wv  = (const float*)d_in[7];
    const float* sa_bv  = (const float*)d_in[8];
    const float* sa_wo  = (const float*)d_in[9];
    const float* sa_bo  = (const float*)d_in[10];
    const float* ca_wq  = (const float*)d_in[11];
    const float* ca_bq  = (const float*)d_in[12];
    const float* ca_wk  = (const float*)d_in[13];
    const float* ca_bk  = (const float*)d_in[14];
    const float* ca_wv  = (const float*)d_in[15];
    const float* ca_bv  = (const float*)d_in[16];
    const float* ca_wo  = (const float*)d_in[17];
    const float* ca_bo  = (const float*)d_in[18];
    const float* ffn_w1 = (const float*)d_in[19];
    const float* ffn_b1 = (const float*)d_in[20];
    const float* ffn_w2 = (const float*)d_in[21];
    const float* ffn_b2 = (const float*)d_in[22];
    const float* ln1_g  = (const float*)d_in[23];
    const float* ln1_b  = (const float*)d_in[24];
    const float* ln2_g  = (const float*)d_in[25];
    const float* ln2_b  = (const float*)d_in[26];
    const float* ln3_g  = (const float*)d_in[27];
    const float* ln3_b  = (const float*)d_in[28];

    float* out = (float*)d_out;
    u16* wsb = (u16*)d_ws;
    const size_t M1 = 1024 * 1024;

    // weights (bf16, transposed [N][K]): 16M elems = 32 MB
    u16* Wsq = wsb + 0 * M1;
    u16* Wsk = wsb + 1 * M1;
    u16* Wsv = wsb + 2 * M1;
    u16* Wso = wsb + 3 * M1;
    u16* Wcq = wsb + 4 * M1;
    u16* Wck = wsb + 5 * M1;
    u16* Wcv = wsb + 6 * M1;
    u16* Wco = wsb + 7 * M1;
    u16* Wf1 = wsb + 8 * M1;    // [4096][1024]
    u16* Wf2 = wsb + 12 * M1;   // [1024][4096]

    // activation slots (bf16, 4M elems each): 6 slots = 48 MB
    u16* sl = wsb + 16 * M1;
    u16* s0 = sl + 0 * 4 * M1;
    u16* s1 = sl + 4 * M1;
    u16* s2 = sl + 8 * M1;
    u16* s3 = sl + 12 * M1;
    u16* s4 = sl + 16 * M1;
    u16* s5 = sl + 20 * M1;
    u16* H  = s0;               // FFN hidden [4096][4096] aliases s0..s3 (dead)

    const dim3 blk(256);
    const dim3 gw11(16, 16);
    const dim3 g1(8, 32);       // N=1024 GEMM
    const dim3 g4(32, 32);      // N=4096 GEMM (FFN1)
    const dim3 ga(64, 16);      // attention
    const dim3 gln(4096);

    // weight conversion + transpose
    trw_kernel<<<gw11, blk, 0, stream>>>(sa_wq, Wsq, 1024, 1024);
    trw_kernel<<<gw11, blk, 0, stream>>>(sa_wk, Wsk, 1024, 1024);
    trw_kernel<<<gw11, blk, 0, stream>>>(sa_wv, Wsv, 1024, 1024);
    trw_kernel<<<gw11, blk, 0, stream>>>(sa_wo, Wso, 1024, 1024);
    trw_kernel<<<gw11, blk, 0, stream>>>(ca_wq, Wcq, 1024, 1024);
    trw_kernel<<<gw11, blk, 0, stream>>>(ca_wk, Wck, 1024, 1024);
    trw_kernel<<<gw11, blk, 0, stream>>>(ca_wv, Wcv, 1024, 1024);
    trw_kernel<<<gw11, blk, 0, stream>>>(ca_wo, Wco, 1024, 1024);
    trw_kernel<<<dim3(64, 16), blk, 0, stream>>>(ffn_w1, Wf1, 1024, 4096);
    trw_kernel<<<dim3(16, 64), blk, 0, stream>>>(ffn_w2, Wf2, 4096, 1024);

    // activation conversion
    cvt_kernel<<<2048, blk, 0, stream>>>(tgt, s0, 1024 * 1024);
    cvt_kernel<<<2048, blk, 0, stream>>>(mem, s1, 1024 * 1024);

    // ---- self-attention ----
    gemm_mfma<0><<<g1, blk, 0, stream>>>(s0, Wsq, sa_bq, nullptr, s2, 1024, 1024);
    gemm_mfma<0><<<g1, blk, 0, stream>>>(s0, Wsk, sa_bk, nullptr, s3, 1024, 1024);
    gemm_mfma<4><<<g1, blk, 0, stream>>>(s0, Wsv, sa_bv, nullptr, s4, 1024, 1024);  // s4 = Vt
    fattn_mfma<1><<<ga, blk, 0, stream>>>(s2, s3, s4, s5);
    gemm_mfma<2><<<g1, blk, 0, stream>>>(s5, Wso, sa_bo, s0, s2, 1024, 1024);
    ln_bf16_kernel<<<gln, blk, 0, stream>>>(s2, ln1_g, ln1_b, s3);     // x1 = s3

    // ---- cross-attention ----
    gemm_mfma<0><<<g1, blk, 0, stream>>>(s3, Wcq, ca_bq, nullptr, s2, 1024, 1024);
    gemm_mfma<0><<<g1, blk, 0, stream>>>(s1, Wck, ca_bk, nullptr, s4, 1024, 1024);
    gemm_mfma<4><<<g1, blk, 0, stream>>>(s1, Wcv, ca_bv, nullptr, s5, 1024, 1024);  // s5 = Vt
    fattn_mfma<0><<<ga, blk, 0, stream>>>(s2, s4, s5, s0);
    gemm_mfma<2><<<g1, blk, 0, stream>>>(s0, Wco, ca_bo, s3, s2, 1024, 1024);
    ln_bf16_kernel<<<gln, blk, 0, stream>>>(s2, ln2_g, ln2_b, s4);     // x2 = s4

    // ---- FFN ----
    gemm_mfma<1><<<g4, blk, 0, stream>>>(s4, Wf1, ffn_b1, nullptr, H, 4096, 1024);
    gemm_mfma<3><<<g1, blk, 0, stream>>>(H, Wf2, ffn_b2, s4, out, 1024, 4096);
    ln_kernel<<<gln, blk, 0, stream>>>(out, ln3_g, ln3_b, out);
}

// Round 5
// 467.022 us; speedup vs baseline: 17.8619x; 1.1140x over previous
//
#include <hip/hip_runtime.h>
#include <hip/hip_bf16.h>

typedef unsigned short u16;
typedef __attribute__((ext_vector_type(8))) short bf16x8;
typedef __attribute__((ext_vector_type(4))) float floatx4;

__device__ inline float u2f(unsigned u) { union { unsigned i; float f; } x; x.i = u; return x.f; }
__device__ inline float bflo(unsigned p) { return u2f(p << 16); }
__device__ inline float bfhi(unsigned p) { return u2f(p & 0xffff0000u); }
__device__ inline u16 f2bf(float f) {
    union { __hip_bfloat16 h; u16 u; } x;
    x.h = __float2bfloat16(f);
    return x.u;
}

#define GLDS(g, l) __builtin_amdgcn_global_load_lds( \
    (const __attribute__((address_space(1))) void*)(g), \
    (__attribute__((address_space(3))) void*)(l), 16, 0, 0)

// ---------------------------------------------------------------------------
// bf16 MFMA GEMM: C[M,N] = A[M,K] @ Bt[N,K]^T + bias (+res) (+relu)
// 128x128 tile, 4 waves (2x2), 16x16x32 MFMA, BK=32, XCD-chunked swizzle.
// EPI: 0 = bf16 out, 1 = bf16 out + relu, 2 = bf16 out + bf16 res,
//      3 = f32 out + bf16 res,
//      5 = segmented QKV (seg0->Cv plain, seg1->o1 plain, seg2->o2 Vt),
//      6 = segmented KV  (seg0->Cv plain, seg1->o1 Vt)
// Segmented outputs have row stride 1024 (per-segment); Vt layout:
// Vt[b*16+h][d][t] with t fast (b = token>>10, h = segcol>>6, d = segcol&63).
// ---------------------------------------------------------------------------
template<int EPI>
__global__ __launch_bounds__(256) void gemm_mfma(
        const u16* __restrict__ A, const u16* __restrict__ Bt,
        const float* __restrict__ bias, const u16* __restrict__ res,
        void* __restrict__ Cv, u16* __restrict__ o1, u16* __restrict__ o2,
        int N, int K)
{
    __shared__ u16 Als[128 * 32];
    __shared__ u16 Bls[128 * 32];

    const int tid = threadIdx.x;
    const int lane = tid & 63, wv = tid >> 6;
    const int wr = wv >> 1, wc = wv & 1;

    // XCD-chunked bijective swizzle (all grids have nwg % 8 == 0):
    // HW assigns block i -> XCD i%8; give each XCD a contiguous tile chunk.
    const int gx = gridDim.x;
    const int nwg = gx * gridDim.y;
    const int bid0 = blockIdx.y * gx + blockIdx.x;
    const int nbid = (bid0 & 7) * (nwg >> 3) + (bid0 >> 3);
    const int bx = nbid % gx, by = nbid / gx;
    const int row0 = by * 128, col0 = bx * 128;

    // staging: linear LDS dest, inverse-swizzled global source (16B/lane x2)
    const u16* pa[2];
    const u16* pb[2];
    int ldst[2];
    #pragma unroll
    for (int i = 0; i < 2; ++i) {
        const int idx = i * 256 + tid;               // 0..511
        const int r = idx >> 2;                      // tile row 0..127
        const int kob = (idx & 3) << 4;              // byte off in 64B row
        const int sw = kob ^ (((r >> 1) & 3) << 4);  // swizzled byte off
        pa[i] = A  + (size_t)(row0 + r) * K + (sw >> 1);
        pb[i] = Bt + (size_t)(col0 + r) * K + (sw >> 1);
        ldst[i] = idx * 8;                           // u16 elements
    }

    // fragment read offsets (swizzled)
    int offa[4], offb[4];
    const int rsel = lane & 15, slot = lane >> 4;
    #pragma unroll
    for (int m = 0; m < 4; ++m) {
        const int ra = wr * 64 + m * 16 + rsel;
        offa[m] = ra * 32 + (((slot << 4) ^ (((ra >> 1) & 3) << 4)) >> 1);
        const int rb = wc * 64 + m * 16 + rsel;
        offb[m] = rb * 32 + (((slot << 4) ^ (((rb >> 1) & 3) << 4)) >> 1);
    }

    floatx4 acc[4][4] = {};

    for (int kt = 0; kt < K; kt += 32) {
        __syncthreads();
        #pragma unroll
        for (int i = 0; i < 2; ++i) {
            GLDS(pa[i] + kt, &Als[ldst[i]]);
            GLDS(pb[i] + kt, &Bls[ldst[i]]);
        }
        __syncthreads();

        bf16x8 af[4], bfr[4];
        #pragma unroll
        for (int m = 0; m < 4; ++m) af[m] = *(const bf16x8*)&Als[offa[m]];
        #pragma unroll
        for (int n = 0; n < 4; ++n) bfr[n] = *(const bf16x8*)&Bls[offb[n]];
        #pragma unroll
        for (int m = 0; m < 4; ++m)
            #pragma unroll
            for (int n = 0; n < 4; ++n)
                acc[m][n] = __builtin_amdgcn_mfma_f32_16x16x32_bf16(
                        af[m], bfr[n], acc[m][n], 0, 0, 0);
    }

    // epilogue: C/D layout col=lane&15, row=(lane>>4)*4+reg
    const int cr4 = (lane >> 4) * 4;
    const int cc = lane & 15;

    if (EPI == 5 || EPI == 6) {
        const int seg = col0 >> 10;                  // block-uniform
        const int vtseg = (EPI == 5) ? 2 : 1;
        u16* dst;
        if (EPI == 5) dst = (seg == 0) ? (u16*)Cv : (seg == 1 ? o1 : o2);
        else          dst = (seg == 0) ? (u16*)Cv : o1;

        if (seg == vtseg) {
            #pragma unroll
            for (int n = 0; n < 4; ++n) {
                const int col = col0 + wc * 64 + n * 16 + cc;
                const float bv = bias[col];
                const int vcol = col & 1023;
                const int h = vcol >> 6, d = vcol & 63;
                #pragma unroll
                for (int m = 0; m < 4; ++m) {
                    const int t = row0 + wr * 64 + m * 16 + cr4;
                    const int b = t >> 10;
                    ushort4 o4;
                    o4.x = f2bf(acc[m][n][0] + bv);
                    o4.y = f2bf(acc[m][n][1] + bv);
                    o4.z = f2bf(acc[m][n][2] + bv);
                    o4.w = f2bf(acc[m][n][3] + bv);
                    *(ushort4*)(dst +
                        (((size_t)(b * 16 + h) * 64 + d) * 1024 + (t & 1023))) = o4;
                }
            }
        } else {
            #pragma unroll
            for (int n = 0; n < 4; ++n) {
                const int col = col0 + wc * 64 + n * 16 + cc;
                const float bv = bias[col];
                const int oc = col & 1023;
                #pragma unroll
                for (int m = 0; m < 4; ++m) {
                    const int rowb = row0 + wr * 64 + m * 16 + cr4;
                    #pragma unroll
                    for (int r = 0; r < 4; ++r)
                        dst[(size_t)(rowb + r) * 1024 + oc] = f2bf(acc[m][n][r] + bv);
                }
            }
        }
        return;
    }

    #pragma unroll
    for (int n = 0; n < 4; ++n) {
        const int col = col0 + wc * 64 + n * 16 + cc;
        const float bv = bias[col];
        #pragma unroll
        for (int m = 0; m < 4; ++m) {
            const int rowb = row0 + wr * 64 + m * 16 + cr4;
            #pragma unroll
            for (int r = 0; r < 4; ++r) {
                float v = acc[m][n][r] + bv;
                const size_t o = (size_t)(rowb + r) * N + col;
                if (EPI == 2 || EPI == 3) v += u2f((unsigned)res[o] << 16);
                if (EPI == 1) v = fmaxf(v, 0.f);
                if (EPI == 3) ((float*)Cv)[o] = v;
                else          ((u16*)Cv)[o] = f2bf(v);
            }
        }
    }
}

// ---------------------------------------------------------------------------
// Batched 1024x1024 weight convert+transpose (8 weights, one dispatch).
// W[K=1024,N=1024] f32 -> Wt[N][K] bf16. Grid (16,16,8).
// ---------------------------------------------------------------------------
struct TrwB { const float* w[8]; u16* o[8]; };

__global__ __launch_bounds__(256) void trw8_kernel(TrwB p)
{
    __shared__ float ts[64][65];
    const int tid = threadIdx.x;
    const int n0 = blockIdx.x * 64, k0 = blockIdx.y * 64;
    const float* __restrict__ W = p.w[blockIdx.z];
    u16* __restrict__ Wt = p.o[blockIdx.z];
    const int tr = tid >> 4, tc4 = (tid & 15) * 4;
    #pragma unroll
    for (int i = 0; i < 4; ++i) {
        const float4 v = *(const float4*)(W + (size_t)(k0 + tr + i * 16) * 1024 + n0 + tc4);
        ts[tr + i * 16][tc4 + 0] = v.x;
        ts[tr + i * 16][tc4 + 1] = v.y;
        ts[tr + i * 16][tc4 + 2] = v.z;
        ts[tr + i * 16][tc4 + 3] = v.w;
    }
    __syncthreads();
    #pragma unroll
    for (int i = 0; i < 4; ++i) {
        const int nr = tr + i * 16;
        ushort4 o;
        o.x = f2bf(ts[tc4 + 0][nr]);
        o.y = f2bf(ts[tc4 + 1][nr]);
        o.z = f2bf(ts[tc4 + 2][nr]);
        o.w = f2bf(ts[tc4 + 3][nr]);
        *(ushort4*)(Wt + (size_t)(n0 + nr) * 1024 + k0 + tc4) = o;
    }
}

// generic weight transpose (FFN weights)
__global__ __launch_bounds__(256) void trw_kernel(
        const float* __restrict__ W, u16* __restrict__ Wt, int K, int N)
{
    __shared__ float ts[64][65];
    const int tid = threadIdx.x;
    const int n0 = blockIdx.x * 64, k0 = blockIdx.y * 64;
    const int tr = tid >> 4, tc4 = (tid & 15) * 4;
    #pragma unroll
    for (int i = 0; i < 4; ++i) {
        const float4 v = *(const float4*)(W + (size_t)(k0 + tr + i * 16) * N + n0 + tc4);
        ts[tr + i * 16][tc4 + 0] = v.x;
        ts[tr + i * 16][tc4 + 1] = v.y;
        ts[tr + i * 16][tc4 + 2] = v.z;
        ts[tr + i * 16][tc4 + 3] = v.w;
    }
    __syncthreads();
    #pragma unroll
    for (int i = 0; i < 4; ++i) {
        const int nr = tr + i * 16;
        ushort4 o;
        o.x = f2bf(ts[tc4 + 0][nr]);
        o.y = f2bf(ts[tc4 + 1][nr]);
        o.z = f2bf(ts[tc4 + 2][nr]);
        o.w = f2bf(ts[tc4 + 3][nr]);
        *(ushort4*)(Wt + (size_t)(n0 + nr) * K + k0 + tc4) = o;
    }
}

// fp32 -> bf16 elementwise (n4 = count/4)
__global__ __launch_bounds__(256) void cvt_kernel(
        const float* __restrict__ in, u16* __restrict__ out, int n4)
{
    for (int i = blockIdx.x * 256 + threadIdx.x; i < n4; i += gridDim.x * 256) {
        const float4 v = ((const float4*)in)[i];
        ushort4 o;
        o.x = f2bf(v.x); o.y = f2bf(v.y); o.z = f2bf(v.z); o.w = f2bf(v.w);
        ((ushort4*)out)[i] = o;
    }
}

// concat up to 3 bias vectors of 1024 into one f32 buffer
__global__ __launch_bounds__(256) void bcat_kernel(
        const float* __restrict__ b0, const float* __restrict__ b1,
        const float* __restrict__ b2, float* __restrict__ o, int n)
{
    const int i = blockIdx.x * 256 + threadIdx.x;
    if (i >= n) return;
    const float* s = (i < 1024) ? b0 : (i < 2048 ? b1 : b2);
    o[i] = s[i & 1023];
}

// ---------------------------------------------------------------------------
// MFMA flash attention. Q,K: [4096][1024] bf16 (head h at cols h*64..+64).
// Vt: [b*16+h][64 d][1024 t] bf16. Block = 4 waves, one (b,h) x 64 q-rows.
// Grid (64, 16). LDS tiles 64x64 bf16, byte = r*128 + ((c*2) ^ ((r&7)<<4)).
// ---------------------------------------------------------------------------
template<int CAUSAL>
__global__ __launch_bounds__(256) void fattn_mfma(
        const u16* __restrict__ Q, const u16* __restrict__ K,
        const u16* __restrict__ Vt, u16* __restrict__ O)
{
    __shared__ u16 Qs[64 * 64];
    __shared__ u16 Ks[64 * 64];
    __shared__ u16 Ps[64 * 64];
    __shared__ u16 Vs[64 * 64];

    const int tid = threadIdx.x;
    const int lane = tid & 63, wv = tid >> 6;
    const int bh = blockIdx.x;
    const int b = bh >> 4, h = bh & 15;
    const int qt = blockIdx.y, q0 = qt * 64;

    const size_t qkbase = (size_t)b * (1024 * 1024) + (size_t)h * 64;
    const size_t vtbase = (size_t)bh * 64 * 1024;

    // stage Q (swizzled)
    #pragma unroll
    for (int i = 0; i < 2; ++i) {
        const int idx = i * 256 + tid, r = idx >> 3, s = idx & 7;
        const uint4 v = *(const uint4*)(Q + qkbase + (size_t)(q0 + r) * 1024 + s * 8);
        *(uint4*)((char*)Qs + r * 128 + ((s ^ (r & 7)) << 4)) = v;
    }
    __syncthreads();

    // hoist Q a-frags (each wave owns rows wv*16..+16)
    bf16x8 qf[2];
    #pragma unroll
    for (int ks = 0; ks < 2; ++ks) {
        const int r = wv * 16 + (lane & 15);
        const int slot = ks * 4 + (lane >> 4);
        qf[ks] = *(const bf16x8*)((char*)Qs + r * 128 + ((slot ^ (r & 7)) << 4));
    }

    float m_i[4] = {-1e30f, -1e30f, -1e30f, -1e30f};
    float l_i[4] = {0.f, 0.f, 0.f, 0.f};
    floatx4 o_acc[4] = {};

    const int ktmax = CAUSAL ? qt : 15;
    for (int kt = 0; kt <= ktmax; ++kt) {
        __syncthreads();
        #pragma unroll
        for (int i = 0; i < 2; ++i) {
            const int idx = i * 256 + tid, r = idx >> 3, s = idx & 7;
            const uint4 kv = *(const uint4*)(K + qkbase + (size_t)(kt * 64 + r) * 1024 + s * 8);
            *(uint4*)((char*)Ks + r * 128 + ((s ^ (r & 7)) << 4)) = kv;
            const uint4 vv = *(const uint4*)(Vt + vtbase + (size_t)r * 1024 + kt * 64 + s * 8);
            *(uint4*)((char*)Vs + r * 128 + ((s ^ (r & 7)) << 4)) = vv;
        }
        __syncthreads();

        // S = Q @ K^T
        floatx4 sa[4] = {};
        #pragma unroll
        for (int ks = 0; ks < 2; ++ks) {
            #pragma unroll
            for (int n = 0; n < 4; ++n) {
                const int r = n * 16 + (lane & 15);
                const int slot = ks * 4 + (lane >> 4);
                const bf16x8 bf = *(const bf16x8*)((char*)Ks + r * 128 + ((slot ^ (r & 7)) << 4));
                sa[n] = __builtin_amdgcn_mfma_f32_16x16x32_bf16(qf[ks], bf, sa[n], 0, 0, 0);
            }
        }

        // scale + mask
        float p[4][4];
        #pragma unroll
        for (int n = 0; n < 4; ++n)
            #pragma unroll
            for (int r = 0; r < 4; ++r) {
                float v = sa[n][r] * 0.125f;
                if (CAUSAL && kt == qt) {
                    const int ql = wv * 16 + (lane >> 4) * 4 + r;
                    const int kl = n * 16 + (lane & 15);
                    if (kl > ql) v = -1e30f;
                }
                p[n][r] = v;
            }

        // online softmax
        #pragma unroll
        for (int r = 0; r < 4; ++r) {
            float mx = fmaxf(fmaxf(p[0][r], p[1][r]), fmaxf(p[2][r], p[3][r]));
            mx = fmaxf(mx, __shfl_xor(mx, 1));
            mx = fmaxf(mx, __shfl_xor(mx, 2));
            mx = fmaxf(mx, __shfl_xor(mx, 4));
            mx = fmaxf(mx, __shfl_xor(mx, 8));
            const float mn = fmaxf(m_i[r], mx);
            const float al = __expf(m_i[r] - mn);
            m_i[r] = mn;
            float rs = 0.f;
            #pragma unroll
            for (int n = 0; n < 4; ++n) { p[n][r] = __expf(p[n][r] - mn); rs += p[n][r]; }
            rs += __shfl_xor(rs, 1);
            rs += __shfl_xor(rs, 2);
            rs += __shfl_xor(rs, 4);
            rs += __shfl_xor(rs, 8);
            l_i[r] = l_i[r] * al + rs;
            o_acc[0][r] *= al; o_acc[1][r] *= al;
            o_acc[2][r] *= al; o_acc[3][r] *= al;
        }

        // write P to own wave's LDS rows (same-wave RAW, no barrier)
        #pragma unroll
        for (int n = 0; n < 4; ++n)
            #pragma unroll
            for (int r = 0; r < 4; ++r) {
                const int qr = wv * 16 + (lane >> 4) * 4 + r;
                const int k2 = (n * 16 + (lane & 15)) * 2;
                *(u16*)((char*)Ps + qr * 128 + (k2 ^ ((qr & 7) << 4))) = f2bf(p[n][r]);
            }

        // O += P @ V
        #pragma unroll
        for (int ks = 0; ks < 2; ++ks) {
            const int ra = wv * 16 + (lane & 15);
            const int slot = ks * 4 + (lane >> 4);
            const bf16x8 af = *(const bf16x8*)((char*)Ps + ra * 128 + ((slot ^ (ra & 7)) << 4));
            #pragma unroll
            for (int n = 0; n < 4; ++n) {
                const int rv = n * 16 + (lane & 15);
                const bf16x8 bf = *(const bf16x8*)((char*)Vs + rv * 128 + ((slot ^ (rv & 7)) << 4));
                o_acc[n] = __builtin_amdgcn_mfma_f32_16x16x32_bf16(af, bf, o_acc[n], 0, 0, 0);
            }
        }
    }

    #pragma unroll
    for (int r = 0; r < 4; ++r) {
        const float inv = 1.f / l_i[r];
        const int qg = q0 + wv * 16 + (lane >> 4) * 4 + r;
        #pragma unroll
        for (int n = 0; n < 4; ++n) {
            const int d = n * 16 + (lane & 15);
            O[qkbase + (size_t)qg * 1024 + d] = f2bf(o_acc[n][r] * inv);
        }
    }
}

// ---------------------------------------------------------------------------
// LayerNorm, bf16 in/out, fp32 stats. One block (256) per row of 1024.
// ---------------------------------------------------------------------------
__global__ __launch_bounds__(256) void ln_bf16_kernel(
        const u16* __restrict__ X, const float* __restrict__ g,
        const float* __restrict__ bta, u16* __restrict__ Y)
{
    __shared__ float red[4];
    const int row = blockIdx.x, tid = threadIdx.x;
    const int wave = tid >> 6, lane = tid & 63;

    const uint2 u = *(const uint2*)(X + (size_t)row * 1024 + tid * 4);
    const float x0 = bflo(u.x), x1 = bfhi(u.x), x2 = bflo(u.y), x3 = bfhi(u.y);

    float s = x0 + x1 + x2 + x3;
    #pragma unroll
    for (int off = 32; off; off >>= 1) s += __shfl_xor(s, off);
    if (lane == 0) red[wave] = s;
    __syncthreads();
    const float mu = (red[0] + red[1] + red[2] + red[3]) * (1.f / 1024.f);
    __syncthreads();

    const float d0 = x0 - mu, d1 = x1 - mu, d2 = x2 - mu, d3 = x3 - mu;
    float s2 = d0 * d0 + d1 * d1 + d2 * d2 + d3 * d3;
    #pragma unroll
    for (int off = 32; off; off >>= 1) s2 += __shfl_xor(s2, off);
    if (lane == 0) red[wave] = s2;
    __syncthreads();
    const float var = (red[0] + red[1] + red[2] + red[3]) * (1.f / 1024.f);
    const float rs = rsqrtf(var + 1e-5f);

    const float4 gg = ((const float4*)g)[tid];
    const float4 bb = ((const float4*)bta)[tid];
    ushort4 o;
    o.x = f2bf(d0 * rs * gg.x + bb.x);
    o.y = f2bf(d1 * rs * gg.y + bb.y);
    o.z = f2bf(d2 * rs * gg.z + bb.z);
    o.w = f2bf(d3 * rs * gg.w + bb.w);
    *(ushort4*)(Y + (size_t)row * 1024 + tid * 4) = o;
}

// fp32 in-place LayerNorm (final output)
__global__ __launch_bounds__(256) void ln_kernel(
        const float* X, const float* __restrict__ g,
        const float* __restrict__ bta, float* Y)
{
    __shared__ float red[4];
    const int row = blockIdx.x;
    const int tid = threadIdx.x;
    const int wave = tid >> 6, lane = tid & 63;

    const float4 v = ((const float4*)(X + (size_t)row * 1024))[tid];

    float s = v.x + v.y + v.z + v.w;
    #pragma unroll
    for (int off = 32; off; off >>= 1) s += __shfl_xor(s, off);
    if (lane == 0) red[wave] = s;
    __syncthreads();
    const float mu = (red[0] + red[1] + red[2] + red[3]) * (1.f / 1024.f);
    __syncthreads();

    const float dx = v.x - mu, dy = v.y - mu, dz = v.z - mu, dw = v.w - mu;
    float s2 = dx * dx + dy * dy + dz * dz + dw * dw;
    #pragma unroll
    for (int off = 32; off; off >>= 1) s2 += __shfl_xor(s2, off);
    if (lane == 0) red[wave] = s2;
    __syncthreads();
    const float var = (red[0] + red[1] + red[2] + red[3]) * (1.f / 1024.f);
    const float rs = rsqrtf(var + 1e-5f);

    const float4 gg = ((const float4*)g)[tid];
    const float4 bb = ((const float4*)bta)[tid];
    float4 o;
    o.x = dx * rs * gg.x + bb.x;
    o.y = dy * rs * gg.y + bb.y;
    o.z = dz * rs * gg.z + bb.z;
    o.w = dw * rs * gg.w + bb.w;
    ((float4*)(Y + (size_t)row * 1024))[tid] = o;
}

// ---------------------------------------------------------------------------
extern "C" void kernel_launch(void* const* d_in, const int* in_sizes, int n_in,
                              void* d_out, int out_size, void* d_ws, size_t ws_size,
                              hipStream_t stream)
{
    const float* tgt    = (const float*)d_in[0];
    const float* mem    = (const float*)d_in[1];
    const float* sa_wq  = (const float*)d_in[3];
    const float* sa_bq  = (const float*)d_in[4];
    const float* sa_wk  = (const float*)d_in[5];
    const float* sa_bk  = (const float*)d_in[6];
    const float* sa_wv  = (const float*)d_in[7];
    const float* sa_bv  = (const float*)d_in[8];
    const float* sa_wo  = (const float*)d_in[9];
    const float* sa_bo  = (const float*)d_in[10];
    const float* ca_wq  = (const float*)d_in[11];
    const float* ca_bq  = (const float*)d_in[12];
    const float* ca_wk  = (const float*)d_in[13];
    const float* ca_bk  = (const float*)d_in[14];
    const float* ca_wv  = (const float*)d_in[15];
    const float* ca_bv  = (const float*)d_in[16];
    const float* ca_wo  = (const float*)d_in[17];
    const float* ca_bo  = (const float*)d_in[18];
    const float* ffn_w1 = (const float*)d_in[19];
    const float* ffn_b1 = (const float*)d_in[20];
    const float* ffn_w2 = (const float*)d_in[21];
    const float* ffn_b2 = (const float*)d_in[22];
    const float* ln1_g  = (const float*)d_in[23];
    const float* ln1_b  = (const float*)d_in[24];
    const float* ln2_g  = (const float*)d_in[25];
    const float* ln2_b  = (const float*)d_in[26];
    const float* ln3_g  = (const float*)d_in[27];
    const float* ln3_b  = (const float*)d_in[28];

    float* out = (float*)d_out;
    u16* wsb = (u16*)d_ws;
    const size_t M1 = 1024 * 1024;

    // weights (bf16, transposed [N][K]): 32 MB.
    // sa q/k/v contiguous (fused QKV Bt); ca k/v contiguous (fused KV Bt).
    u16* Wsq = wsb + 0 * M1;
    u16* Wsk = wsb + 1 * M1;
    u16* Wsv = wsb + 2 * M1;
    u16* Wso = wsb + 3 * M1;
    u16* Wcq = wsb + 4 * M1;
    u16* Wck = wsb + 5 * M1;
    u16* Wcv = wsb + 6 * M1;
    u16* Wco = wsb + 7 * M1;
    u16* Wf1 = wsb + 8 * M1;    // [4096][1024]
    u16* Wf2 = wsb + 12 * M1;   // [1024][4096]

    // activation slots (bf16, 4M elems each): 48 MB
    u16* sl = wsb + 16 * M1;
    u16* s0 = sl + 0 * 4 * M1;
    u16* s1 = sl + 4 * M1;
    u16* s2 = sl + 8 * M1;
    u16* s3 = sl + 12 * M1;
    u16* s4 = sl + 16 * M1;
    u16* s5 = sl + 20 * M1;
    u16* H  = s0;               // FFN hidden [4096][4096] aliases s0..s3 (dead)

    // f32 bias concat buffers (after slots; +20 KB)
    float* biasQKV = (float*)(wsb + 40 * M1);   // [3072]
    float* biasKV  = biasQKV + 3072;            // [2048]

    const dim3 blk(256);
    const dim3 gqkv(24, 32);    // N=3072 fused QKV
    const dim3 gkv(16, 32);     // N=2048 fused KV
    const dim3 g1(8, 32);       // N=1024 GEMM
    const dim3 g4(32, 32);      // N=4096 GEMM (FFN1)
    const dim3 ga(64, 16);      // attention
    const dim3 gln(4096);

    // ---- weight/bias prep ----
    TrwB tb;
    tb.w[0] = sa_wq; tb.o[0] = Wsq;
    tb.w[1] = sa_wk; tb.o[1] = Wsk;
    tb.w[2] = sa_wv; tb.o[2] = Wsv;
    tb.w[3] = sa_wo; tb.o[3] = Wso;
    tb.w[4] = ca_wq; tb.o[4] = Wcq;
    tb.w[5] = ca_wk; tb.o[5] = Wck;
    tb.w[6] = ca_wv; tb.o[6] = Wcv;
    tb.w[7] = ca_wo; tb.o[7] = Wco;
    trw8_kernel<<<dim3(16, 16, 8), blk, 0, stream>>>(tb);
    trw_kernel<<<dim3(64, 16), blk, 0, stream>>>(ffn_w1, Wf1, 1024, 4096);
    trw_kernel<<<dim3(16, 64), blk, 0, stream>>>(ffn_w2, Wf2, 4096, 1024);
    bcat_kernel<<<12, blk, 0, stream>>>(sa_bq, sa_bk, sa_bv, biasQKV, 3072);
    bcat_kernel<<<8, blk, 0, stream>>>(ca_bk, ca_bv, ca_bv, biasKV, 2048);
    cvt_kernel<<<2048, blk, 0, stream>>>(tgt, s0, 1024 * 1024);
    cvt_kernel<<<2048, blk, 0, stream>>>(mem, s1, 1024 * 1024);

    // ---- self-attention ----
    // fused QKV: Q->s2, K->s3, Vt->s4
    gemm_mfma<5><<<gqkv, blk, 0, stream>>>(s0, Wsq, biasQKV, nullptr,
                                           s2, s3, s4, 3072, 1024);
    fattn_mfma<1><<<ga, blk, 0, stream>>>(s2, s3, s4, s5);
    gemm_mfma<2><<<g1, blk, 0, stream>>>(s5, Wso, sa_bo, s0, s2, nullptr, nullptr, 1024, 1024);
    ln_bf16_kernel<<<gln, blk, 0, stream>>>(s2, ln1_g, ln1_b, s3);     // x1 = s3

    // ---- cross-attention ----
    gemm_mfma<0><<<g1, blk, 0, stream>>>(s3, Wcq, ca_bq, nullptr, s2, nullptr, nullptr, 1024, 1024);
    // fused KV from memory: K->s4, Vt->s5
    gemm_mfma<6><<<gkv, blk, 0, stream>>>(s1, Wck, biasKV, nullptr,
                                          s4, s5, nullptr, 2048, 1024);
    fattn_mfma<0><<<ga, blk, 0, stream>>>(s2, s4, s5, s0);
    gemm_mfma<2><<<g1, blk, 0, stream>>>(s0, Wco, ca_bo, s3, s2, nullptr, nullptr, 1024, 1024);
    ln_bf16_kernel<<<gln, blk, 0, stream>>>(s2, ln2_g, ln2_b, s4);     // x2 = s4

    // ---- FFN ----
    gemm_mfma<1><<<g4, blk, 0, stream>>>(s4, Wf1, ffn_b1, nullptr, H, nullptr, nullptr, 4096, 1024);
    gemm_mfma<3><<<g1, blk, 0, stream>>>(H, Wf2, ffn_b2, s4, out, nullptr, nullptr, 1024, 4096);
    ln_kernel<<<gln, blk, 0, stream>>>(out, ln3_g, ln3_b, out);
}

// Round 6
// 412.005 us; speedup vs baseline: 20.2471x; 1.1335x over previous
//
#include <hip/hip_runtime.h>
#include <hip/hip_bf16.h>

typedef unsigned short u16;
typedef __attribute__((ext_vector_type(8))) short bf16x8;
typedef __attribute__((ext_vector_type(4))) float floatx4;

__device__ inline float u2f(unsigned u) { union { unsigned i; float f; } x; x.i = u; return x.f; }
__device__ inline float bflo(unsigned p) { return u2f(p << 16); }
__device__ inline float bfhi(unsigned p) { return u2f(p & 0xffff0000u); }
__device__ inline u16 f2bf(float f) {
    union { __hip_bfloat16 h; u16 u; } x;
    x.h = __float2bfloat16(f);
    return x.u;
}

#define GLDS(g, l) __builtin_amdgcn_global_load_lds( \
    (const __attribute__((address_space(1))) void*)(g), \
    (__attribute__((address_space(3))) void*)(l), 16, 0, 0)

// ---------------------------------------------------------------------------
// bf16 MFMA GEMM: C[M,N] = A[M,K] @ Bt[N,K]^T + bias (+res) (+relu)
// 128x128 tile, 4 waves (2x2), 16x16x32 MFMA, BK=32, XCD-chunked swizzle.
// 2-phase double-buffered K-loop: stage tile t+1 (global_load_lds, async)
// BEFORE computing tile t; the trailing __syncthreads' vmcnt(0) drain then
// lands AFTER the MFMAs, hiding HBM latency even at 1 block/CU.
// EPI: 0 = bf16 out, 1 = bf16 out + relu, 2 = bf16 out + bf16 res,
//      3 = f32 out + bf16 res,
//      5 = segmented QKV (seg0->Cv plain, seg1->o1 plain, seg2->o2 Vt),
//      6 = segmented KV  (seg0->Cv plain, seg1->o1 Vt)
// Vt layout: Vt[b*16+h][d][t], t fast.
// ---------------------------------------------------------------------------
template<int EPI>
__global__ __launch_bounds__(256) void gemm_mfma(
        const u16* __restrict__ A, const u16* __restrict__ Bt,
        const float* __restrict__ bias, const u16* __restrict__ res,
        void* __restrict__ Cv, u16* __restrict__ o1, u16* __restrict__ o2,
        int N, int K)
{
    __shared__ u16 As0[128 * 32];
    __shared__ u16 Bs0[128 * 32];
    __shared__ u16 As1[128 * 32];
    __shared__ u16 Bs1[128 * 32];

    const int tid = threadIdx.x;
    const int lane = tid & 63, wv = tid >> 6;
    const int wr = wv >> 1, wc = wv & 1;

    // XCD-chunked bijective swizzle (all grids have nwg % 8 == 0)
    const int gx = gridDim.x;
    const int nwg = gx * gridDim.y;
    const int bid0 = blockIdx.y * gx + blockIdx.x;
    const int nbid = (bid0 & 7) * (nwg >> 3) + (bid0 >> 3);
    const int bx = nbid % gx, by = nbid / gx;
    const int row0 = by * 128, col0 = bx * 128;

    // staging: linear LDS dest, inverse-swizzled global source (16B/lane x2)
    const u16* pa[2];
    const u16* pb[2];
    int ldst[2];
    #pragma unroll
    for (int i = 0; i < 2; ++i) {
        const int idx = i * 256 + tid;               // 0..511
        const int r = idx >> 2;                      // tile row 0..127
        const int kob = (idx & 3) << 4;              // byte off in 64B row
        const int sw = kob ^ (((r >> 1) & 3) << 4);  // swizzled byte off
        pa[i] = A  + (size_t)(row0 + r) * K + (sw >> 1);
        pb[i] = Bt + (size_t)(col0 + r) * K + (sw >> 1);
        ldst[i] = idx * 8;                           // u16 elements
    }

    // fragment read offsets (swizzled)
    int offa[4], offb[4];
    const int rsel = lane & 15, slot = lane >> 4;
    #pragma unroll
    for (int m = 0; m < 4; ++m) {
        const int ra = wr * 64 + m * 16 + rsel;
        offa[m] = ra * 32 + (((slot << 4) ^ (((ra >> 1) & 3) << 4)) >> 1);
        const int rb = wc * 64 + m * 16 + rsel;
        offb[m] = rb * 32 + (((slot << 4) ^ (((rb >> 1) & 3) << 4)) >> 1);
    }

    floatx4 acc[4][4] = {};

#define STAGE(AA, BB, t) do {                                   \
        const int ko_ = (t) << 5;                               \
        GLDS(pa[0] + ko_, &AA[ldst[0]]);                        \
        GLDS(pb[0] + ko_, &BB[ldst[0]]);                        \
        GLDS(pa[1] + ko_, &AA[ldst[1]]);                        \
        GLDS(pb[1] + ko_, &BB[ldst[1]]);                        \
    } while (0)

#define COMPUTE(AA, BB) do {                                    \
        bf16x8 af[4], bfr[4];                                   \
        _Pragma("unroll")                                       \
        for (int m = 0; m < 4; ++m) af[m] = *(const bf16x8*)&AA[offa[m]]; \
        _Pragma("unroll")                                       \
        for (int n = 0; n < 4; ++n) bfr[n] = *(const bf16x8*)&BB[offb[n]]; \
        _Pragma("unroll")                                       \
        for (int m = 0; m < 4; ++m)                             \
            _Pragma("unroll")                                   \
            for (int n = 0; n < 4; ++n)                         \
                acc[m][n] = __builtin_amdgcn_mfma_f32_16x16x32_bf16( \
                        af[m], bfr[n], acc[m][n], 0, 0, 0);     \
    } while (0)

    const int nkt = K >> 5;          // always even (K = 1024 or 4096)
    STAGE(As0, Bs0, 0);
    __syncthreads();                 // buf0 ready
    for (int t = 0; t < nkt; t += 2) {
        STAGE(As1, Bs1, t + 1);      // async: in flight during compute
        COMPUTE(As0, Bs0);
        __syncthreads();             // drain t+1 loads + sync reads of buf0
        if (t + 2 < nkt) STAGE(As0, Bs0, t + 2);
        COMPUTE(As1, Bs1);
        __syncthreads();
    }
#undef STAGE
#undef COMPUTE

    // epilogue: C/D layout col=lane&15, row=(lane>>4)*4+reg
    const int cr4 = (lane >> 4) * 4;
    const int cc = lane & 15;

    if (EPI == 5 || EPI == 6) {
        const int seg = col0 >> 10;                  // block-uniform
        const int vtseg = (EPI == 5) ? 2 : 1;
        u16* dst;
        if (EPI == 5) dst = (seg == 0) ? (u16*)Cv : (seg == 1 ? o1 : o2);
        else          dst = (seg == 0) ? (u16*)Cv : o1;

        if (seg == vtseg) {
            #pragma unroll
            for (int n = 0; n < 4; ++n) {
                const int col = col0 + wc * 64 + n * 16 + cc;
                const float bv = bias[col];
                const int vcol = col & 1023;
                const int h = vcol >> 6, d = vcol & 63;
                #pragma unroll
                for (int m = 0; m < 4; ++m) {
                    const int t = row0 + wr * 64 + m * 16 + cr4;
                    const int b = t >> 10;
                    ushort4 o4;
                    o4.x = f2bf(acc[m][n][0] + bv);
                    o4.y = f2bf(acc[m][n][1] + bv);
                    o4.z = f2bf(acc[m][n][2] + bv);
                    o4.w = f2bf(acc[m][n][3] + bv);
                    *(ushort4*)(dst +
                        (((size_t)(b * 16 + h) * 64 + d) * 1024 + (t & 1023))) = o4;
                }
            }
        } else {
            #pragma unroll
            for (int n = 0; n < 4; ++n) {
                const int col = col0 + wc * 64 + n * 16 + cc;
                const float bv = bias[col];
                const int oc = col & 1023;
                #pragma unroll
                for (int m = 0; m < 4; ++m) {
                    const int rowb = row0 + wr * 64 + m * 16 + cr4;
                    #pragma unroll
                    for (int r = 0; r < 4; ++r)
                        dst[(size_t)(rowb + r) * 1024 + oc] = f2bf(acc[m][n][r] + bv);
                }
            }
        }
        return;
    }

    #pragma unroll
    for (int n = 0; n < 4; ++n) {
        const int col = col0 + wc * 64 + n * 16 + cc;
        const float bv = bias[col];
        #pragma unroll
        for (int m = 0; m < 4; ++m) {
            const int rowb = row0 + wr * 64 + m * 16 + cr4;
            #pragma unroll
            for (int r = 0; r < 4; ++r) {
                float v = acc[m][n][r] + bv;
                const size_t o = (size_t)(rowb + r) * N + col;
                if (EPI == 2 || EPI == 3) v += u2f((unsigned)res[o] << 16);
                if (EPI == 1) v = fmaxf(v, 0.f);
                if (EPI == 3) ((float*)Cv)[o] = v;
                else          ((u16*)Cv)[o] = f2bf(v);
            }
        }
    }
}

// ---------------------------------------------------------------------------
// Batched 1024x1024 weight convert+transpose (8 weights, one dispatch).
// ---------------------------------------------------------------------------
struct TrwB { const float* w[8]; u16* o[8]; };

__global__ __launch_bounds__(256) void trw8_kernel(TrwB p)
{
    __shared__ float ts[64][65];
    const int tid = threadIdx.x;
    const int n0 = blockIdx.x * 64, k0 = blockIdx.y * 64;
    const float* __restrict__ W = p.w[blockIdx.z];
    u16* __restrict__ Wt = p.o[blockIdx.z];
    const int tr = tid >> 4, tc4 = (tid & 15) * 4;
    #pragma unroll
    for (int i = 0; i < 4; ++i) {
        const float4 v = *(const float4*)(W + (size_t)(k0 + tr + i * 16) * 1024 + n0 + tc4);
        ts[tr + i * 16][tc4 + 0] = v.x;
        ts[tr + i * 16][tc4 + 1] = v.y;
        ts[tr + i * 16][tc4 + 2] = v.z;
        ts[tr + i * 16][tc4 + 3] = v.w;
    }
    __syncthreads();
    #pragma unroll
    for (int i = 0; i < 4; ++i) {
        const int nr = tr + i * 16;
        ushort4 o;
        o.x = f2bf(ts[tc4 + 0][nr]);
        o.y = f2bf(ts[tc4 + 1][nr]);
        o.z = f2bf(ts[tc4 + 2][nr]);
        o.w = f2bf(ts[tc4 + 3][nr]);
        *(ushort4*)(Wt + (size_t)(n0 + nr) * 1024 + k0 + tc4) = o;
    }
}

// generic weight transpose (FFN weights)
__global__ __launch_bounds__(256) void trw_kernel(
        const float* __restrict__ W, u16* __restrict__ Wt, int K, int N)
{
    __shared__ float ts[64][65];
    const int tid = threadIdx.x;
    const int n0 = blockIdx.x * 64, k0 = blockIdx.y * 64;
    const int tr = tid >> 4, tc4 = (tid & 15) * 4;
    #pragma unroll
    for (int i = 0; i < 4; ++i) {
        const float4 v = *(const float4*)(W + (size_t)(k0 + tr + i * 16) * N + n0 + tc4);
        ts[tr + i * 16][tc4 + 0] = v.x;
        ts[tr + i * 16][tc4 + 1] = v.y;
        ts[tr + i * 16][tc4 + 2] = v.z;
        ts[tr + i * 16][tc4 + 3] = v.w;
    }
    __syncthreads();
    #pragma unroll
    for (int i = 0; i < 4; ++i) {
        const int nr = tr + i * 16;
        ushort4 o;
        o.x = f2bf(ts[tc4 + 0][nr]);
        o.y = f2bf(ts[tc4 + 1][nr]);
        o.z = f2bf(ts[tc4 + 2][nr]);
        o.w = f2bf(ts[tc4 + 3][nr]);
        *(ushort4*)(Wt + (size_t)(n0 + nr) * K + k0 + tc4) = o;
    }
}

// fp32 -> bf16 elementwise (n4 = count/4)
__global__ __launch_bounds__(256) void cvt_kernel(
        const float* __restrict__ in, u16* __restrict__ out, int n4)
{
    for (int i = blockIdx.x * 256 + threadIdx.x; i < n4; i += gridDim.x * 256) {
        const float4 v = ((const float4*)in)[i];
        ushort4 o;
        o.x = f2bf(v.x); o.y = f2bf(v.y); o.z = f2bf(v.z); o.w = f2bf(v.w);
        ((ushort4*)out)[i] = o;
    }
}

// concat up to 3 bias vectors of 1024 into one f32 buffer
__global__ __launch_bounds__(256) void bcat_kernel(
        const float* __restrict__ b0, const float* __restrict__ b1,
        const float* __restrict__ b2, float* __restrict__ o, int n)
{
    const int i = blockIdx.x * 256 + threadIdx.x;
    if (i >= n) return;
    const float* s = (i < 1024) ? b0 : (i < 2048 ? b1 : b2);
    o[i] = s[i & 1023];
}

// ---------------------------------------------------------------------------
// MFMA flash attention. Q,K: [4096][1024] bf16 (head h at cols h*64..+64).
// Vt: [b*16+h][64 d][1024 t] bf16. Block = 4 waves, one (b,h) x 64 q-rows.
// Grid (64, 16). LDS tiles 64x64 bf16, byte = r*128 + ((c*2) ^ ((r&7)<<4)).
// ---------------------------------------------------------------------------
template<int CAUSAL>
__global__ __launch_bounds__(256) void fattn_mfma(
        const u16* __restrict__ Q, const u16* __restrict__ K,
        const u16* __restrict__ Vt, u16* __restrict__ O)
{
    __shared__ u16 Qs[64 * 64];
    __shared__ u16 Ks[64 * 64];
    __shared__ u16 Ps[64 * 64];
    __shared__ u16 Vs[64 * 64];

    const int tid = threadIdx.x;
    const int lane = tid & 63, wv = tid >> 6;
    const int bh = blockIdx.x;
    const int b = bh >> 4, h = bh & 15;
    const int qt = blockIdx.y, q0 = qt * 64;

    const size_t qkbase = (size_t)b * (1024 * 1024) + (size_t)h * 64;
    const size_t vtbase = (size_t)bh * 64 * 1024;

    // stage Q (swizzled)
    #pragma unroll
    for (int i = 0; i < 2; ++i) {
        const int idx = i * 256 + tid, r = idx >> 3, s = idx & 7;
        const uint4 v = *(const uint4*)(Q + qkbase + (size_t)(q0 + r) * 1024 + s * 8);
        *(uint4*)((char*)Qs + r * 128 + ((s ^ (r & 7)) << 4)) = v;
    }
    __syncthreads();

    // hoist Q a-frags (each wave owns rows wv*16..+16)
    bf16x8 qf[2];
    #pragma unroll
    for (int ks = 0; ks < 2; ++ks) {
        const int r = wv * 16 + (lane & 15);
        const int slot = ks * 4 + (lane >> 4);
        qf[ks] = *(const bf16x8*)((char*)Qs + r * 128 + ((slot ^ (r & 7)) << 4));
    }

    float m_i[4] = {-1e30f, -1e30f, -1e30f, -1e30f};
    float l_i[4] = {0.f, 0.f, 0.f, 0.f};
    floatx4 o_acc[4] = {};

    const int ktmax = CAUSAL ? qt : 15;
    for (int kt = 0; kt <= ktmax; ++kt) {
        __syncthreads();
        #pragma unroll
        for (int i = 0; i < 2; ++i) {
            const int idx = i * 256 + tid, r = idx >> 3, s = idx & 7;
            const uint4 kv = *(const uint4*)(K + qkbase + (size_t)(kt * 64 + r) * 1024 + s * 8);
            *(uint4*)((char*)Ks + r * 128 + ((s ^ (r & 7)) << 4)) = kv;
            const uint4 vv = *(const uint4*)(Vt + vtbase + (size_t)r * 1024 + kt * 64 + s * 8);
            *(uint4*)((char*)Vs + r * 128 + ((s ^ (r & 7)) << 4)) = vv;
        }
        __syncthreads();

        // S = Q @ K^T
        floatx4 sa[4] = {};
        #pragma unroll
        for (int ks = 0; ks < 2; ++ks) {
            #pragma unroll
            for (int n = 0; n < 4; ++n) {
                const int r = n * 16 + (lane & 15);
                const int slot = ks * 4 + (lane >> 4);
                const bf16x8 bf = *(const bf16x8*)((char*)Ks + r * 128 + ((slot ^ (r & 7)) << 4));
                sa[n] = __builtin_amdgcn_mfma_f32_16x16x32_bf16(qf[ks], bf, sa[n], 0, 0, 0);
            }
        }

        // scale + mask
        float p[4][4];
        #pragma unroll
        for (int n = 0; n < 4; ++n)
            #pragma unroll
            for (int r = 0; r < 4; ++r) {
                float v = sa[n][r] * 0.125f;
                if (CAUSAL && kt == qt) {
                    const int ql = wv * 16 + (lane >> 4) * 4 + r;
                    const int kl = n * 16 + (lane & 15);
                    if (kl > ql) v = -1e30f;
                }
                p[n][r] = v;
            }

        // online softmax
        #pragma unroll
        for (int r = 0; r < 4; ++r) {
            float mx = fmaxf(fmaxf(p[0][r], p[1][r]), fmaxf(p[2][r], p[3][r]));
            mx = fmaxf(mx, __shfl_xor(mx, 1));
            mx = fmaxf(mx, __shfl_xor(mx, 2));
            mx = fmaxf(mx, __shfl_xor(mx, 4));
            mx = fmaxf(mx, __shfl_xor(mx, 8));
            const float mn = fmaxf(m_i[r], mx);
            const float al = __expf(m_i[r] - mn);
            m_i[r] = mn;
            float rs = 0.f;
            #pragma unroll
            for (int n = 0; n < 4; ++n) { p[n][r] = __expf(p[n][r] - mn); rs += p[n][r]; }
            rs += __shfl_xor(rs, 1);
            rs += __shfl_xor(rs, 2);
            rs += __shfl_xor(rs, 4);
            rs += __shfl_xor(rs, 8);
            l_i[r] = l_i[r] * al + rs;
            o_acc[0][r] *= al; o_acc[1][r] *= al;
            o_acc[2][r] *= al; o_acc[3][r] *= al;
        }

        // write P to own wave's LDS rows (same-wave RAW, no barrier)
        #pragma unroll
        for (int n = 0; n < 4; ++n)
            #pragma unroll
            for (int r = 0; r < 4; ++r) {
                const int qr = wv * 16 + (lane >> 4) * 4 + r;
                const int k2 = (n * 16 + (lane & 15)) * 2;
                *(u16*)((char*)Ps + qr * 128 + (k2 ^ ((qr & 7) << 4))) = f2bf(p[n][r]);
            }

        // O += P @ V
        #pragma unroll
        for (int ks = 0; ks < 2; ++ks) {
            const int ra = wv * 16 + (lane & 15);
            const int slot = ks * 4 + (lane >> 4);
            const bf16x8 af = *(const bf16x8*)((char*)Ps + ra * 128 + ((slot ^ (ra & 7)) << 4));
            #pragma unroll
            for (int n = 0; n < 4; ++n) {
                const int rv = n * 16 + (lane & 15);
                const bf16x8 bf = *(const bf16x8*)((char*)Vs + rv * 128 + ((slot ^ (rv & 7)) << 4));
                o_acc[n] = __builtin_amdgcn_mfma_f32_16x16x32_bf16(af, bf, o_acc[n], 0, 0, 0);
            }
        }
    }

    #pragma unroll
    for (int r = 0; r < 4; ++r) {
        const float inv = 1.f / l_i[r];
        const int qg = q0 + wv * 16 + (lane >> 4) * 4 + r;
        #pragma unroll
        for (int n = 0; n < 4; ++n) {
            const int d = n * 16 + (lane & 15);
            O[qkbase + (size_t)qg * 1024 + d] = f2bf(o_acc[n][r] * inv);
        }
    }
}

// ---------------------------------------------------------------------------
// LayerNorm, bf16 in/out, fp32 stats. One block (256) per row of 1024.
// ---------------------------------------------------------------------------
__global__ __launch_bounds__(256) void ln_bf16_kernel(
        const u16* __restrict__ X, const float* __restrict__ g,
        const float* __restrict__ bta, u16* __restrict__ Y)
{
    __shared__ float red[4];
    const int row = blockIdx.x, tid = threadIdx.x;
    const int wave = tid >> 6, lane = tid & 63;

    const uint2 u = *(const uint2*)(X + (size_t)row * 1024 + tid * 4);
    const float x0 = bflo(u.x), x1 = bfhi(u.x), x2 = bflo(u.y), x3 = bfhi(u.y);

    float s = x0 + x1 + x2 + x3;
    #pragma unroll
    for (int off = 32; off; off >>= 1) s += __shfl_xor(s, off);
    if (lane == 0) red[wave] = s;
    __syncthreads();
    const float mu = (red[0] + red[1] + red[2] + red[3]) * (1.f / 1024.f);
    __syncthreads();

    const float d0 = x0 - mu, d1 = x1 - mu, d2 = x2 - mu, d3 = x3 - mu;
    float s2 = d0 * d0 + d1 * d1 + d2 * d2 + d3 * d3;
    #pragma unroll
    for (int off = 32; off; off >>= 1) s2 += __shfl_xor(s2, off);
    if (lane == 0) red[wave] = s2;
    __syncthreads();
    const float var = (red[0] + red[1] + red[2] + red[3]) * (1.f / 1024.f);
    const float rs = rsqrtf(var + 1e-5f);

    const float4 gg = ((const float4*)g)[tid];
    const float4 bb = ((const float4*)bta)[tid];
    ushort4 o;
    o.x = f2bf(d0 * rs * gg.x + bb.x);
    o.y = f2bf(d1 * rs * gg.y + bb.y);
    o.z = f2bf(d2 * rs * gg.z + bb.z);
    o.w = f2bf(d3 * rs * gg.w + bb.w);
    *(ushort4*)(Y + (size_t)row * 1024 + tid * 4) = o;
}

// fp32 in-place LayerNorm (final output)
__global__ __launch_bounds__(256) void ln_kernel(
        const float* X, const float* __restrict__ g,
        const float* __restrict__ bta, float* Y)
{
    __shared__ float red[4];
    const int row = blockIdx.x;
    const int tid = threadIdx.x;
    const int wave = tid >> 6, lane = tid & 63;

    const float4 v = ((const float4*)(X + (size_t)row * 1024))[tid];

    float s = v.x + v.y + v.z + v.w;
    #pragma unroll
    for (int off = 32; off; off >>= 1) s += __shfl_xor(s, off);
    if (lane == 0) red[wave] = s;
    __syncthreads();
    const float mu = (red[0] + red[1] + red[2] + red[3]) * (1.f / 1024.f);
    __syncthreads();

    const float dx = v.x - mu, dy = v.y - mu, dz = v.z - mu, dw = v.w - mu;
    float s2 = dx * dx + dy * dy + dz * dz + dw * dw;
    #pragma unroll
    for (int off = 32; off; off >>= 1) s2 += __shfl_xor(s2, off);
    if (lane == 0) red[wave] = s2;
    __syncthreads();
    const float var = (red[0] + red[1] + red[2] + red[3]) * (1.f / 1024.f);
    const float rs = rsqrtf(var + 1e-5f);

    const float4 gg = ((const float4*)g)[tid];
    const float4 bb = ((const float4*)bta)[tid];
    float4 o;
    o.x = dx * rs * gg.x + bb.x;
    o.y = dy * rs * gg.y + bb.y;
    o.z = dz * rs * gg.z + bb.z;
    o.w = dw * rs * gg.w + bb.w;
    ((float4*)(Y + (size_t)row * 1024))[tid] = o;
}

// ---------------------------------------------------------------------------
extern "C" void kernel_launch(void* const* d_in, const int* in_sizes, int n_in,
                              void* d_out, int out_size, void* d_ws, size_t ws_size,
                              hipStream_t stream)
{
    const float* tgt    = (const float*)d_in[0];
    const float* mem    = (const float*)d_in[1];
    const float* sa_wq  = (const float*)d_in[3];
    const float* sa_bq  = (const float*)d_in[4];
    const float* sa_wk  = (const float*)d_in[5];
    const float* sa_bk  = (const float*)d_in[6];
    const float* sa_wv  = (const float*)d_in[7];
    const float* sa_bv  = (const float*)d_in[8];
    const float* sa_wo  = (const float*)d_in[9];
    const float* sa_bo  = (const float*)d_in[10];
    const float* ca_wq  = (const float*)d_in[11];
    const float* ca_bq  = (const float*)d_in[12];
    const float* ca_wk  = (const float*)d_in[13];
    const float* ca_bk  = (const float*)d_in[14];
    const float* ca_wv  = (const float*)d_in[15];
    const float* ca_bv  = (const float*)d_in[16];
    const float* ca_wo  = (const float*)d_in[17];
    const float* ca_bo  = (const float*)d_in[18];
    const float* ffn_w1 = (const float*)d_in[19];
    const float* ffn_b1 = (const float*)d_in[20];
    const float* ffn_w2 = (const float*)d_in[21];
    const float* ffn_b2 = (const float*)d_in[22];
    const float* ln1_g  = (const float*)d_in[23];
    const float* ln1_b  = (const float*)d_in[24];
    const float* ln2_g  = (const float*)d_in[25];
    const float* ln2_b  = (const float*)d_in[26];
    const float* ln3_g  = (const float*)d_in[27];
    const float* ln3_b  = (const float*)d_in[28];

    float* out = (float*)d_out;
    u16* wsb = (u16*)d_ws;
    const size_t M1 = 1024 * 1024;

    // weights (bf16, transposed [N][K]): 32 MB.
    u16* Wsq = wsb + 0 * M1;
    u16* Wsk = wsb + 1 * M1;
    u16* Wsv = wsb + 2 * M1;
    u16* Wso = wsb + 3 * M1;
    u16* Wcq = wsb + 4 * M1;
    u16* Wck = wsb + 5 * M1;
    u16* Wcv = wsb + 6 * M1;
    u16* Wco = wsb + 7 * M1;
    u16* Wf1 = wsb + 8 * M1;    // [4096][1024]
    u16* Wf2 = wsb + 12 * M1;   // [1024][4096]

    // activation slots (bf16, 4M elems each): 48 MB
    u16* sl = wsb + 16 * M1;
    u16* s0 = sl + 0 * 4 * M1;
    u16* s1 = sl + 4 * M1;
    u16* s2 = sl + 8 * M1;
    u16* s3 = sl + 12 * M1;
    u16* s4 = sl + 16 * M1;
    u16* s5 = sl + 20 * M1;
    u16* H  = s0;               // FFN hidden [4096][4096] aliases s0..s3 (dead)

    // f32 bias concat buffers (after slots; +20 KB)
    float* biasQKV = (float*)(wsb + 40 * M1);   // [3072]
    float* biasKV  = biasQKV + 3072;            // [2048]

    const dim3 blk(256);
    const dim3 gqkv(24, 32);    // N=3072 fused QKV
    const dim3 gkv(16, 32);     // N=2048 fused KV
    const dim3 g1(8, 32);       // N=1024 GEMM
    const dim3 g4(32, 32);      // N=4096 GEMM (FFN1)
    const dim3 ga(64, 16);      // attention
    const dim3 gln(4096);

    // ---- weight/bias prep ----
    TrwB tb;
    tb.w[0] = sa_wq; tb.o[0] = Wsq;
    tb.w[1] = sa_wk; tb.o[1] = Wsk;
    tb.w[2] = sa_wv; tb.o[2] = Wsv;
    tb.w[3] = sa_wo; tb.o[3] = Wso;
    tb.w[4] = ca_wq; tb.o[4] = Wcq;
    tb.w[5] = ca_wk; tb.o[5] = Wck;
    tb.w[6] = ca_wv; tb.o[6] = Wcv;
    tb.w[7] = ca_wo; tb.o[7] = Wco;
    trw8_kernel<<<dim3(16, 16, 8), blk, 0, stream>>>(tb);
    trw_kernel<<<dim3(64, 16), blk, 0, stream>>>(ffn_w1, Wf1, 1024, 4096);
    trw_kernel<<<dim3(16, 64), blk, 0, stream>>>(ffn_w2, Wf2, 4096, 1024);
    bcat_kernel<<<12, blk, 0, stream>>>(sa_bq, sa_bk, sa_bv, biasQKV, 3072);
    bcat_kernel<<<8, blk, 0, stream>>>(ca_bk, ca_bv, ca_bv, biasKV, 2048);
    cvt_kernel<<<2048, blk, 0, stream>>>(tgt, s0, 1024 * 1024);
    cvt_kernel<<<2048, blk, 0, stream>>>(mem, s1, 1024 * 1024);

    // ---- self-attention ----
    // fused QKV: Q->s2, K->s3, Vt->s4
    gemm_mfma<5><<<gqkv, blk, 0, stream>>>(s0, Wsq, biasQKV, nullptr,
                                           s2, s3, s4, 3072, 1024);
    fattn_mfma<1><<<ga, blk, 0, stream>>>(s2, s3, s4, s5);
    gemm_mfma<2><<<g1, blk, 0, stream>>>(s5, Wso, sa_bo, s0, s2, nullptr, nullptr, 1024, 1024);
    ln_bf16_kernel<<<gln, blk, 0, stream>>>(s2, ln1_g, ln1_b, s3);     // x1 = s3

    // ---- cross-attention ----
    gemm_mfma<0><<<g1, blk, 0, stream>>>(s3, Wcq, ca_bq, nullptr, s2, nullptr, nullptr, 1024, 1024);
    // fused KV from memory: K->s4, Vt->s5
    gemm_mfma<6><<<gkv, blk, 0, stream>>>(s1, Wck, biasKV, nullptr,
                                          s4, s5, nullptr, 2048, 1024);
    fattn_mfma<0><<<ga, blk, 0, stream>>>(s2, s4, s5, s0);
    gemm_mfma<2><<<g1, blk, 0, stream>>>(s0, Wco, ca_bo, s3, s2, nullptr, nullptr, 1024, 1024);
    ln_bf16_kernel<<<gln, blk, 0, stream>>>(s2, ln2_g, ln2_b, s4);     // x2 = s4

    // ---- FFN ----
    gemm_mfma<1><<<g4, blk, 0, stream>>>(s4, Wf1, ffn_b1, nullptr, H, nullptr, nullptr, 4096, 1024);
    gemm_mfma<3><<<g1, blk, 0, stream>>>(H, Wf2, ffn_b2, s4, out, nullptr, nullptr, 1024, 4096);
    ln_kernel<<<gln, blk, 0, stream>>>(out, ln3_g, ln3_b, out);
}

// Round 7
// 401.286 us; speedup vs baseline: 20.7879x; 1.0267x over previous
//
#include <hip/hip_runtime.h>
#include <hip/hip_bf16.h>

typedef unsigned short u16;
typedef __attribute__((ext_vector_type(8))) short bf16x8;
typedef __attribute__((ext_vector_type(4))) float floatx4;

__device__ inline float u2f(unsigned u) { union { unsigned i; float f; } x; x.i = u; return x.f; }
__device__ inline float bflo(unsigned p) { return u2f(p << 16); }
__device__ inline float bfhi(unsigned p) { return u2f(p & 0xffff0000u); }
__device__ inline u16 f2bf(float f) {
    union { __hip_bfloat16 h; u16 u; } x;
    x.h = __float2bfloat16(f);
    return x.u;
}

#define GLDS(g, l) __builtin_amdgcn_global_load_lds( \
    (const __attribute__((address_space(1))) void*)(g), \
    (__attribute__((address_space(3))) void*)(l), 16, 0, 0)

// ---------------------------------------------------------------------------
// bf16 MFMA GEMM: C[M,N] = A[M,K] @ Bt[N,K]^T + bias (+res) (+relu)
// 128x128 tile, 4 waves (2x2), 16x16x32 MFMA, BK=32, XCD-chunked swizzle.
// 3-buffer counted-vmcnt pipeline (T3+T4): stage tile t+2 while computing
// tile t; s_waitcnt vmcnt(4) waits only for tile t's 4 loads, leaving tile
// t+1's in flight across the barrier. Loads get ~2 compute phases to land;
// vmcnt never drains to 0 in the main loop (last tile only).
// EPI: 0 = bf16 out, 1 = bf16 out + relu, 2 = bf16 out + bf16 res,
//      3 = f32 out + bf16 res,
//      5 = segmented QKV (seg0->Cv plain, seg1->o1 plain, seg2->o2 Vt),
//      6 = segmented KV  (seg0->Cv plain, seg1->o1 Vt)
// Vt layout: Vt[b*16+h][d][t], t fast.
// ---------------------------------------------------------------------------
template<int EPI>
__global__ __launch_bounds__(256) void gemm_mfma(
        const u16* __restrict__ A, const u16* __restrict__ Bt,
        const float* __restrict__ bias, const u16* __restrict__ res,
        void* __restrict__ Cv, u16* __restrict__ o1, u16* __restrict__ o2,
        int N, int K)
{
    __shared__ u16 As0[128 * 32];
    __shared__ u16 Bs0[128 * 32];
    __shared__ u16 As1[128 * 32];
    __shared__ u16 Bs1[128 * 32];
    __shared__ u16 As2[128 * 32];
    __shared__ u16 Bs2[128 * 32];

    const int tid = threadIdx.x;
    const int lane = tid & 63, wv = tid >> 6;
    const int wr = wv >> 1, wc = wv & 1;

    // XCD-chunked bijective swizzle (all grids have nwg % 8 == 0)
    const int gx = gridDim.x;
    const int nwg = gx * gridDim.y;
    const int bid0 = blockIdx.y * gx + blockIdx.x;
    const int nbid = (bid0 & 7) * (nwg >> 3) + (bid0 >> 3);
    const int bx = nbid % gx, by = nbid / gx;
    const int row0 = by * 128, col0 = bx * 128;

    // staging: linear LDS dest, inverse-swizzled global source (16B/lane x2)
    const u16* pa[2];
    const u16* pb[2];
    int ldst[2];
    #pragma unroll
    for (int i = 0; i < 2; ++i) {
        const int idx = i * 256 + tid;               // 0..511
        const int r = idx >> 2;                      // tile row 0..127
        const int kob = (idx & 3) << 4;              // byte off in 64B row
        const int sw = kob ^ (((r >> 1) & 3) << 4);  // swizzled byte off
        pa[i] = A  + (size_t)(row0 + r) * K + (sw >> 1);
        pb[i] = Bt + (size_t)(col0 + r) * K + (sw >> 1);
        ldst[i] = idx * 8;                           // u16 elements
    }

    // fragment read offsets (swizzled)
    int offa[4], offb[4];
    const int rsel = lane & 15, slot = lane >> 4;
    #pragma unroll
    for (int m = 0; m < 4; ++m) {
        const int ra = wr * 64 + m * 16 + rsel;
        offa[m] = ra * 32 + (((slot << 4) ^ (((ra >> 1) & 3) << 4)) >> 1);
        const int rb = wc * 64 + m * 16 + rsel;
        offb[m] = rb * 32 + (((slot << 4) ^ (((rb >> 1) & 3) << 4)) >> 1);
    }

    floatx4 acc[4][4] = {};

#define STAGE(AA, BB, t) do {                                   \
        const int ko_ = (t) << 5;                               \
        GLDS(pa[0] + ko_, &AA[ldst[0]]);                        \
        GLDS(pb[0] + ko_, &BB[ldst[0]]);                        \
        GLDS(pa[1] + ko_, &AA[ldst[1]]);                        \
        GLDS(pb[1] + ko_, &BB[ldst[1]]);                        \
    } while (0)

#define COMPUTE(AA, BB) do {                                    \
        bf16x8 af[4], bfr[4];                                   \
        _Pragma("unroll")                                       \
        for (int m = 0; m < 4; ++m) af[m] = *(const bf16x8*)&AA[offa[m]]; \
        _Pragma("unroll")                                       \
        for (int n = 0; n < 4; ++n) bfr[n] = *(const bf16x8*)&BB[offb[n]]; \
        _Pragma("unroll")                                       \
        for (int m = 0; m < 4; ++m)                             \
            _Pragma("unroll")                                   \
            for (int n = 0; n < 4; ++n)                         \
                acc[m][n] = __builtin_amdgcn_mfma_f32_16x16x32_bf16( \
                        af[m], bfr[n], acc[m][n], 0, 0, 0);     \
    } while (0)

// one pipeline phase: tile t computed from (CA,CB); tile t+2 staged to (NA,NB)
#define PHASE(CA, CB, NA, NB, t) do {                           \
        if ((t) < nkt - 1) asm volatile("s_waitcnt vmcnt(4)" ::: "memory"); \
        else               asm volatile("s_waitcnt vmcnt(0)" ::: "memory"); \
        __builtin_amdgcn_s_barrier();                           \
        __builtin_amdgcn_sched_barrier(0);                      \
        if ((t) + 2 < nkt) STAGE(NA, NB, (t) + 2);              \
        COMPUTE(CA, CB);                                        \
    } while (0)

    const int nkt = K >> 5;          // 32 or 128 (nkt % 3 == 2)
    STAGE(As0, Bs0, 0);
    STAGE(As1, Bs1, 1);
    int t = 0;
    for (; t + 3 <= nkt; t += 3) {
        PHASE(As0, Bs0, As2, Bs2, t);
        PHASE(As1, Bs1, As0, Bs0, t + 1);
        PHASE(As2, Bs2, As1, Bs1, t + 2);
    }
    if (t < nkt)     PHASE(As0, Bs0, As2, Bs2, t);       // tile nkt-2
    if (t + 1 < nkt) PHASE(As1, Bs1, As0, Bs0, t + 1);   // tile nkt-1
#undef STAGE
#undef COMPUTE
#undef PHASE

    // epilogue: C/D layout col=lane&15, row=(lane>>4)*4+reg
    const int cr4 = (lane >> 4) * 4;
    const int cc = lane & 15;

    if (EPI == 5 || EPI == 6) {
        const int seg = col0 >> 10;                  // block-uniform
        const int vtseg = (EPI == 5) ? 2 : 1;
        u16* dst;
        if (EPI == 5) dst = (seg == 0) ? (u16*)Cv : (seg == 1 ? o1 : o2);
        else          dst = (seg == 0) ? (u16*)Cv : o1;

        if (seg == vtseg) {
            #pragma unroll
            for (int n = 0; n < 4; ++n) {
                const int col = col0 + wc * 64 + n * 16 + cc;
                const float bv = bias[col];
                const int vcol = col & 1023;
                const int h = vcol >> 6, d = vcol & 63;
                #pragma unroll
                for (int m = 0; m < 4; ++m) {
                    const int tk = row0 + wr * 64 + m * 16 + cr4;
                    const int b = tk >> 10;
                    ushort4 o4;
                    o4.x = f2bf(acc[m][n][0] + bv);
                    o4.y = f2bf(acc[m][n][1] + bv);
                    o4.z = f2bf(acc[m][n][2] + bv);
                    o4.w = f2bf(acc[m][n][3] + bv);
                    *(ushort4*)(dst +
                        (((size_t)(b * 16 + h) * 64 + d) * 1024 + (tk & 1023))) = o4;
                }
            }
        } else {
            #pragma unroll
            for (int n = 0; n < 4; ++n) {
                const int col = col0 + wc * 64 + n * 16 + cc;
                const float bv = bias[col];
                const int oc = col & 1023;
                #pragma unroll
                for (int m = 0; m < 4; ++m) {
                    const int rowb = row0 + wr * 64 + m * 16 + cr4;
                    #pragma unroll
                    for (int r = 0; r < 4; ++r)
                        dst[(size_t)(rowb + r) * 1024 + oc] = f2bf(acc[m][n][r] + bv);
                }
            }
        }
        return;
    }

    #pragma unroll
    for (int n = 0; n < 4; ++n) {
        const int col = col0 + wc * 64 + n * 16 + cc;
        const float bv = bias[col];
        #pragma unroll
        for (int m = 0; m < 4; ++m) {
            const int rowb = row0 + wr * 64 + m * 16 + cr4;
            #pragma unroll
            for (int r = 0; r < 4; ++r) {
                float v = acc[m][n][r] + bv;
                const size_t o = (size_t)(rowb + r) * N + col;
                if (EPI == 2 || EPI == 3) v += u2f((unsigned)res[o] << 16);
                if (EPI == 1) v = fmaxf(v, 0.f);
                if (EPI == 3) ((float*)Cv)[o] = v;
                else          ((u16*)Cv)[o] = f2bf(v);
            }
        }
    }
}

// ---------------------------------------------------------------------------
// Batched 1024x1024 weight convert+transpose (8 weights, one dispatch).
// ---------------------------------------------------------------------------
struct TrwB { const float* w[8]; u16* o[8]; };

__global__ __launch_bounds__(256) void trw8_kernel(TrwB p)
{
    __shared__ float ts[64][65];
    const int tid = threadIdx.x;
    const int n0 = blockIdx.x * 64, k0 = blockIdx.y * 64;
    const float* __restrict__ W = p.w[blockIdx.z];
    u16* __restrict__ Wt = p.o[blockIdx.z];
    const int tr = tid >> 4, tc4 = (tid & 15) * 4;
    #pragma unroll
    for (int i = 0; i < 4; ++i) {
        const float4 v = *(const float4*)(W + (size_t)(k0 + tr + i * 16) * 1024 + n0 + tc4);
        ts[tr + i * 16][tc4 + 0] = v.x;
        ts[tr + i * 16][tc4 + 1] = v.y;
        ts[tr + i * 16][tc4 + 2] = v.z;
        ts[tr + i * 16][tc4 + 3] = v.w;
    }
    __syncthreads();
    #pragma unroll
    for (int i = 0; i < 4; ++i) {
        const int nr = tr + i * 16;
        ushort4 o;
        o.x = f2bf(ts[tc4 + 0][nr]);
        o.y = f2bf(ts[tc4 + 1][nr]);
        o.z = f2bf(ts[tc4 + 2][nr]);
        o.w = f2bf(ts[tc4 + 3][nr]);
        *(ushort4*)(Wt + (size_t)(n0 + nr) * 1024 + k0 + tc4) = o;
    }
}

// generic weight transpose (FFN weights)
__global__ __launch_bounds__(256) void trw_kernel(
        const float* __restrict__ W, u16* __restrict__ Wt, int K, int N)
{
    __shared__ float ts[64][65];
    const int tid = threadIdx.x;
    const int n0 = blockIdx.x * 64, k0 = blockIdx.y * 64;
    const int tr = tid >> 4, tc4 = (tid & 15) * 4;
    #pragma unroll
    for (int i = 0; i < 4; ++i) {
        const float4 v = *(const float4*)(W + (size_t)(k0 + tr + i * 16) * N + n0 + tc4);
        ts[tr + i * 16][tc4 + 0] = v.x;
        ts[tr + i * 16][tc4 + 1] = v.y;
        ts[tr + i * 16][tc4 + 2] = v.z;
        ts[tr + i * 16][tc4 + 3] = v.w;
    }
    __syncthreads();
    #pragma unroll
    for (int i = 0; i < 4; ++i) {
        const int nr = tr + i * 16;
        ushort4 o;
        o.x = f2bf(ts[tc4 + 0][nr]);
        o.y = f2bf(ts[tc4 + 1][nr]);
        o.z = f2bf(ts[tc4 + 2][nr]);
        o.w = f2bf(ts[tc4 + 3][nr]);
        *(ushort4*)(Wt + (size_t)(n0 + nr) * K + k0 + tc4) = o;
    }
}

// fp32 -> bf16 elementwise (n4 = count/4)
__global__ __launch_bounds__(256) void cvt_kernel(
        const float* __restrict__ in, u16* __restrict__ out, int n4)
{
    for (int i = blockIdx.x * 256 + threadIdx.x; i < n4; i += gridDim.x * 256) {
        const float4 v = ((const float4*)in)[i];
        ushort4 o;
        o.x = f2bf(v.x); o.y = f2bf(v.y); o.z = f2bf(v.z); o.w = f2bf(v.w);
        ((ushort4*)out)[i] = o;
    }
}

// concat up to 3 bias vectors of 1024 into one f32 buffer
__global__ __launch_bounds__(256) void bcat_kernel(
        const float* __restrict__ b0, const float* __restrict__ b1,
        const float* __restrict__ b2, float* __restrict__ o, int n)
{
    const int i = blockIdx.x * 256 + threadIdx.x;
    if (i >= n) return;
    const float* s = (i < 1024) ? b0 : (i < 2048 ? b1 : b2);
    o[i] = s[i & 1023];
}

// ---------------------------------------------------------------------------
// MFMA flash attention. Q,K: [4096][1024] bf16 (head h at cols h*64..+64).
// Vt: [b*16+h][64 d][1024 t] bf16. Block = 4 waves, one (b,h) x 64 q-rows.
// Grid (64, 16). LDS tiles 64x64 bf16, byte = r*128 + ((c*2) ^ ((r&7)<<4)).
// ---------------------------------------------------------------------------
template<int CAUSAL>
__global__ __launch_bounds__(256) void fattn_mfma(
        const u16* __restrict__ Q, const u16* __restrict__ K,
        const u16* __restrict__ Vt, u16* __restrict__ O)
{
    __shared__ u16 Qs[64 * 64];
    __shared__ u16 Ks[64 * 64];
    __shared__ u16 Ps[64 * 64];
    __shared__ u16 Vs[64 * 64];

    const int tid = threadIdx.x;
    const int lane = tid & 63, wv = tid >> 6;
    const int bh = blockIdx.x;
    const int b = bh >> 4, h = bh & 15;
    const int qt = blockIdx.y, q0 = qt * 64;

    const size_t qkbase = (size_t)b * (1024 * 1024) + (size_t)h * 64;
    const size_t vtbase = (size_t)bh * 64 * 1024;

    // stage Q (swizzled)
    #pragma unroll
    for (int i = 0; i < 2; ++i) {
        const int idx = i * 256 + tid, r = idx >> 3, s = idx & 7;
        const uint4 v = *(const uint4*)(Q + qkbase + (size_t)(q0 + r) * 1024 + s * 8);
        *(uint4*)((char*)Qs + r * 128 + ((s ^ (r & 7)) << 4)) = v;
    }
    __syncthreads();

    // hoist Q a-frags (each wave owns rows wv*16..+16)
    bf16x8 qf[2];
    #pragma unroll
    for (int ks = 0; ks < 2; ++ks) {
        const int r = wv * 16 + (lane & 15);
        const int slot = ks * 4 + (lane >> 4);
        qf[ks] = *(const bf16x8*)((char*)Qs + r * 128 + ((slot ^ (r & 7)) << 4));
    }

    float m_i[4] = {-1e30f, -1e30f, -1e30f, -1e30f};
    float l_i[4] = {0.f, 0.f, 0.f, 0.f};
    floatx4 o_acc[4] = {};

    const int ktmax = CAUSAL ? qt : 15;
    for (int kt = 0; kt <= ktmax; ++kt) {
        __syncthreads();
        #pragma unroll
        for (int i = 0; i < 2; ++i) {
            const int idx = i * 256 + tid, r = idx >> 3, s = idx & 7;
            const uint4 kv = *(const uint4*)(K + qkbase + (size_t)(kt * 64 + r) * 1024 + s * 8);
            *(uint4*)((char*)Ks + r * 128 + ((s ^ (r & 7)) << 4)) = kv;
            const uint4 vv = *(const uint4*)(Vt + vtbase + (size_t)r * 1024 + kt * 64 + s * 8);
            *(uint4*)((char*)Vs + r * 128 + ((s ^ (r & 7)) << 4)) = vv;
        }
        __syncthreads();

        // S = Q @ K^T
        floatx4 sa[4] = {};
        #pragma unroll
        for (int ks = 0; ks < 2; ++ks) {
            #pragma unroll
            for (int n = 0; n < 4; ++n) {
                const int r = n * 16 + (lane & 15);
                const int slot = ks * 4 + (lane >> 4);
                const bf16x8 bf = *(const bf16x8*)((char*)Ks + r * 128 + ((slot ^ (r & 7)) << 4));
                sa[n] = __builtin_amdgcn_mfma_f32_16x16x32_bf16(qf[ks], bf, sa[n], 0, 0, 0);
            }
        }

        // scale + mask
        float p[4][4];
        #pragma unroll
        for (int n = 0; n < 4; ++n)
            #pragma unroll
            for (int r = 0; r < 4; ++r) {
                float v = sa[n][r] * 0.125f;
                if (CAUSAL && kt == qt) {
                    const int ql = wv * 16 + (lane >> 4) * 4 + r;
                    const int kl = n * 16 + (lane & 15);
                    if (kl > ql) v = -1e30f;
                }
                p[n][r] = v;
            }

        // online softmax
        #pragma unroll
        for (int r = 0; r < 4; ++r) {
            float mx = fmaxf(fmaxf(p[0][r], p[1][r]), fmaxf(p[2][r], p[3][r]));
            mx = fmaxf(mx, __shfl_xor(mx, 1));
            mx = fmaxf(mx, __shfl_xor(mx, 2));
            mx = fmaxf(mx, __shfl_xor(mx, 4));
            mx = fmaxf(mx, __shfl_xor(mx, 8));
            const float mn = fmaxf(m_i[r], mx);
            const float al = __expf(m_i[r] - mn);
            m_i[r] = mn;
            float rs = 0.f;
            #pragma unroll
            for (int n = 0; n < 4; ++n) { p[n][r] = __expf(p[n][r] - mn); rs += p[n][r]; }
            rs += __shfl_xor(rs, 1);
            rs += __shfl_xor(rs, 2);
            rs += __shfl_xor(rs, 4);
            rs += __shfl_xor(rs, 8);
            l_i[r] = l_i[r] * al + rs;
            o_acc[0][r] *= al; o_acc[1][r] *= al;
            o_acc[2][r] *= al; o_acc[3][r] *= al;
        }

        // write P to own wave's LDS rows (same-wave RAW, no barrier)
        #pragma unroll
        for (int n = 0; n < 4; ++n)
            #pragma unroll
            for (int r = 0; r < 4; ++r) {
                const int qr = wv * 16 + (lane >> 4) * 4 + r;
                const int k2 = (n * 16 + (lane & 15)) * 2;
                *(u16*)((char*)Ps + qr * 128 + (k2 ^ ((qr & 7) << 4))) = f2bf(p[n][r]);
            }

        // O += P @ V
        #pragma unroll
        for (int ks = 0; ks < 2; ++ks) {
            const int ra = wv * 16 + (lane & 15);
            const int slot = ks * 4 + (lane >> 4);
            const bf16x8 af = *(const bf16x8*)((char*)Ps + ra * 128 + ((slot ^ (ra & 7)) << 4));
            #pragma unroll
            for (int n = 0; n < 4; ++n) {
                const int rv = n * 16 + (lane & 15);
                const bf16x8 bf = *(const bf16x8*)((char*)Vs + rv * 128 + ((slot ^ (rv & 7)) << 4));
                o_acc[n] = __builtin_amdgcn_mfma_f32_16x16x32_bf16(af, bf, o_acc[n], 0, 0, 0);
            }
        }
    }

    #pragma unroll
    for (int r = 0; r < 4; ++r) {
        const float inv = 1.f / l_i[r];
        const int qg = q0 + wv * 16 + (lane >> 4) * 4 + r;
        #pragma unroll
        for (int n = 0; n < 4; ++n) {
            const int d = n * 16 + (lane & 15);
            O[qkbase + (size_t)qg * 1024 + d] = f2bf(o_acc[n][r] * inv);
        }
    }
}

// ---------------------------------------------------------------------------
// LayerNorm, bf16 in/out, fp32 stats. One block (256) per row of 1024.
// ---------------------------------------------------------------------------
__global__ __launch_bounds__(256) void ln_bf16_kernel(
        const u16* __restrict__ X, const float* __restrict__ g,
        const float* __restrict__ bta, u16* __restrict__ Y)
{
    __shared__ float red[4];
    const int row = blockIdx.x, tid = threadIdx.x;
    const int wave = tid >> 6, lane = tid & 63;

    const uint2 u = *(const uint2*)(X + (size_t)row * 1024 + tid * 4);
    const float x0 = bflo(u.x), x1 = bfhi(u.x), x2 = bflo(u.y), x3 = bfhi(u.y);

    float s = x0 + x1 + x2 + x3;
    #pragma unroll
    for (int off = 32; off; off >>= 1) s += __shfl_xor(s, off);
    if (lane == 0) red[wave] = s;
    __syncthreads();
    const float mu = (red[0] + red[1] + red[2] + red[3]) * (1.f / 1024.f);
    __syncthreads();

    const float d0 = x0 - mu, d1 = x1 - mu, d2 = x2 - mu, d3 = x3 - mu;
    float s2 = d0 * d0 + d1 * d1 + d2 * d2 + d3 * d3;
    #pragma unroll
    for (int off = 32; off; off >>= 1) s2 += __shfl_xor(s2, off);
    if (lane == 0) red[wave] = s2;
    __syncthreads();
    const float var = (red[0] + red[1] + red[2] + red[3]) * (1.f / 1024.f);
    const float rs = rsqrtf(var + 1e-5f);

    const float4 gg = ((const float4*)g)[tid];
    const float4 bb = ((const float4*)bta)[tid];
    ushort4 o;
    o.x = f2bf(d0 * rs * gg.x + bb.x);
    o.y = f2bf(d1 * rs * gg.y + bb.y);
    o.z = f2bf(d2 * rs * gg.z + bb.z);
    o.w = f2bf(d3 * rs * gg.w + bb.w);
    *(ushort4*)(Y + (size_t)row * 1024 + tid * 4) = o;
}

// fp32 in-place LayerNorm (final output)
__global__ __launch_bounds__(256) void ln_kernel(
        const float* X, const float* __restrict__ g,
        const float* __restrict__ bta, float* Y)
{
    __shared__ float red[4];
    const int row = blockIdx.x;
    const int tid = threadIdx.x;
    const int wave = tid >> 6, lane = tid & 63;

    const float4 v = ((const float4*)(X + (size_t)row * 1024))[tid];

    float s = v.x + v.y + v.z + v.w;
    #pragma unroll
    for (int off = 32; off; off >>= 1) s += __shfl_xor(s, off);
    if (lane == 0) red[wave] = s;
    __syncthreads();
    const float mu = (red[0] + red[1] + red[2] + red[3]) * (1.f / 1024.f);
    __syncthreads();

    const float dx = v.x - mu, dy = v.y - mu, dz = v.z - mu, dw = v.w - mu;
    float s2 = dx * dx + dy * dy + dz * dz + dw * dw;
    #pragma unroll
    for (int off = 32; off; off >>= 1) s2 += __shfl_xor(s2, off);
    if (lane == 0) red[wave] = s2;
    __syncthreads();
    const float var = (red[0] + red[1] + red[2] + red[3]) * (1.f / 1024.f);
    const float rs = rsqrtf(var + 1e-5f);

    const float4 gg = ((const float4*)g)[tid];
    const float4 bb = ((const float4*)bta)[tid];
    float4 o;
    o.x = dx * rs * gg.x + bb.x;
    o.y = dy * rs * gg.y + bb.y;
    o.z = dz * rs * gg.z + bb.z;
    o.w = dw * rs * gg.w + bb.w;
    ((float4*)(Y + (size_t)row * 1024))[tid] = o;
}

// ---------------------------------------------------------------------------
extern "C" void kernel_launch(void* const* d_in, const int* in_sizes, int n_in,
                              void* d_out, int out_size, void* d_ws, size_t ws_size,
                              hipStream_t stream)
{
    const float* tgt    = (const float*)d_in[0];
    const float* mem    = (const float*)d_in[1];
    const float* sa_wq  = (const float*)d_in[3];
    const float* sa_bq  = (const float*)d_in[4];
    const float* sa_wk  = (const float*)d_in[5];
    const float* sa_bk  = (const float*)d_in[6];
    const float* sa_wv  = (const float*)d_in[7];
    const float* sa_bv  = (const float*)d_in[8];
    const float* sa_wo  = (const float*)d_in[9];
    const float* sa_bo  = (const float*)d_in[10];
    const float* ca_wq  = (const float*)d_in[11];
    const float* ca_bq  = (const float*)d_in[12];
    const float* ca_wk  = (const float*)d_in[13];
    const float* ca_bk  = (const float*)d_in[14];
    const float* ca_wv  = (const float*)d_in[15];
    const float* ca_bv  = (const float*)d_in[16];
    const float* ca_wo  = (const float*)d_in[17];
    const float* ca_bo  = (const float*)d_in[18];
    const float* ffn_w1 = (const float*)d_in[19];
    const float* ffn_b1 = (const float*)d_in[20];
    const float* ffn_w2 = (const float*)d_in[21];
    const float* ffn_b2 = (const float*)d_in[22];
    const float* ln1_g  = (const float*)d_in[23];
    const float* ln1_b  = (const float*)d_in[24];
    const float* ln2_g  = (const float*)d_in[25];
    const float* ln2_b  = (const float*)d_in[26];
    const float* ln3_g  = (const float*)d_in[27];
    const float* ln3_b  = (const float*)d_in[28];

    float* out = (float*)d_out;
    u16* wsb = (u16*)d_ws;
    const size_t M1 = 1024 * 1024;

    // weights (bf16, transposed [N][K]): 32 MB.
    u16* Wsq = wsb + 0 * M1;
    u16* Wsk = wsb + 1 * M1;
    u16* Wsv = wsb + 2 * M1;
    u16* Wso = wsb + 3 * M1;
    u16* Wcq = wsb + 4 * M1;
    u16* Wck = wsb + 5 * M1;
    u16* Wcv = wsb + 6 * M1;
    u16* Wco = wsb + 7 * M1;
    u16* Wf1 = wsb + 8 * M1;    // [4096][1024]
    u16* Wf2 = wsb + 12 * M1;   // [1024][4096]

    // activation slots (bf16, 4M elems each): 48 MB
    u16* sl = wsb + 16 * M1;
    u16* s0 = sl + 0 * 4 * M1;
    u16* s1 = sl + 4 * M1;
    u16* s2 = sl + 8 * M1;
    u16* s3 = sl + 12 * M1;
    u16* s4 = sl + 16 * M1;
    u16* s5 = sl + 20 * M1;
    u16* H  = s0;               // FFN hidden [4096][4096] aliases s0..s3 (dead)

    // f32 bias concat buffers (after slots; +20 KB)
    float* biasQKV = (float*)(wsb + 40 * M1);   // [3072]
    float* biasKV  = biasQKV + 3072;            // [2048]

    const dim3 blk(256);
    const dim3 gqkv(24, 32);    // N=3072 fused QKV
    const dim3 gkv(16, 32);     // N=2048 fused KV
    const dim3 g1(8, 32);       // N=1024 GEMM
    const dim3 g4(32, 32);      // N=4096 GEMM (FFN1)
    const dim3 ga(64, 16);      // attention
    const dim3 gln(4096);

    // ---- weight/bias prep ----
    TrwB tb;
    tb.w[0] = sa_wq; tb.o[0] = Wsq;
    tb.w[1] = sa_wk; tb.o[1] = Wsk;
    tb.w[2] = sa_wv; tb.o[2] = Wsv;
    tb.w[3] = sa_wo; tb.o[3] = Wso;
    tb.w[4] = ca_wq; tb.o[4] = Wcq;
    tb.w[5] = ca_wk; tb.o[5] = Wck;
    tb.w[6] = ca_wv; tb.o[6] = Wcv;
    tb.w[7] = ca_wo; tb.o[7] = Wco;
    trw8_kernel<<<dim3(16, 16, 8), blk, 0, stream>>>(tb);
    trw_kernel<<<dim3(64, 16), blk, 0, stream>>>(ffn_w1, Wf1, 1024, 4096);
    trw_kernel<<<dim3(16, 64), blk, 0, stream>>>(ffn_w2, Wf2, 4096, 1024);
    bcat_kernel<<<12, blk, 0, stream>>>(sa_bq, sa_bk, sa_bv, biasQKV, 3072);
    bcat_kernel<<<8, blk, 0, stream>>>(ca_bk, ca_bv, ca_bv, biasKV, 2048);
    cvt_kernel<<<2048, blk, 0, stream>>>(tgt, s0, 1024 * 1024);
    cvt_kernel<<<2048, blk, 0, stream>>>(mem, s1, 1024 * 1024);

    // ---- self-attention ----
    // fused QKV: Q->s2, K->s3, Vt->s4
    gemm_mfma<5><<<gqkv, blk, 0, stream>>>(s0, Wsq, biasQKV, nullptr,
                                           s2, s3, s4, 3072, 1024);
    fattn_mfma<1><<<ga, blk, 0, stream>>>(s2, s3, s4, s5);
    gemm_mfma<2><<<g1, blk, 0, stream>>>(s5, Wso, sa_bo, s0, s2, nullptr, nullptr, 1024, 1024);
    ln_bf16_kernel<<<gln, blk, 0, stream>>>(s2, ln1_g, ln1_b, s3);     // x1 = s3

    // ---- cross-attention ----
    gemm_mfma<0><<<g1, blk, 0, stream>>>(s3, Wcq, ca_bq, nullptr, s2, nullptr, nullptr, 1024, 1024);
    // fused KV from memory: K->s4, Vt->s5
    gemm_mfma<6><<<gkv, blk, 0, stream>>>(s1, Wck, biasKV, nullptr,
                                          s4, s5, nullptr, 2048, 1024);
    fattn_mfma<0><<<ga, blk, 0, stream>>>(s2, s4, s5, s0);
    gemm_mfma<2><<<g1, blk, 0, stream>>>(s0, Wco, ca_bo, s3, s2, nullptr, nullptr, 1024, 1024);
    ln_bf16_kernel<<<gln, blk, 0, stream>>>(s2, ln2_g, ln2_b, s4);     // x2 = s4

    // ---- FFN ----
    gemm_mfma<1><<<g4, blk, 0, stream>>>(s4, Wf1, ffn_b1, nullptr, H, nullptr, nullptr, 4096, 1024);
    gemm_mfma<3><<<g1, blk, 0, stream>>>(H, Wf2, ffn_b2, s4, out, nullptr, nullptr, 1024, 4096);
    ln_kernel<<<gln, blk, 0, stream>>>(out, ln3_g, ln3_b, out);
}

// Round 8
// 399.340 us; speedup vs baseline: 20.8892x; 1.0049x over previous
//
#include <hip/hip_runtime.h>
#include <hip/hip_bf16.h>

typedef unsigned short u16;
typedef __attribute__((ext_vector_type(8))) short bf16x8;
typedef __attribute__((ext_vector_type(4))) float floatx4;

__device__ inline float u2f(unsigned u) { union { unsigned i; float f; } x; x.i = u; return x.f; }
__device__ inline float bflo(unsigned p) { return u2f(p << 16); }
__device__ inline float bfhi(unsigned p) { return u2f(p & 0xffff0000u); }
__device__ inline u16 f2bf(float f) {
    union { __hip_bfloat16 h; u16 u; } x;
    x.h = __float2bfloat16(f);
    return x.u;
}

#define GLDS(g, l) __builtin_amdgcn_global_load_lds( \
    (const __attribute__((address_space(1))) void*)(g), \
    (__attribute__((address_space(3))) void*)(l), 16, 0, 0)

// ---------------------------------------------------------------------------
// bf16 MFMA GEMM: C[M,N] = A[M,K] @ Bt[N,K]^T + bias (+res) (+relu)
// 128x64 tile, 4 waves (2x2 over 128x64 -> 64x32/wave), 16x16x32 MFMA, BK=32.
// 3-buffer counted-vmcnt pipeline: stage tile t+2 while computing tile t;
// vmcnt(3) waits only tile t's 3 loads (A:2, B:1 per thread).
// Grid doubled vs 128x128 -> 2+ blocks/CU for latency hiding.
// EPI: 0 = bf16 out, 1 = bf16 out + relu, 2 = bf16 out + bf16 res,
//      3 = f32 out + bf16 res,
//      5 = segmented QKV (seg0->Cv, seg1->o1, seg2->o2 Vt),
//      6 = segmented KV  (seg0->Cv, seg1->o1 Vt)
// Vt layout: Vt[b*16+h][d][t], t fast.
// ---------------------------------------------------------------------------
template<int EPI>
__global__ __launch_bounds__(256, 2) void gemm_mfma(
        const u16* __restrict__ A, const u16* __restrict__ Bt,
        const float* __restrict__ bias, const u16* __restrict__ res,
        void* __restrict__ Cv, u16* __restrict__ o1, u16* __restrict__ o2,
        int N, int K)
{
    __shared__ u16 As0[128 * 32];
    __shared__ u16 Bs0[64 * 32];
    __shared__ u16 As1[128 * 32];
    __shared__ u16 Bs1[64 * 32];
    __shared__ u16 As2[128 * 32];
    __shared__ u16 Bs2[64 * 32];

    const int tid = threadIdx.x;
    const int lane = tid & 63, wv = tid >> 6;
    const int wr = wv >> 1, wc = wv & 1;

    // XCD-chunked bijective swizzle (all grids have nwg % 8 == 0)
    const int gx = gridDim.x;
    const int nwg = gx * gridDim.y;
    const int bid0 = blockIdx.y * gx + blockIdx.x;
    const int nbid = (bid0 & 7) * (nwg >> 3) + (bid0 >> 3);
    const int bx = nbid % gx, by = nbid / gx;
    const int row0 = by * 128, col0 = bx * 64;

    // staging: linear LDS dest, inverse-swizzled global source
    const u16* pa[2];
    int ldst[2];
    #pragma unroll
    for (int i = 0; i < 2; ++i) {
        const int idx = i * 256 + tid;               // 0..511
        const int r = idx >> 2;                      // A tile row 0..127
        const int kob = (idx & 3) << 4;              // byte off in 64B row
        const int sw = kob ^ (((r >> 1) & 3) << 4);
        pa[i] = A + (size_t)(row0 + r) * K + (sw >> 1);
        ldst[i] = idx * 8;
    }
    const int rB = tid >> 2;                         // B tile row 0..63
    const int kobB = (tid & 3) << 4;
    const int swB = kobB ^ (((rB >> 1) & 3) << 4);
    const u16* pb = Bt + (size_t)(col0 + rB) * K + (swB >> 1);
    const int ldstB = tid * 8;

    // fragment read offsets (swizzled)
    int offa[4], offb[2];
    const int rsel = lane & 15, slot = lane >> 4;
    #pragma unroll
    for (int m = 0; m < 4; ++m) {
        const int ra = wr * 64 + m * 16 + rsel;
        offa[m] = ra * 32 + (((slot << 4) ^ (((ra >> 1) & 3) << 4)) >> 1);
    }
    #pragma unroll
    for (int n = 0; n < 2; ++n) {
        const int rb = wc * 32 + n * 16 + rsel;
        offb[n] = rb * 32 + (((slot << 4) ^ (((rb >> 1) & 3) << 4)) >> 1);
    }

    floatx4 acc[4][2] = {};

#define STAGE(AA, BB, t) do {                                   \
        const int ko_ = (t) << 5;                               \
        GLDS(pa[0] + ko_, &AA[ldst[0]]);                        \
        GLDS(pa[1] + ko_, &AA[ldst[1]]);                        \
        GLDS(pb + ko_, &BB[ldstB]);                             \
    } while (0)

#define COMPUTE(AA, BB) do {                                    \
        bf16x8 af[4], bfr[2];                                   \
        _Pragma("unroll")                                       \
        for (int m = 0; m < 4; ++m) af[m] = *(const bf16x8*)&AA[offa[m]]; \
        _Pragma("unroll")                                       \
        for (int n = 0; n < 2; ++n) bfr[n] = *(const bf16x8*)&BB[offb[n]]; \
        _Pragma("unroll")                                       \
        for (int m = 0; m < 4; ++m)                             \
            _Pragma("unroll")                                   \
            for (int n = 0; n < 2; ++n)                         \
                acc[m][n] = __builtin_amdgcn_mfma_f32_16x16x32_bf16( \
                        af[m], bfr[n], acc[m][n], 0, 0, 0);     \
    } while (0)

#define PHASE(CA, CB, NA, NB, t) do {                           \
        if ((t) < nkt - 1) asm volatile("s_waitcnt vmcnt(3)" ::: "memory"); \
        else               asm volatile("s_waitcnt vmcnt(0)" ::: "memory"); \
        __builtin_amdgcn_s_barrier();                           \
        __builtin_amdgcn_sched_barrier(0);                      \
        if ((t) + 2 < nkt) STAGE(NA, NB, (t) + 2);              \
        COMPUTE(CA, CB);                                        \
    } while (0)

    const int nkt = K >> 5;          // 32 or 128
    STAGE(As0, Bs0, 0);
    STAGE(As1, Bs1, 1);
    int t = 0;
    for (; t + 3 <= nkt; t += 3) {
        PHASE(As0, Bs0, As2, Bs2, t);
        PHASE(As1, Bs1, As0, Bs0, t + 1);
        PHASE(As2, Bs2, As1, Bs1, t + 2);
    }
    if (t < nkt)     PHASE(As0, Bs0, As2, Bs2, t);
    if (t + 1 < nkt) PHASE(As1, Bs1, As0, Bs0, t + 1);
#undef STAGE
#undef COMPUTE
#undef PHASE

    // epilogue: C/D layout col=lane&15, row=(lane>>4)*4+reg
    const int cr4 = (lane >> 4) * 4;
    const int cc = lane & 15;

    if (EPI == 5 || EPI == 6) {
        const int seg = col0 >> 10;                  // block-uniform
        const int vtseg = (EPI == 5) ? 2 : 1;
        u16* dst;
        if (EPI == 5) dst = (seg == 0) ? (u16*)Cv : (seg == 1 ? o1 : o2);
        else          dst = (seg == 0) ? (u16*)Cv : o1;

        if (seg == vtseg) {
            #pragma unroll
            for (int n = 0; n < 2; ++n) {
                const int col = col0 + wc * 32 + n * 16 + cc;
                const float bv = bias[col];
                const int vcol = col & 1023;
                const int h = vcol >> 6, d = vcol & 63;
                #pragma unroll
                for (int m = 0; m < 4; ++m) {
                    const int tk = row0 + wr * 64 + m * 16 + cr4;
                    const int b = tk >> 10;
                    ushort4 o4;
                    o4.x = f2bf(acc[m][n][0] + bv);
                    o4.y = f2bf(acc[m][n][1] + bv);
                    o4.z = f2bf(acc[m][n][2] + bv);
                    o4.w = f2bf(acc[m][n][3] + bv);
                    *(ushort4*)(dst +
                        (((size_t)(b * 16 + h) * 64 + d) * 1024 + (tk & 1023))) = o4;
                }
            }
        } else {
            #pragma unroll
            for (int n = 0; n < 2; ++n) {
                const int col = col0 + wc * 32 + n * 16 + cc;
                const float bv = bias[col];
                const int oc = col & 1023;
                #pragma unroll
                for (int m = 0; m < 4; ++m) {
                    const int rowb = row0 + wr * 64 + m * 16 + cr4;
                    #pragma unroll
                    for (int r = 0; r < 4; ++r)
                        dst[(size_t)(rowb + r) * 1024 + oc] = f2bf(acc[m][n][r] + bv);
                }
            }
        }
        return;
    }

    #pragma unroll
    for (int n = 0; n < 2; ++n) {
        const int col = col0 + wc * 32 + n * 16 + cc;
        const float bv = bias[col];
        #pragma unroll
        for (int m = 0; m < 4; ++m) {
            const int rowb = row0 + wr * 64 + m * 16 + cr4;
            #pragma unroll
            for (int r = 0; r < 4; ++r) {
                float v = acc[m][n][r] + bv;
                const size_t o = (size_t)(rowb + r) * N + col;
                if (EPI == 2 || EPI == 3) v += u2f((unsigned)res[o] << 16);
                if (EPI == 1) v = fmaxf(v, 0.f);
                if (EPI == 3) ((float*)Cv)[o] = v;
                else          ((u16*)Cv)[o] = f2bf(v);
            }
        }
    }
}

// ---------------------------------------------------------------------------
// Batched 1024x1024 weight convert+transpose (8 weights, one dispatch).
// ---------------------------------------------------------------------------
struct TrwB { const float* w[8]; u16* o[8]; };

__global__ __launch_bounds__(256) void trw8_kernel(TrwB p)
{
    __shared__ float ts[64][65];
    const int tid = threadIdx.x;
    const int n0 = blockIdx.x * 64, k0 = blockIdx.y * 64;
    const float* __restrict__ W = p.w[blockIdx.z];
    u16* __restrict__ Wt = p.o[blockIdx.z];
    const int tr = tid >> 4, tc4 = (tid & 15) * 4;
    #pragma unroll
    for (int i = 0; i < 4; ++i) {
        const float4 v = *(const float4*)(W + (size_t)(k0 + tr + i * 16) * 1024 + n0 + tc4);
        ts[tr + i * 16][tc4 + 0] = v.x;
        ts[tr + i * 16][tc4 + 1] = v.y;
        ts[tr + i * 16][tc4 + 2] = v.z;
        ts[tr + i * 16][tc4 + 3] = v.w;
    }
    __syncthreads();
    #pragma unroll
    for (int i = 0; i < 4; ++i) {
        const int nr = tr + i * 16;
        ushort4 o;
        o.x = f2bf(ts[tc4 + 0][nr]);
        o.y = f2bf(ts[tc4 + 1][nr]);
        o.z = f2bf(ts[tc4 + 2][nr]);
        o.w = f2bf(ts[tc4 + 3][nr]);
        *(ushort4*)(Wt + (size_t)(n0 + nr) * 1024 + k0 + tc4) = o;
    }
}

// generic weight transpose (FFN weights)
__global__ __launch_bounds__(256) void trw_kernel(
        const float* __restrict__ W, u16* __restrict__ Wt, int K, int N)
{
    __shared__ float ts[64][65];
    const int tid = threadIdx.x;
    const int n0 = blockIdx.x * 64, k0 = blockIdx.y * 64;
    const int tr = tid >> 4, tc4 = (tid & 15) * 4;
    #pragma unroll
    for (int i = 0; i < 4; ++i) {
        const float4 v = *(const float4*)(W + (size_t)(k0 + tr + i * 16) * N + n0 + tc4);
        ts[tr + i * 16][tc4 + 0] = v.x;
        ts[tr + i * 16][tc4 + 1] = v.y;
        ts[tr + i * 16][tc4 + 2] = v.z;
        ts[tr + i * 16][tc4 + 3] = v.w;
    }
    __syncthreads();
    #pragma unroll
    for (int i = 0; i < 4; ++i) {
        const int nr = tr + i * 16;
        ushort4 o;
        o.x = f2bf(ts[tc4 + 0][nr]);
        o.y = f2bf(ts[tc4 + 1][nr]);
        o.z = f2bf(ts[tc4 + 2][nr]);
        o.w = f2bf(ts[tc4 + 3][nr]);
        *(ushort4*)(Wt + (size_t)(n0 + nr) * K + k0 + tc4) = o;
    }
}

// fp32 -> bf16 elementwise (n4 = count/4)
__global__ __launch_bounds__(256) void cvt_kernel(
        const float* __restrict__ in, u16* __restrict__ out, int n4)
{
    for (int i = blockIdx.x * 256 + threadIdx.x; i < n4; i += gridDim.x * 256) {
        const float4 v = ((const float4*)in)[i];
        ushort4 o;
        o.x = f2bf(v.x); o.y = f2bf(v.y); o.z = f2bf(v.z); o.w = f2bf(v.w);
        ((ushort4*)out)[i] = o;
    }
}

// concat up to 3 bias vectors of 1024 into one f32 buffer
__global__ __launch_bounds__(256) void bcat_kernel(
        const float* __restrict__ b0, const float* __restrict__ b1,
        const float* __restrict__ b2, float* __restrict__ o, int n)
{
    const int i = blockIdx.x * 256 + threadIdx.x;
    if (i >= n) return;
    const float* s = (i < 1024) ? b0 : (i < 2048 ? b1 : b2);
    o[i] = s[i & 1023];
}

// ---------------------------------------------------------------------------
// MFMA flash attention, K/V double-buffered (T14 issue-early/write-late).
// Q,K: [4096][1024] bf16 (head h at cols h*64..+64).
// Vt: [b*16+h][64 d][1024 t] bf16. Block = 4 waves, one (b,h) x 64 q-rows.
// Grid (64, 16). LDS tiles 64x64 bf16, byte = r*128 + ((c*2) ^ ((r&7)<<4)).
// Softmax in log2 domain: scale = 0.125*log2(e), exp2f (native v_exp_f32).
// ---------------------------------------------------------------------------
template<int CAUSAL>
__global__ __launch_bounds__(256) void fattn_mfma(
        const u16* __restrict__ Q, const u16* __restrict__ K,
        const u16* __restrict__ Vt, u16* __restrict__ O)
{
    __shared__ u16 Qs[64 * 64];
    __shared__ u16 Ks0[64 * 64];
    __shared__ u16 Ks1[64 * 64];
    __shared__ u16 Vs0[64 * 64];
    __shared__ u16 Vs1[64 * 64];
    __shared__ u16 Ps[64 * 64];

    const int tid = threadIdx.x;
    const int lane = tid & 63, wv = tid >> 6;
    const int bh = blockIdx.x;
    const int b = bh >> 4, h = bh & 15;
    const int qt = blockIdx.y, q0 = qt * 64;
    const float SCL = 0.18033688011f;   // 0.125 * log2(e)

    const size_t qkbase = (size_t)b * (1024 * 1024) + (size_t)h * 64;
    const size_t vtbase = (size_t)bh * 64 * 1024;

    // per-thread staging geometry (2 x uint4 per matrix)
    const int r0 = tid >> 3, s0 = tid & 7;           // i=0
    const int r1 = 32 + (tid >> 3), s1 = tid & 7;    // i=1

    // stage Q (swizzled)
    {
        const uint4 v0 = *(const uint4*)(Q + qkbase + (size_t)(q0 + r0) * 1024 + s0 * 8);
        *(uint4*)((char*)Qs + r0 * 128 + ((s0 ^ (r0 & 7)) << 4)) = v0;
        const uint4 v1 = *(const uint4*)(Q + qkbase + (size_t)(q0 + r1) * 1024 + s1 * 8);
        *(uint4*)((char*)Qs + r1 * 128 + ((s1 ^ (r1 & 7)) << 4)) = v1;
    }
    __syncthreads();

    // hoist Q a-frags (each wave owns rows wv*16..+16)
    bf16x8 qf[2];
    #pragma unroll
    for (int ks = 0; ks < 2; ++ks) {
        const int r = wv * 16 + (lane & 15);
        const int slot = ks * 4 + (lane >> 4);
        qf[ks] = *(const bf16x8*)((char*)Qs + r * 128 + ((slot ^ (r & 7)) << 4));
    }

    float m_i[4] = {-1e30f, -1e30f, -1e30f, -1e30f};
    float l_i[4] = {0.f, 0.f, 0.f, 0.f};
    floatx4 o_acc[4] = {};

    const int ktmax = CAUSAL ? qt : 15;
    uint4 pk0, pk1, pv0, pv1;

#define LOADKV(kt) do {                                                      \
        pk0 = *(const uint4*)(K + qkbase + (size_t)((kt) * 64 + r0) * 1024 + s0 * 8); \
        pk1 = *(const uint4*)(K + qkbase + (size_t)((kt) * 64 + r1) * 1024 + s1 * 8); \
        pv0 = *(const uint4*)(Vt + vtbase + (size_t)r0 * 1024 + (kt) * 64 + s0 * 8);  \
        pv1 = *(const uint4*)(Vt + vtbase + (size_t)r1 * 1024 + (kt) * 64 + s1 * 8);  \
    } while (0)

#define STOREKV(KN, VN) do {                                                 \
        *(uint4*)((char*)KN + r0 * 128 + ((s0 ^ (r0 & 7)) << 4)) = pk0;      \
        *(uint4*)((char*)KN + r1 * 128 + ((s1 ^ (r1 & 7)) << 4)) = pk1;      \
        *(uint4*)((char*)VN + r0 * 128 + ((s0 ^ (r0 & 7)) << 4)) = pv0;      \
        *(uint4*)((char*)VN + r1 * 128 + ((s1 ^ (r1 & 7)) << 4)) = pv1;      \
    } while (0)

#define ABODY(KC, VC, KN, VN, kt) do {                                       \
        const bool pre_ = (kt) + 1 <= ktmax;                                 \
        if (pre_) LOADKV((kt) + 1);                                          \
        /* S = Q @ K^T */                                                    \
        floatx4 sa[4] = {};                                                  \
        _Pragma("unroll")                                                    \
        for (int ks = 0; ks < 2; ++ks) {                                     \
            _Pragma("unroll")                                                \
            for (int n = 0; n < 4; ++n) {                                    \
                const int rr = n * 16 + (lane & 15);                         \
                const int sl = ks * 4 + (lane >> 4);                         \
                const bf16x8 bf = *(const bf16x8*)((char*)KC + rr * 128 + ((sl ^ (rr & 7)) << 4)); \
                sa[n] = __builtin_amdgcn_mfma_f32_16x16x32_bf16(qf[ks], bf, sa[n], 0, 0, 0); \
            }                                                                \
        }                                                                    \
        float p[4][4];                                                       \
        _Pragma("unroll")                                                    \
        for (int n = 0; n < 4; ++n)                                          \
            _Pragma("unroll")                                                \
            for (int r = 0; r < 4; ++r) {                                    \
                float v = sa[n][r] * SCL;                                    \
                if (CAUSAL && (kt) == qt) {                                  \
                    const int ql = wv * 16 + (lane >> 4) * 4 + r;            \
                    const int kl = n * 16 + (lane & 15);                     \
                    if (kl > ql) v = -1e30f;                                 \
                }                                                            \
                p[n][r] = v;                                                 \
            }                                                                \
        _Pragma("unroll")                                                    \
        for (int r = 0; r < 4; ++r) {                                        \
            float mx = fmaxf(fmaxf(p[0][r], p[1][r]), fmaxf(p[2][r], p[3][r])); \
            mx = fmaxf(mx, __shfl_xor(mx, 1));                               \
            mx = fmaxf(mx, __shfl_xor(mx, 2));                               \
            mx = fmaxf(mx, __shfl_xor(mx, 4));                               \
            mx = fmaxf(mx, __shfl_xor(mx, 8));                               \
            const float mn = fmaxf(m_i[r], mx);                              \
            const float al = exp2f(m_i[r] - mn);                             \
            m_i[r] = mn;                                                     \
            float rs = 0.f;                                                  \
            _Pragma("unroll")                                                \
            for (int n = 0; n < 4; ++n) { p[n][r] = exp2f(p[n][r] - mn); rs += p[n][r]; } \
            rs += __shfl_xor(rs, 1);                                         \
            rs += __shfl_xor(rs, 2);                                         \
            rs += __shfl_xor(rs, 4);                                         \
            rs += __shfl_xor(rs, 8);                                         \
            l_i[r] = l_i[r] * al + rs;                                       \
            o_acc[0][r] *= al; o_acc[1][r] *= al;                            \
            o_acc[2][r] *= al; o_acc[3][r] *= al;                            \
        }                                                                    \
        _Pragma("unroll")                                                    \
        for (int n = 0; n < 4; ++n)                                          \
            _Pragma("unroll")                                                \
            for (int r = 0; r < 4; ++r) {                                    \
                const int qr = wv * 16 + (lane >> 4) * 4 + r;                \
                const int k2 = (n * 16 + (lane & 15)) * 2;                   \
                *(u16*)((char*)Ps + qr * 128 + (k2 ^ ((qr & 7) << 4))) = f2bf(p[n][r]); \
            }                                                                \
        _Pragma("unroll")                                                    \
        for (int ks = 0; ks < 2; ++ks) {                                     \
            const int ra = wv * 16 + (lane & 15);                            \
            const int sl = ks * 4 + (lane >> 4);                             \
            const bf16x8 af = *(const bf16x8*)((char*)Ps + ra * 128 + ((sl ^ (ra & 7)) << 4)); \
            _Pragma("unroll")                                                \
            for (int n = 0; n < 4; ++n) {                                    \
                const int rv = n * 16 + (lane & 15);                         \
                const bf16x8 bf = *(const bf16x8*)((char*)VC + rv * 128 + ((sl ^ (rv & 7)) << 4)); \
                o_acc[n] = __builtin_amdgcn_mfma_f32_16x16x32_bf16(af, bf, o_acc[n], 0, 0, 0); \
            }                                                                \
        }                                                                    \
        if (pre_) STOREKV(KN, VN);                                           \
        __syncthreads();                                                     \
    } while (0)

    LOADKV(0);
    STOREKV(Ks0, Vs0);
    __syncthreads();
    for (int kt = 0; kt <= ktmax; kt += 2) {
        ABODY(Ks0, Vs0, Ks1, Vs1, kt);
        if (kt + 1 <= ktmax) ABODY(Ks1, Vs1, Ks0, Vs0, kt + 1);
    }
#undef LOADKV
#undef STOREKV
#undef ABODY

    #pragma unroll
    for (int r = 0; r < 4; ++r) {
        const float inv = 1.f / l_i[r];
        const int qg = q0 + wv * 16 + (lane >> 4) * 4 + r;
        #pragma unroll
        for (int n = 0; n < 4; ++n) {
            const int d = n * 16 + (lane & 15);
            O[qkbase + (size_t)qg * 1024 + d] = f2bf(o_acc[n][r] * inv);
        }
    }
}

// ---------------------------------------------------------------------------
// LayerNorm, bf16 in/out, fp32 stats. One block (256) per row of 1024.
// ---------------------------------------------------------------------------
__global__ __launch_bounds__(256) void ln_bf16_kernel(
        const u16* __restrict__ X, const float* __restrict__ g,
        const float* __restrict__ bta, u16* __restrict__ Y)
{
    __shared__ float red[4];
    const int row = blockIdx.x, tid = threadIdx.x;
    const int wave = tid >> 6, lane = tid & 63;

    const uint2 u = *(const uint2*)(X + (size_t)row * 1024 + tid * 4);
    const float x0 = bflo(u.x), x1 = bfhi(u.x), x2 = bflo(u.y), x3 = bfhi(u.y);

    float s = x0 + x1 + x2 + x3;
    #pragma unroll
    for (int off = 32; off; off >>= 1) s += __shfl_xor(s, off);
    if (lane == 0) red[wave] = s;
    __syncthreads();
    const float mu = (red[0] + red[1] + red[2] + red[3]) * (1.f / 1024.f);
    __syncthreads();

    const float d0 = x0 - mu, d1 = x1 - mu, d2 = x2 - mu, d3 = x3 - mu;
    float s2 = d0 * d0 + d1 * d1 + d2 * d2 + d3 * d3;
    #pragma unroll
    for (int off = 32; off; off >>= 1) s2 += __shfl_xor(s2, off);
    if (lane == 0) red[wave] = s2;
    __syncthreads();
    const float var = (red[0] + red[1] + red[2] + red[3]) * (1.f / 1024.f);
    const float rs = rsqrtf(var + 1e-5f);

    const float4 gg = ((const float4*)g)[tid];
    const float4 bb = ((const float4*)bta)[tid];
    ushort4 o;
    o.x = f2bf(d0 * rs * gg.x + bb.x);
    o.y = f2bf(d1 * rs * gg.y + bb.y);
    o.z = f2bf(d2 * rs * gg.z + bb.z);
    o.w = f2bf(d3 * rs * gg.w + bb.w);
    *(ushort4*)(Y + (size_t)row * 1024 + tid * 4) = o;
}

// fp32 in-place LayerNorm (final output)
__global__ __launch_bounds__(256) void ln_kernel(
        const float* X, const float* __restrict__ g,
        const float* __restrict__ bta, float* Y)
{
    __shared__ float red[4];
    const int row = blockIdx.x;
    const int tid = threadIdx.x;
    const int wave = tid >> 6, lane = tid & 63;

    const float4 v = ((const float4*)(X + (size_t)row * 1024))[tid];

    float s = v.x + v.y + v.z + v.w;
    #pragma unroll
    for (int off = 32; off; off >>= 1) s += __shfl_xor(s, off);
    if (lane == 0) red[wave] = s;
    __syncthreads();
    const float mu = (red[0] + red[1] + red[2] + red[3]) * (1.f / 1024.f);
    __syncthreads();

    const float dx = v.x - mu, dy = v.y - mu, dz = v.z - mu, dw = v.w - mu;
    float s2 = dx * dx + dy * dy + dz * dz + dw * dw;
    #pragma unroll
    for (int off = 32; off; off >>= 1) s2 += __shfl_xor(s2, off);
    if (lane == 0) red[wave] = s2;
    __syncthreads();
    const float var = (red[0] + red[1] + red[2] + red[3]) * (1.f / 1024.f);
    const float rs = rsqrtf(var + 1e-5f);

    const float4 gg = ((const float4*)g)[tid];
    const float4 bb = ((const float4*)bta)[tid];
    float4 o;
    o.x = dx * rs * gg.x + bb.x;
    o.y = dy * rs * gg.y + bb.y;
    o.z = dz * rs * gg.z + bb.z;
    o.w = dw * rs * gg.w + bb.w;
    ((float4*)(Y + (size_t)row * 1024))[tid] = o;
}

// ---------------------------------------------------------------------------
extern "C" void kernel_launch(void* const* d_in, const int* in_sizes, int n_in,
                              void* d_out, int out_size, void* d_ws, size_t ws_size,
                              hipStream_t stream)
{
    const float* tgt    = (const float*)d_in[0];
    const float* mem    = (const float*)d_in[1];
    const float* sa_wq  = (const float*)d_in[3];
    const float* sa_bq  = (const float*)d_in[4];
    const float* sa_wk  = (const float*)d_in[5];
    const float* sa_bk  = (const float*)d_in[6];
    const float* sa_wv  = (const float*)d_in[7];
    const float* sa_bv  = (const float*)d_in[8];
    const float* sa_wo  = (const float*)d_in[9];
    const float* sa_bo  = (const float*)d_in[10];
    const float* ca_wq  = (const float*)d_in[11];
    const float* ca_bq  = (const float*)d_in[12];
    const float* ca_wk  = (const float*)d_in[13];
    const float* ca_bk  = (const float*)d_in[14];
    const float* ca_wv  = (const float*)d_in[15];
    const float* ca_bv  = (const float*)d_in[16];
    const float* ca_wo  = (const float*)d_in[17];
    const float* ca_bo  = (const float*)d_in[18];
    const float* ffn_w1 = (const float*)d_in[19];
    const float* ffn_b1 = (const float*)d_in[20];
    const float* ffn_w2 = (const float*)d_in[21];
    const float* ffn_b2 = (const float*)d_in[22];
    const float* ln1_g  = (const float*)d_in[23];
    const float* ln1_b  = (const float*)d_in[24];
    const float* ln2_g  = (const float*)d_in[25];
    const float* ln2_b  = (const float*)d_in[26];
    const float* ln3_g  = (const float*)d_in[27];
    const float* ln3_b  = (const float*)d_in[28];

    float* out = (float*)d_out;
    u16* wsb = (u16*)d_ws;
    const size_t M1 = 1024 * 1024;

    // weights (bf16, transposed [N][K]): 32 MB.
    u16* Wsq = wsb + 0 * M1;
    u16* Wsk = wsb + 1 * M1;
    u16* Wsv = wsb + 2 * M1;
    u16* Wso = wsb + 3 * M1;
    u16* Wcq = wsb + 4 * M1;
    u16* Wck = wsb + 5 * M1;
    u16* Wcv = wsb + 6 * M1;
    u16* Wco = wsb + 7 * M1;
    u16* Wf1 = wsb + 8 * M1;    // [4096][1024]
    u16* Wf2 = wsb + 12 * M1;   // [1024][4096]

    // activation slots (bf16, 4M elems each): 48 MB
    u16* sl = wsb + 16 * M1;
    u16* s0 = sl + 0 * 4 * M1;
    u16* s1 = sl + 4 * M1;
    u16* s2 = sl + 8 * M1;
    u16* s3 = sl + 12 * M1;
    u16* s4 = sl + 16 * M1;
    u16* s5 = sl + 20 * M1;
    u16* H  = s0;               // FFN hidden [4096][4096] aliases s0..s3 (dead)

    // f32 bias concat buffers (after slots; +20 KB)
    float* biasQKV = (float*)(wsb + 40 * M1);   // [3072]
    float* biasKV  = biasQKV + 3072;            // [2048]

    const dim3 blk(256);
    const dim3 gqkv(48, 32);    // N=3072 fused QKV (BN=64)
    const dim3 gkv(32, 32);     // N=2048 fused KV
    const dim3 g1(16, 32);      // N=1024 GEMM
    const dim3 g4(64, 32);      // N=4096 GEMM (FFN1)
    const dim3 ga(64, 16);      // attention
    const dim3 gln(4096);

    // ---- weight/bias prep ----
    TrwB tb;
    tb.w[0] = sa_wq; tb.o[0] = Wsq;
    tb.w[1] = sa_wk; tb.o[1] = Wsk;
    tb.w[2] = sa_wv; tb.o[2] = Wsv;
    tb.w[3] = sa_wo; tb.o[3] = Wso;
    tb.w[4] = ca_wq; tb.o[4] = Wcq;
    tb.w[5] = ca_wk; tb.o[5] = Wck;
    tb.w[6] = ca_wv; tb.o[6] = Wcv;
    tb.w[7] = ca_wo; tb.o[7] = Wco;
    trw8_kernel<<<dim3(16, 16, 8), blk, 0, stream>>>(tb);
    trw_kernel<<<dim3(64, 16), blk, 0, stream>>>(ffn_w1, Wf1, 1024, 4096);
    trw_kernel<<<dim3(16, 64), blk, 0, stream>>>(ffn_w2, Wf2, 4096, 1024);
    bcat_kernel<<<12, blk, 0, stream>>>(sa_bq, sa_bk, sa_bv, biasQKV, 3072);
    bcat_kernel<<<8, blk, 0, stream>>>(ca_bk, ca_bv, ca_bv, biasKV, 2048);
    cvt_kernel<<<2048, blk, 0, stream>>>(tgt, s0, 1024 * 1024);
    cvt_kernel<<<2048, blk, 0, stream>>>(mem, s1, 1024 * 1024);

    // ---- self-attention ----
    // fused QKV: Q->s2, K->s3, Vt->s4
    gemm_mfma<5><<<gqkv, blk, 0, stream>>>(s0, Wsq, biasQKV, nullptr,
                                           s2, s3, s4, 3072, 1024);
    fattn_mfma<1><<<ga, blk, 0, stream>>>(s2, s3, s4, s5);
    gemm_mfma<2><<<g1, blk, 0, stream>>>(s5, Wso, sa_bo, s0, s2, nullptr, nullptr, 1024, 1024);
    ln_bf16_kernel<<<gln, blk, 0, stream>>>(s2, ln1_g, ln1_b, s3);     // x1 = s3

    // ---- cross-attention ----
    gemm_mfma<0><<<g1, blk, 0, stream>>>(s3, Wcq, ca_bq, nullptr, s2, nullptr, nullptr, 1024, 1024);
    // fused KV from memory: K->s4, Vt->s5
    gemm_mfma<6><<<gkv, blk, 0, stream>>>(s1, Wck, biasKV, nullptr,
                                          s4, s5, nullptr, 2048, 1024);
    fattn_mfma<0><<<ga, blk, 0, stream>>>(s2, s4, s5, s0);
    gemm_mfma<2><<<g1, blk, 0, stream>>>(s0, Wco, ca_bo, s3, s2, nullptr, nullptr, 1024, 1024);
    ln_bf16_kernel<<<gln, blk, 0, stream>>>(s2, ln2_g, ln2_b, s4);     // x2 = s4

    // ---- FFN ----
    gemm_mfma<1><<<g4, blk, 0, stream>>>(s4, Wf1, ffn_b1, nullptr, H, nullptr, nullptr, 4096, 1024);
    gemm_mfma<3><<<g1, blk, 0, stream>>>(H, Wf2, ffn_b2, s4, out, nullptr, nullptr, 1024, 4096);
    ln_kernel<<<gln, blk, 0, stream>>>(out, ln3_g, ln3_b, out);
}

// Round 9
// 375.134 us; speedup vs baseline: 22.2371x; 1.0645x over previous
//
#include <hip/hip_runtime.h>
#include <hip/hip_bf16.h>

typedef unsigned short u16;
typedef __attribute__((ext_vector_type(8))) short bf16x8;
typedef __attribute__((ext_vector_type(4))) float floatx4;

__device__ inline float u2f(unsigned u) { union { unsigned i; float f; } x; x.i = u; return x.f; }
__device__ inline float bflo(unsigned p) { return u2f(p << 16); }
__device__ inline float bfhi(unsigned p) { return u2f(p & 0xffff0000u); }
__device__ inline u16 f2bf(float f) {
    union { __hip_bfloat16 h; u16 u; } x;
    x.h = __float2bfloat16(f);
    return x.u;
}
__device__ inline unsigned pk2bf(float lo, float hi) {
    return ((unsigned)f2bf(hi) << 16) | f2bf(lo);
}

#define GLDS(g, l) __builtin_amdgcn_global_load_lds( \
    (const __attribute__((address_space(1))) void*)(g), \
    (__attribute__((address_space(3))) void*)(l), 16, 0, 0)

// ---------------------------------------------------------------------------
// bf16 MFMA GEMM: C[M,N] = A[M,K] @ Bt[N,K]^T + bias (+res) (+relu)
// 128x64 tile, 4 waves, 16x16x32 MFMA, BK=32, XCD-chunked swizzle,
// 3-buffer counted-vmcnt pipeline (unchanged from round 8).
// EPI: 0 bf16, 1 +relu, 2 +bf16 res, 3 f32+res, 5 seg QKV, 6 seg KV.
// ---------------------------------------------------------------------------
template<int EPI>
__global__ __launch_bounds__(256, 2) void gemm_mfma(
        const u16* __restrict__ A, const u16* __restrict__ Bt,
        const float* __restrict__ bias, const u16* __restrict__ res,
        void* __restrict__ Cv, u16* __restrict__ o1, u16* __restrict__ o2,
        int N, int K)
{
    __shared__ u16 As0[128 * 32];
    __shared__ u16 Bs0[64 * 32];
    __shared__ u16 As1[128 * 32];
    __shared__ u16 Bs1[64 * 32];
    __shared__ u16 As2[128 * 32];
    __shared__ u16 Bs2[64 * 32];

    const int tid = threadIdx.x;
    const int lane = tid & 63, wv = tid >> 6;
    const int wr = wv >> 1, wc = wv & 1;

    const int gx = gridDim.x;
    const int nwg = gx * gridDim.y;
    const int bid0 = blockIdx.y * gx + blockIdx.x;
    const int nbid = (bid0 & 7) * (nwg >> 3) + (bid0 >> 3);
    const int bx = nbid % gx, by = nbid / gx;
    const int row0 = by * 128, col0 = bx * 64;

    const u16* pa[2];
    int ldst[2];
    #pragma unroll
    for (int i = 0; i < 2; ++i) {
        const int idx = i * 256 + tid;
        const int r = idx >> 2;
        const int kob = (idx & 3) << 4;
        const int sw = kob ^ (((r >> 1) & 3) << 4);
        pa[i] = A + (size_t)(row0 + r) * K + (sw >> 1);
        ldst[i] = idx * 8;
    }
    const int rB = tid >> 2;
    const int kobB = (tid & 3) << 4;
    const int swB = kobB ^ (((rB >> 1) & 3) << 4);
    const u16* pb = Bt + (size_t)(col0 + rB) * K + (swB >> 1);
    const int ldstB = tid * 8;

    int offa[4], offb[2];
    const int rsel = lane & 15, slot = lane >> 4;
    #pragma unroll
    for (int m = 0; m < 4; ++m) {
        const int ra = wr * 64 + m * 16 + rsel;
        offa[m] = ra * 32 + (((slot << 4) ^ (((ra >> 1) & 3) << 4)) >> 1);
    }
    #pragma unroll
    for (int n = 0; n < 2; ++n) {
        const int rb = wc * 32 + n * 16 + rsel;
        offb[n] = rb * 32 + (((slot << 4) ^ (((rb >> 1) & 3) << 4)) >> 1);
    }

    floatx4 acc[4][2] = {};

#define STAGE(AA, BB, t) do {                                   \
        const int ko_ = (t) << 5;                               \
        GLDS(pa[0] + ko_, &AA[ldst[0]]);                        \
        GLDS(pa[1] + ko_, &AA[ldst[1]]);                        \
        GLDS(pb + ko_, &BB[ldstB]);                             \
    } while (0)

#define COMPUTE(AA, BB) do {                                    \
        bf16x8 af[4], bfr[2];                                   \
        _Pragma("unroll")                                       \
        for (int m = 0; m < 4; ++m) af[m] = *(const bf16x8*)&AA[offa[m]]; \
        _Pragma("unroll")                                       \
        for (int n = 0; n < 2; ++n) bfr[n] = *(const bf16x8*)&BB[offb[n]]; \
        _Pragma("unroll")                                       \
        for (int m = 0; m < 4; ++m)                             \
            _Pragma("unroll")                                   \
            for (int n = 0; n < 2; ++n)                         \
                acc[m][n] = __builtin_amdgcn_mfma_f32_16x16x32_bf16( \
                        af[m], bfr[n], acc[m][n], 0, 0, 0);     \
    } while (0)

#define PHASE(CA, CB, NA, NB, t) do {                           \
        if ((t) < nkt - 1) asm volatile("s_waitcnt vmcnt(3)" ::: "memory"); \
        else               asm volatile("s_waitcnt vmcnt(0)" ::: "memory"); \
        __builtin_amdgcn_s_barrier();                           \
        __builtin_amdgcn_sched_barrier(0);                      \
        if ((t) + 2 < nkt) STAGE(NA, NB, (t) + 2);              \
        COMPUTE(CA, CB);                                        \
    } while (0)

    const int nkt = K >> 5;
    STAGE(As0, Bs0, 0);
    STAGE(As1, Bs1, 1);
    int t = 0;
    for (; t + 3 <= nkt; t += 3) {
        PHASE(As0, Bs0, As2, Bs2, t);
        PHASE(As1, Bs1, As0, Bs0, t + 1);
        PHASE(As2, Bs2, As1, Bs1, t + 2);
    }
    if (t < nkt)     PHASE(As0, Bs0, As2, Bs2, t);
    if (t + 1 < nkt) PHASE(As1, Bs1, As0, Bs0, t + 1);
#undef STAGE
#undef COMPUTE
#undef PHASE

    const int cr4 = (lane >> 4) * 4;
    const int cc = lane & 15;

    if (EPI == 5 || EPI == 6) {
        const int seg = col0 >> 10;
        const int vtseg = (EPI == 5) ? 2 : 1;
        u16* dst;
        if (EPI == 5) dst = (seg == 0) ? (u16*)Cv : (seg == 1 ? o1 : o2);
        else          dst = (seg == 0) ? (u16*)Cv : o1;

        if (seg == vtseg) {
            #pragma unroll
            for (int n = 0; n < 2; ++n) {
                const int col = col0 + wc * 32 + n * 16 + cc;
                const float bv = bias[col];
                const int vcol = col & 1023;
                const int h = vcol >> 6, d = vcol & 63;
                #pragma unroll
                for (int m = 0; m < 4; ++m) {
                    const int tk = row0 + wr * 64 + m * 16 + cr4;
                    const int b = tk >> 10;
                    ushort4 o4;
                    o4.x = f2bf(acc[m][n][0] + bv);
                    o4.y = f2bf(acc[m][n][1] + bv);
                    o4.z = f2bf(acc[m][n][2] + bv);
                    o4.w = f2bf(acc[m][n][3] + bv);
                    *(ushort4*)(dst +
                        (((size_t)(b * 16 + h) * 64 + d) * 1024 + (tk & 1023))) = o4;
                }
            }
        } else {
            #pragma unroll
            for (int n = 0; n < 2; ++n) {
                const int col = col0 + wc * 32 + n * 16 + cc;
                const float bv = bias[col];
                const int oc = col & 1023;
                #pragma unroll
                for (int m = 0; m < 4; ++m) {
                    const int rowb = row0 + wr * 64 + m * 16 + cr4;
                    #pragma unroll
                    for (int r = 0; r < 4; ++r)
                        dst[(size_t)(rowb + r) * 1024 + oc] = f2bf(acc[m][n][r] + bv);
                }
            }
        }
        return;
    }

    #pragma unroll
    for (int n = 0; n < 2; ++n) {
        const int col = col0 + wc * 32 + n * 16 + cc;
        const float bv = bias[col];
        #pragma unroll
        for (int m = 0; m < 4; ++m) {
            const int rowb = row0 + wr * 64 + m * 16 + cr4;
            #pragma unroll
            for (int r = 0; r < 4; ++r) {
                float v = acc[m][n][r] + bv;
                const size_t o = (size_t)(rowb + r) * N + col;
                if (EPI == 2 || EPI == 3) v += u2f((unsigned)res[o] << 16);
                if (EPI == 1) v = fmaxf(v, 0.f);
                if (EPI == 3) ((float*)Cv)[o] = v;
                else          ((u16*)Cv)[o] = f2bf(v);
            }
        }
    }
}

// ---------------------------------------------------------------------------
// Batched 1024x1024 weight convert+transpose (8 weights, one dispatch).
// ---------------------------------------------------------------------------
struct TrwB { const float* w[8]; u16* o[8]; };

__global__ __launch_bounds__(256) void trw8_kernel(TrwB p)
{
    __shared__ float ts[64][65];
    const int tid = threadIdx.x;
    const int n0 = blockIdx.x * 64, k0 = blockIdx.y * 64;
    const float* __restrict__ W = p.w[blockIdx.z];
    u16* __restrict__ Wt = p.o[blockIdx.z];
    const int tr = tid >> 4, tc4 = (tid & 15) * 4;
    #pragma unroll
    for (int i = 0; i < 4; ++i) {
        const float4 v = *(const float4*)(W + (size_t)(k0 + tr + i * 16) * 1024 + n0 + tc4);
        ts[tr + i * 16][tc4 + 0] = v.x;
        ts[tr + i * 16][tc4 + 1] = v.y;
        ts[tr + i * 16][tc4 + 2] = v.z;
        ts[tr + i * 16][tc4 + 3] = v.w;
    }
    __syncthreads();
    #pragma unroll
    for (int i = 0; i < 4; ++i) {
        const int nr = tr + i * 16;
        ushort4 o;
        o.x = f2bf(ts[tc4 + 0][nr]);
        o.y = f2bf(ts[tc4 + 1][nr]);
        o.z = f2bf(ts[tc4 + 2][nr]);
        o.w = f2bf(ts[tc4 + 3][nr]);
        *(ushort4*)(Wt + (size_t)(n0 + nr) * 1024 + k0 + tc4) = o;
    }
}

// generic weight transpose (FFN weights)
__global__ __launch_bounds__(256) void trw_kernel(
        const float* __restrict__ W, u16* __restrict__ Wt, int K, int N)
{
    __shared__ float ts[64][65];
    const int tid = threadIdx.x;
    const int n0 = blockIdx.x * 64, k0 = blockIdx.y * 64;
    const int tr = tid >> 4, tc4 = (tid & 15) * 4;
    #pragma unroll
    for (int i = 0; i < 4; ++i) {
        const float4 v = *(const float4*)(W + (size_t)(k0 + tr + i * 16) * N + n0 + tc4);
        ts[tr + i * 16][tc4 + 0] = v.x;
        ts[tr + i * 16][tc4 + 1] = v.y;
        ts[tr + i * 16][tc4 + 2] = v.z;
        ts[tr + i * 16][tc4 + 3] = v.w;
    }
    __syncthreads();
    #pragma unroll
    for (int i = 0; i < 4; ++i) {
        const int nr = tr + i * 16;
        ushort4 o;
        o.x = f2bf(ts[tc4 + 0][nr]);
        o.y = f2bf(ts[tc4 + 1][nr]);
        o.z = f2bf(ts[tc4 + 2][nr]);
        o.w = f2bf(ts[tc4 + 3][nr]);
        *(ushort4*)(Wt + (size_t)(n0 + nr) * K + k0 + tc4) = o;
    }
}

// fp32 -> bf16 elementwise (n4 = count/4)
__global__ __launch_bounds__(256) void cvt_kernel(
        const float* __restrict__ in, u16* __restrict__ out, int n4)
{
    for (int i = blockIdx.x * 256 + threadIdx.x; i < n4; i += gridDim.x * 256) {
        const float4 v = ((const float4*)in)[i];
        ushort4 o;
        o.x = f2bf(v.x); o.y = f2bf(v.y); o.z = f2bf(v.z); o.w = f2bf(v.w);
        ((ushort4*)out)[i] = o;
    }
}

// concat up to 3 bias vectors of 1024 into one f32 buffer
__global__ __launch_bounds__(256) void bcat_kernel(
        const float* __restrict__ b0, const float* __restrict__ b1,
        const float* __restrict__ b2, float* __restrict__ o, int n)
{
    const int i = blockIdx.x * 256 + threadIdx.x;
    if (i >= n) return;
    const float* s = (i < 1024) ? b0 : (i < 2048 ? b1 : b2);
    o[i] = s[i & 1023];
}

// ---------------------------------------------------------------------------
// MFMA flash attention, SWAPPED-OPERAND form.
// S^T = mfma(K, Q): C/D col = q -> each lane owns one full q-row of S.
// Softmax: 15 in-lane ops + 2 shfl_xor(16/32); m/l are per-lane scalars.
// PV: O^T = mfma(Vt, P^T); P staged to LDS pre-packed in B-frag layout
// (4x b64 writes, 2x b128 reads). O^T transposed back via LDS once per block.
// Q,K: [4096][1024] bf16 (head h at cols h*64..+64).
// Vt: [b*16+h][64 d][1024 t] bf16. Block = 4 waves, 64 q-rows. Grid (64,16).
// LDS 24 KB: Ks + Vs + Ps (P, then O^T staging).
// ---------------------------------------------------------------------------
template<int CAUSAL>
__global__ __launch_bounds__(256) void fattn_mfma(
        const u16* __restrict__ Q, const u16* __restrict__ K,
        const u16* __restrict__ Vt, u16* __restrict__ O)
{
    __shared__ u16 Ks[64 * 64];
    __shared__ u16 Vs[64 * 64];
    __shared__ u16 Ps[64 * 64];

    const int tid = threadIdx.x;
    const int lane = tid & 63, wv = tid >> 6;
    const int g = lane >> 4, qx = lane & 15;
    const int bh = blockIdx.x;
    const int b = bh >> 4, h = bh & 15;
    const int qt = blockIdx.y, q0 = qt * 64;
    const float SCL = 0.18033688011f;   // 0.125 * log2(e)

    const size_t qkbase = (size_t)b * (1024 * 1024) + (size_t)h * 64;
    const size_t vtbase = (size_t)bh * 64 * 1024;

    const int qr = wv * 16 + qx;        // local q row 0..63 (wave-partitioned)
    const int qg = q0 + qr;             // global q row
    const int swzq = (qr & 7) << 4;

    // Q fragments straight from global (B-operand: lane holds its q-row)
    bf16x8 qf[2];
    #pragma unroll
    for (int ks = 0; ks < 2; ++ks)
        qf[ks] = *(const bf16x8*)(Q + qkbase + (size_t)qg * 1024 + ks * 32 + g * 8);

    const int r0 = tid >> 3, s0 = tid & 7;   // staging geometry (+32 rows for i=1)

    float m_i = -1e30f, l_i = 0.f;
    floatx4 o_acc[4] = {};   // O^T: row d = n*16+4g+r, col q = qx

    const int ktmax = CAUSAL ? qt : 15;
    for (int kt = 0; kt <= ktmax; ++kt) {
        __syncthreads();
        #pragma unroll
        for (int i = 0; i < 2; ++i) {
            const int r = i * 32 + r0;
            const uint4 kv = *(const uint4*)(K + qkbase + (size_t)(kt * 64 + r) * 1024 + s0 * 8);
            *(uint4*)((char*)Ks + r * 128 + ((s0 ^ (r & 7)) << 4)) = kv;
            const uint4 vv = *(const uint4*)(Vt + vtbase + (size_t)r * 1024 + kt * 64 + s0 * 8);
            *(uint4*)((char*)Vs + r * 128 + ((s0 ^ (r & 7)) << 4)) = vv;
        }
        __syncthreads();

        // S^T[k][q] = mfma(K-frag, Q-frag)
        floatx4 sa[4] = {};
        #pragma unroll
        for (int ks = 0; ks < 2; ++ks) {
            #pragma unroll
            for (int m = 0; m < 4; ++m) {
                const int rr = m * 16 + qx;
                const int sl = ks * 4 + g;
                const bf16x8 kf = *(const bf16x8*)((char*)Ks + rr * 128 + ((sl ^ (rr & 7)) << 4));
                sa[m] = __builtin_amdgcn_mfma_f32_16x16x32_bf16(kf, qf[ks], sa[m], 0, 0, 0);
            }
        }

        // scale + mask; lane holds S[q][k] for k = m*16 + 4g + r
        float p[4][4];
        float mx = -1e30f;
        #pragma unroll
        for (int m = 0; m < 4; ++m)
            #pragma unroll
            for (int r = 0; r < 4; ++r) {
                float v = sa[m][r] * SCL;
                if (CAUSAL && kt == qt) {
                    const int kl = m * 16 + g * 4 + r;
                    if (kl > qr) v = -1e30f;
                }
                p[m][r] = v;
                mx = fmaxf(mx, v);
            }
        mx = fmaxf(mx, __shfl_xor(mx, 16));
        mx = fmaxf(mx, __shfl_xor(mx, 32));

        const float mn = fmaxf(m_i, mx);
        const float al = exp2f(m_i - mn);
        m_i = mn;
        float rs = 0.f;
        #pragma unroll
        for (int m = 0; m < 4; ++m)
            #pragma unroll
            for (int r = 0; r < 4; ++r) { p[m][r] = exp2f(p[m][r] - mn); rs += p[m][r]; }
        rs += __shfl_xor(rs, 16);
        rs += __shfl_xor(rs, 32);
        l_i = l_i * al + rs;
        #pragma unroll
        for (int n = 0; n < 4; ++n) o_acc[n] *= al;

        // P -> LDS, pre-packed bf16 in B-frag-ready layout (4x b64/lane)
        #pragma unroll
        for (int m = 0; m < 4; ++m) {
            uint2 pk;
            pk.x = pk2bf(p[m][0], p[m][1]);
            pk.y = pk2bf(p[m][2], p[m][3]);
            *(uint2*)((char*)Ps + qr * 128 + ((m * 32 + g * 8) ^ swzq)) = pk;
        }
        // same-wave RAW (each wave's rows are private) -> no barrier

        // O^T += mfma(Vt-frag, P^T-frag)
        #pragma unroll
        for (int ks2 = 0; ks2 < 2; ++ks2) {
            const bf16x8 pf = *(const bf16x8*)((char*)Ps + qr * 128 + ((ks2 * 64 + g * 16) ^ swzq));
            #pragma unroll
            for (int n = 0; n < 4; ++n) {
                const int rv = n * 16 + qx;
                const int sl = ks2 * 4 + g;
                const bf16x8 vf = *(const bf16x8*)((char*)Vs + rv * 128 + ((sl ^ (rv & 7)) << 4));
                o_acc[n] = __builtin_amdgcn_mfma_f32_16x16x32_bf16(vf, pf, o_acc[n], 0, 0, 0);
            }
        }
    }

    // epilogue: normalize, transpose O^T -> O through Ps (wave-private rows)
    const float inv = 1.f / l_i;
    #pragma unroll
    for (int n = 0; n < 4; ++n) {
        uint2 ov;
        ov.x = pk2bf(o_acc[n][0] * inv, o_acc[n][1] * inv);
        ov.y = pk2bf(o_acc[n][2] * inv, o_acc[n][3] * inv);
        *(uint2*)((char*)Ps + qr * 128 + ((n * 32 + g * 8) ^ swzq)) = ov;
    }
    const int orow = wv * 16 + (lane >> 2);
    const int swzo = (orow & 7) << 4;
    #pragma unroll
    for (int i = 0; i < 2; ++i) {
        const int cb = ((lane & 3) * 2 + i) * 16;    // byte chunk within row
        const uint4 ov = *(const uint4*)((char*)Ps + orow * 128 + (cb ^ swzo));
        *(uint4*)(O + qkbase + (size_t)(q0 + orow) * 1024 + cb / 2) = ov;
    }
}

// ---------------------------------------------------------------------------
// LayerNorm, bf16 in/out, fp32 stats. One block (256) per row of 1024.
// ---------------------------------------------------------------------------
__global__ __launch_bounds__(256) void ln_bf16_kernel(
        const u16* __restrict__ X, const float* __restrict__ g,
        const float* __restrict__ bta, u16* __restrict__ Y)
{
    __shared__ float red[4];
    const int row = blockIdx.x, tid = threadIdx.x;
    const int wave = tid >> 6, lane = tid & 63;

    const uint2 u = *(const uint2*)(X + (size_t)row * 1024 + tid * 4);
    const float x0 = bflo(u.x), x1 = bfhi(u.x), x2 = bflo(u.y), x3 = bfhi(u.y);

    float s = x0 + x1 + x2 + x3;
    #pragma unroll
    for (int off = 32; off; off >>= 1) s += __shfl_xor(s, off);
    if (lane == 0) red[wave] = s;
    __syncthreads();
    const float mu = (red[0] + red[1] + red[2] + red[3]) * (1.f / 1024.f);
    __syncthreads();

    const float d0 = x0 - mu, d1 = x1 - mu, d2 = x2 - mu, d3 = x3 - mu;
    float s2 = d0 * d0 + d1 * d1 + d2 * d2 + d3 * d3;
    #pragma unroll
    for (int off = 32; off; off >>= 1) s2 += __shfl_xor(s2, off);
    if (lane == 0) red[wave] = s2;
    __syncthreads();
    const float var = (red[0] + red[1] + red[2] + red[3]) * (1.f / 1024.f);
    const float rs = rsqrtf(var + 1e-5f);

    const float4 gg = ((const float4*)g)[tid];
    const float4 bb = ((const float4*)bta)[tid];
    ushort4 o;
    o.x = f2bf(d0 * rs * gg.x + bb.x);
    o.y = f2bf(d1 * rs * gg.y + bb.y);
    o.z = f2bf(d2 * rs * gg.z + bb.z);
    o.w = f2bf(d3 * rs * gg.w + bb.w);
    *(ushort4*)(Y + (size_t)row * 1024 + tid * 4) = o;
}

// fp32 in-place LayerNorm (final output)
__global__ __launch_bounds__(256) void ln_kernel(
        const float* X, const float* __restrict__ g,
        const float* __restrict__ bta, float* Y)
{
    __shared__ float red[4];
    const int row = blockIdx.x;
    const int tid = threadIdx.x;
    const int wave = tid >> 6, lane = tid & 63;

    const float4 v = ((const float4*)(X + (size_t)row * 1024))[tid];

    float s = v.x + v.y + v.z + v.w;
    #pragma unroll
    for (int off = 32; off; off >>= 1) s += __shfl_xor(s, off);
    if (lane == 0) red[wave] = s;
    __syncthreads();
    const float mu = (red[0] + red[1] + red[2] + red[3]) * (1.f / 1024.f);
    __syncthreads();

    const float dx = v.x - mu, dy = v.y - mu, dz = v.z - mu, dw = v.w - mu;
    float s2 = dx * dx + dy * dy + dz * dz + dw * dw;
    #pragma unroll
    for (int off = 32; off; off >>= 1) s2 += __shfl_xor(s2, off);
    if (lane == 0) red[wave] = s2;
    __syncthreads();
    const float var = (red[0] + red[1] + red[2] + red[3]) * (1.f / 1024.f);
    const float rs = rsqrtf(var + 1e-5f);

    const float4 gg = ((const float4*)g)[tid];
    const float4 bb = ((const float4*)bta)[tid];
    float4 o;
    o.x = dx * rs * gg.x + bb.x;
    o.y = dy * rs * gg.y + bb.y;
    o.z = dz * rs * gg.z + bb.z;
    o.w = dw * rs * gg.w + bb.w;
    ((float4*)(Y + (size_t)row * 1024))[tid] = o;
}

// ---------------------------------------------------------------------------
extern "C" void kernel_launch(void* const* d_in, const int* in_sizes, int n_in,
                              void* d_out, int out_size, void* d_ws, size_t ws_size,
                              hipStream_t stream)
{
    const float* tgt    = (const float*)d_in[0];
    const float* mem    = (const float*)d_in[1];
    const float* sa_wq  = (const float*)d_in[3];
    const float* sa_bq  = (const float*)d_in[4];
    const float* sa_wk  = (const float*)d_in[5];
    const float* sa_bk  = (const float*)d_in[6];
    const float* sa_wv  = (const float*)d_in[7];
    const float* sa_bv  = (const float*)d_in[8];
    const float* sa_wo  = (const float*)d_in[9];
    const float* sa_bo  = (const float*)d_in[10];
    const float* ca_wq  = (const float*)d_in[11];
    const float* ca_bq  = (const float*)d_in[12];
    const float* ca_wk  = (const float*)d_in[13];
    const float* ca_bk  = (const float*)d_in[14];
    const float* ca_wv  = (const float*)d_in[15];
    const float* ca_bv  = (const float*)d_in[16];
    const float* ca_wo  = (const float*)d_in[17];
    const float* ca_bo  = (const float*)d_in[18];
    const float* ffn_w1 = (const float*)d_in[19];
    const float* ffn_b1 = (const float*)d_in[20];
    const float* ffn_w2 = (const float*)d_in[21];
    const float* ffn_b2 = (const float*)d_in[22];
    const float* ln1_g  = (const float*)d_in[23];
    const float* ln1_b  = (const float*)d_in[24];
    const float* ln2_g  = (const float*)d_in[25];
    const float* ln2_b  = (const float*)d_in[26];
    const float* ln3_g  = (const float*)d_in[27];
    const float* ln3_b  = (const float*)d_in[28];

    float* out = (float*)d_out;
    u16* wsb = (u16*)d_ws;
    const size_t M1 = 1024 * 1024;

    // weights (bf16, transposed [N][K]): 32 MB.
    u16* Wsq = wsb + 0 * M1;
    u16* Wsk = wsb + 1 * M1;
    u16* Wsv = wsb + 2 * M1;
    u16* Wso = wsb + 3 * M1;
    u16* Wcq = wsb + 4 * M1;
    u16* Wck = wsb + 5 * M1;
    u16* Wcv = wsb + 6 * M1;
    u16* Wco = wsb + 7 * M1;
    u16* Wf1 = wsb + 8 * M1;    // [4096][1024]
    u16* Wf2 = wsb + 12 * M1;   // [1024][4096]

    // activation slots (bf16, 4M elems each): 48 MB
    u16* sl = wsb + 16 * M1;
    u16* s0 = sl + 0 * 4 * M1;
    u16* s1 = sl + 4 * M1;
    u16* s2 = sl + 8 * M1;
    u16* s3 = sl + 12 * M1;
    u16* s4 = sl + 16 * M1;
    u16* s5 = sl + 20 * M1;
    u16* H  = s0;               // FFN hidden [4096][4096] aliases s0..s3 (dead)

    // f32 bias concat buffers (after slots; +20 KB)
    float* biasQKV = (float*)(wsb + 40 * M1);   // [3072]
    float* biasKV  = biasQKV + 3072;            // [2048]

    const dim3 blk(256);
    const dim3 gqkv(48, 32);    // N=3072 fused QKV (BN=64)
    const dim3 gkv(32, 32);     // N=2048 fused KV
    const dim3 g1(16, 32);      // N=1024 GEMM
    const dim3 g4(64, 32);      // N=4096 GEMM (FFN1)
    const dim3 ga(64, 16);      // attention
    const dim3 gln(4096);

    // ---- weight/bias prep ----
    TrwB tb;
    tb.w[0] = sa_wq; tb.o[0] = Wsq;
    tb.w[1] = sa_wk; tb.o[1] = Wsk;
    tb.w[2] = sa_wv; tb.o[2] = Wsv;
    tb.w[3] = sa_wo; tb.o[3] = Wso;
    tb.w[4] = ca_wq; tb.o[4] = Wcq;
    tb.w[5] = ca_wk; tb.o[5] = Wck;
    tb.w[6] = ca_wv; tb.o[6] = Wcv;
    tb.w[7] = ca_wo; tb.o[7] = Wco;
    trw8_kernel<<<dim3(16, 16, 8), blk, 0, stream>>>(tb);
    trw_kernel<<<dim3(64, 16), blk, 0, stream>>>(ffn_w1, Wf1, 1024, 4096);
    trw_kernel<<<dim3(16, 64), blk, 0, stream>>>(ffn_w2, Wf2, 4096, 1024);
    bcat_kernel<<<12, blk, 0, stream>>>(sa_bq, sa_bk, sa_bv, biasQKV, 3072);
    bcat_kernel<<<8, blk, 0, stream>>>(ca_bk, ca_bv, ca_bv, biasKV, 2048);
    cvt_kernel<<<2048, blk, 0, stream>>>(tgt, s0, 1024 * 1024);
    cvt_kernel<<<2048, blk, 0, stream>>>(mem, s1, 1024 * 1024);

    // ---- self-attention ----
    // fused QKV: Q->s2, K->s3, Vt->s4
    gemm_mfma<5><<<gqkv, blk, 0, stream>>>(s0, Wsq, biasQKV, nullptr,
                                           s2, s3, s4, 3072, 1024);
    fattn_mfma<1><<<ga, blk, 0, stream>>>(s2, s3, s4, s5);
    gemm_mfma<2><<<g1, blk, 0, stream>>>(s5, Wso, sa_bo, s0, s2, nullptr, nullptr, 1024, 1024);
    ln_bf16_kernel<<<gln, blk, 0, stream>>>(s2, ln1_g, ln1_b, s3);     // x1 = s3

    // ---- cross-attention ----
    gemm_mfma<0><<<g1, blk, 0, stream>>>(s3, Wcq, ca_bq, nullptr, s2, nullptr, nullptr, 1024, 1024);
    // fused KV from memory: K->s4, Vt->s5
    gemm_mfma<6><<<gkv, blk, 0, stream>>>(s1, Wck, biasKV, nullptr,
                                          s4, s5, nullptr, 2048, 1024);
    fattn_mfma<0><<<ga, blk, 0, stream>>>(s2, s4, s5, s0);
    gemm_mfma<2><<<g1, blk, 0, stream>>>(s0, Wco, ca_bo, s3, s2, nullptr, nullptr, 1024, 1024);
    ln_bf16_kernel<<<gln, blk, 0, stream>>>(s2, ln2_g, ln2_b, s4);     // x2 = s4

    // ---- FFN ----
    gemm_mfma<1><<<g4, blk, 0, stream>>>(s4, Wf1, ffn_b1, nullptr, H, nullptr, nullptr, 4096, 1024);
    gemm_mfma<3><<<g1, blk, 0, stream>>>(H, Wf2, ffn_b2, s4, out, nullptr, nullptr, 1024, 4096);
    ln_kernel<<<gln, blk, 0, stream>>>(out, ln3_g, ln3_b, out);
}

// Round 10
// 348.540 us; speedup vs baseline: 23.9338x; 1.0763x over previous
//
#include <hip/hip_runtime.h>
#include <hip/hip_bf16.h>

typedef unsigned short u16;
typedef __attribute__((ext_vector_type(8))) short bf16x8;
typedef __attribute__((ext_vector_type(4))) float floatx4;

__device__ inline float u2f(unsigned u) { union { unsigned i; float f; } x; x.i = u; return x.f; }
__device__ inline float bflo(unsigned p) { return u2f(p << 16); }
__device__ inline float bfhi(unsigned p) { return u2f(p & 0xffff0000u); }
__device__ inline u16 f2bf(float f) {
    union { __hip_bfloat16 h; u16 u; } x;
    x.h = __float2bfloat16(f);
    return x.u;
}
__device__ inline unsigned pk2bf(float lo, float hi) {
    return ((unsigned)f2bf(hi) << 16) | f2bf(lo);
}

#define GLDS(g, l) __builtin_amdgcn_global_load_lds( \
    (const __attribute__((address_space(1))) void*)(g), \
    (__attribute__((address_space(3))) void*)(l), 16, 0, 0)

// ---------------------------------------------------------------------------
// bf16 MFMA GEMM: C[M,N] = A[M,K] @ Bt[N,K]^T + bias (+res) (+relu)
// Tile 128 x (NF*32), 4 waves, 16x16x32 MFMA, BK=32, XCD-chunked swizzle,
// 3-buffer counted-vmcnt pipeline (T3+T4). NF=4 (BN=128) for wide GEMMs
// (better MFMA:ds_read ratio: 16:8); NF=2 (BN=64) for N=1024 (2 blocks/CU).
// EPI: 0 bf16, 1 +relu, 2 +bf16 res, 3 f32+res, 5 seg QKV, 6 seg KV.
// Vt layout: Vt[b*16+h][d][t], t fast.
// ---------------------------------------------------------------------------
template<int EPI, int NF>
__global__ __launch_bounds__(256, 2) void gemm_mfma(
        const u16* __restrict__ A, const u16* __restrict__ Bt,
        const float* __restrict__ bias, const u16* __restrict__ res,
        void* __restrict__ Cv, u16* __restrict__ o1, u16* __restrict__ o2,
        int N, int K)
{
    constexpr int BN = NF * 32;
    constexpr int BLOADS = BN / 64;          // B gload_lds per thread (1 or 2)

    __shared__ u16 As0[128 * 32];
    __shared__ u16 Bs0[BN * 32];
    __shared__ u16 As1[128 * 32];
    __shared__ u16 Bs1[BN * 32];
    __shared__ u16 As2[128 * 32];
    __shared__ u16 Bs2[BN * 32];

    const int tid = threadIdx.x;
    const int lane = tid & 63, wv = tid >> 6;
    const int wr = wv >> 1, wc = wv & 1;

    const int gx = gridDim.x;
    const int nwg = gx * gridDim.y;
    const int bid0 = blockIdx.y * gx + blockIdx.x;
    const int nbid = (bid0 & 7) * (nwg >> 3) + (bid0 >> 3);
    const int bx = nbid % gx, by = nbid / gx;
    const int row0 = by * 128, col0 = bx * BN;

    const u16* pa[2];
    int ldst[2];
    #pragma unroll
    for (int i = 0; i < 2; ++i) {
        const int idx = i * 256 + tid;
        const int r = idx >> 2;
        const int kob = (idx & 3) << 4;
        const int sw = kob ^ (((r >> 1) & 3) << 4);
        pa[i] = A + (size_t)(row0 + r) * K + (sw >> 1);
        ldst[i] = idx * 8;
    }
    const u16* pb[BLOADS];
    int ldstB[BLOADS];
    #pragma unroll
    for (int i = 0; i < BLOADS; ++i) {
        const int idx = i * 256 + tid;
        const int r = idx >> 2;
        const int kob = (idx & 3) << 4;
        const int sw = kob ^ (((r >> 1) & 3) << 4);
        pb[i] = Bt + (size_t)(col0 + r) * K + (sw >> 1);
        ldstB[i] = idx * 8;
    }

    int offa[4], offb[NF];
    const int rsel = lane & 15, slot = lane >> 4;
    #pragma unroll
    for (int m = 0; m < 4; ++m) {
        const int ra = wr * 64 + m * 16 + rsel;
        offa[m] = ra * 32 + (((slot << 4) ^ (((ra >> 1) & 3) << 4)) >> 1);
    }
    #pragma unroll
    for (int n = 0; n < NF; ++n) {
        const int rb = wc * (NF * 16) + n * 16 + rsel;
        offb[n] = rb * 32 + (((slot << 4) ^ (((rb >> 1) & 3) << 4)) >> 1);
    }

    floatx4 acc[4][NF] = {};

#define STAGE(AA, BB, t) do {                                   \
        const int ko_ = (t) << 5;                               \
        GLDS(pa[0] + ko_, &AA[ldst[0]]);                        \
        GLDS(pa[1] + ko_, &AA[ldst[1]]);                        \
        _Pragma("unroll")                                       \
        for (int i = 0; i < BLOADS; ++i)                        \
            GLDS(pb[i] + ko_, &BB[ldstB[i]]);                   \
    } while (0)

#define COMPUTE(AA, BB) do {                                    \
        bf16x8 af[4], bfr[NF];                                  \
        _Pragma("unroll")                                       \
        for (int m = 0; m < 4; ++m) af[m] = *(const bf16x8*)&AA[offa[m]]; \
        _Pragma("unroll")                                       \
        for (int n = 0; n < NF; ++n) bfr[n] = *(const bf16x8*)&BB[offb[n]]; \
        _Pragma("unroll")                                       \
        for (int m = 0; m < 4; ++m)                             \
            _Pragma("unroll")                                   \
            for (int n = 0; n < NF; ++n)                        \
                acc[m][n] = __builtin_amdgcn_mfma_f32_16x16x32_bf16( \
                        af[m], bfr[n], acc[m][n], 0, 0, 0);     \
    } while (0)

#define PHASE(CA, CB, NA, NB, t) do {                           \
        if ((t) < nkt - 1) {                                    \
            if constexpr (NF == 4)                              \
                asm volatile("s_waitcnt vmcnt(4)" ::: "memory");\
            else                                                \
                asm volatile("s_waitcnt vmcnt(3)" ::: "memory");\
        } else {                                                \
            asm volatile("s_waitcnt vmcnt(0)" ::: "memory");    \
        }                                                       \
        __builtin_amdgcn_s_barrier();                           \
        __builtin_amdgcn_sched_barrier(0);                      \
        if ((t) + 2 < nkt) STAGE(NA, NB, (t) + 2);              \
        COMPUTE(CA, CB);                                        \
    } while (0)

    const int nkt = K >> 5;          // 32 or 128 (nkt % 3 == 2)
    STAGE(As0, Bs0, 0);
    STAGE(As1, Bs1, 1);
    int t = 0;
    for (; t + 3 <= nkt; t += 3) {
        PHASE(As0, Bs0, As2, Bs2, t);
        PHASE(As1, Bs1, As0, Bs0, t + 1);
        PHASE(As2, Bs2, As1, Bs1, t + 2);
    }
    if (t < nkt)     PHASE(As0, Bs0, As2, Bs2, t);
    if (t + 1 < nkt) PHASE(As1, Bs1, As0, Bs0, t + 1);
#undef STAGE
#undef COMPUTE
#undef PHASE

    const int cr4 = (lane >> 4) * 4;
    const int cc = lane & 15;

    if (EPI == 5 || EPI == 6) {
        const int seg = col0 >> 10;                  // block-uniform (1024%BN==0)
        const int vtseg = (EPI == 5) ? 2 : 1;
        u16* dst;
        if (EPI == 5) dst = (seg == 0) ? (u16*)Cv : (seg == 1 ? o1 : o2);
        else          dst = (seg == 0) ? (u16*)Cv : o1;

        if (seg == vtseg) {
            #pragma unroll
            for (int n = 0; n < NF; ++n) {
                const int col = col0 + wc * (NF * 16) + n * 16 + cc;
                const float bv = bias[col];
                const int vcol = col & 1023;
                const int h = vcol >> 6, d = vcol & 63;
                #pragma unroll
                for (int m = 0; m < 4; ++m) {
                    const int tk = row0 + wr * 64 + m * 16 + cr4;
                    const int b = tk >> 10;
                    ushort4 o4;
                    o4.x = f2bf(acc[m][n][0] + bv);
                    o4.y = f2bf(acc[m][n][1] + bv);
                    o4.z = f2bf(acc[m][n][2] + bv);
                    o4.w = f2bf(acc[m][n][3] + bv);
                    *(ushort4*)(dst +
                        (((size_t)(b * 16 + h) * 64 + d) * 1024 + (tk & 1023))) = o4;
                }
            }
        } else {
            #pragma unroll
            for (int n = 0; n < NF; ++n) {
                const int col = col0 + wc * (NF * 16) + n * 16 + cc;
                const float bv = bias[col];
                const int oc = col & 1023;
                #pragma unroll
                for (int m = 0; m < 4; ++m) {
                    const int rowb = row0 + wr * 64 + m * 16 + cr4;
                    #pragma unroll
                    for (int r = 0; r < 4; ++r)
                        dst[(size_t)(rowb + r) * 1024 + oc] = f2bf(acc[m][n][r] + bv);
                }
            }
        }
        return;
    }

    #pragma unroll
    for (int n = 0; n < NF; ++n) {
        const int col = col0 + wc * (NF * 16) + n * 16 + cc;
        const float bv = bias[col];
        #pragma unroll
        for (int m = 0; m < 4; ++m) {
            const int rowb = row0 + wr * 64 + m * 16 + cr4;
            #pragma unroll
            for (int r = 0; r < 4; ++r) {
                float v = acc[m][n][r] + bv;
                const size_t o = (size_t)(rowb + r) * N + col;
                if (EPI == 2 || EPI == 3) v += u2f((unsigned)res[o] << 16);
                if (EPI == 1) v = fmaxf(v, 0.f);
                if (EPI == 3) ((float*)Cv)[o] = v;
                else          ((u16*)Cv)[o] = f2bf(v);
            }
        }
    }
}

// ---------------------------------------------------------------------------
// Batched 1024x1024 weight convert+transpose (8 weights, one dispatch).
// ---------------------------------------------------------------------------
struct TrwB { const float* w[8]; u16* o[8]; };

__global__ __launch_bounds__(256) void trw8_kernel(TrwB p)
{
    __shared__ float ts[64][65];
    const int tid = threadIdx.x;
    const int n0 = blockIdx.x * 64, k0 = blockIdx.y * 64;
    const float* __restrict__ W = p.w[blockIdx.z];
    u16* __restrict__ Wt = p.o[blockIdx.z];
    const int tr = tid >> 4, tc4 = (tid & 15) * 4;
    #pragma unroll
    for (int i = 0; i < 4; ++i) {
        const float4 v = *(const float4*)(W + (size_t)(k0 + tr + i * 16) * 1024 + n0 + tc4);
        ts[tr + i * 16][tc4 + 0] = v.x;
        ts[tr + i * 16][tc4 + 1] = v.y;
        ts[tr + i * 16][tc4 + 2] = v.z;
        ts[tr + i * 16][tc4 + 3] = v.w;
    }
    __syncthreads();
    #pragma unroll
    for (int i = 0; i < 4; ++i) {
        const int nr = tr + i * 16;
        ushort4 o;
        o.x = f2bf(ts[tc4 + 0][nr]);
        o.y = f2bf(ts[tc4 + 1][nr]);
        o.z = f2bf(ts[tc4 + 2][nr]);
        o.w = f2bf(ts[tc4 + 3][nr]);
        *(ushort4*)(Wt + (size_t)(n0 + nr) * 1024 + k0 + tc4) = o;
    }
}

// generic weight transpose (FFN weights)
__global__ __launch_bounds__(256) void trw_kernel(
        const float* __restrict__ W, u16* __restrict__ Wt, int K, int N)
{
    __shared__ float ts[64][65];
    const int tid = threadIdx.x;
    const int n0 = blockIdx.x * 64, k0 = blockIdx.y * 64;
    const int tr = tid >> 4, tc4 = (tid & 15) * 4;
    #pragma unroll
    for (int i = 0; i < 4; ++i) {
        const float4 v = *(const float4*)(W + (size_t)(k0 + tr + i * 16) * N + n0 + tc4);
        ts[tr + i * 16][tc4 + 0] = v.x;
        ts[tr + i * 16][tc4 + 1] = v.y;
        ts[tr + i * 16][tc4 + 2] = v.z;
        ts[tr + i * 16][tc4 + 3] = v.w;
    }
    __syncthreads();
    #pragma unroll
    for (int i = 0; i < 4; ++i) {
        const int nr = tr + i * 16;
        ushort4 o;
        o.x = f2bf(ts[tc4 + 0][nr]);
        o.y = f2bf(ts[tc4 + 1][nr]);
        o.z = f2bf(ts[tc4 + 2][nr]);
        o.w = f2bf(ts[tc4 + 3][nr]);
        *(ushort4*)(Wt + (size_t)(n0 + nr) * K + k0 + tc4) = o;
    }
}

// fp32 -> bf16 elementwise (n4 = count/4)
__global__ __launch_bounds__(256) void cvt_kernel(
        const float* __restrict__ in, u16* __restrict__ out, int n4)
{
    for (int i = blockIdx.x * 256 + threadIdx.x; i < n4; i += gridDim.x * 256) {
        const float4 v = ((const float4*)in)[i];
        ushort4 o;
        o.x = f2bf(v.x); o.y = f2bf(v.y); o.z = f2bf(v.z); o.w = f2bf(v.w);
        ((ushort4*)out)[i] = o;
    }
}

// concat up to 3 bias vectors of 1024 into one f32 buffer
__global__ __launch_bounds__(256) void bcat_kernel(
        const float* __restrict__ b0, const float* __restrict__ b1,
        const float* __restrict__ b2, float* __restrict__ o, int n)
{
    const int i = blockIdx.x * 256 + threadIdx.x;
    if (i >= n) return;
    const float* s = (i < 1024) ? b0 : (i < 2048 ? b1 : b2);
    o[i] = s[i & 1023];
}

// ---------------------------------------------------------------------------
// MFMA flash attention, SWAPPED-OPERAND form (unchanged from round 9).
// S^T = mfma(K, Q): each lane owns one full q-row; softmax is in-lane +
// 2 shfl_xor. PV: O^T = mfma(Vt, P^T), P pre-packed to LDS in B-frag layout.
// ---------------------------------------------------------------------------
template<int CAUSAL>
__global__ __launch_bounds__(256) void fattn_mfma(
        const u16* __restrict__ Q, const u16* __restrict__ K,
        const u16* __restrict__ Vt, u16* __restrict__ O)
{
    __shared__ u16 Ks[64 * 64];
    __shared__ u16 Vs[64 * 64];
    __shared__ u16 Ps[64 * 64];

    const int tid = threadIdx.x;
    const int lane = tid & 63, wv = tid >> 6;
    const int g = lane >> 4, qx = lane & 15;
    const int bh = blockIdx.x;
    const int b = bh >> 4, h = bh & 15;
    const int qt = blockIdx.y, q0 = qt * 64;
    const float SCL = 0.18033688011f;   // 0.125 * log2(e)

    const size_t qkbase = (size_t)b * (1024 * 1024) + (size_t)h * 64;
    const size_t vtbase = (size_t)bh * 64 * 1024;

    const int qr = wv * 16 + qx;
    const int qg = q0 + qr;
    const int swzq = (qr & 7) << 4;

    bf16x8 qf[2];
    #pragma unroll
    for (int ks = 0; ks < 2; ++ks)
        qf[ks] = *(const bf16x8*)(Q + qkbase + (size_t)qg * 1024 + ks * 32 + g * 8);

    const int r0 = tid >> 3, s0 = tid & 7;

    float m_i = -1e30f, l_i = 0.f;
    floatx4 o_acc[4] = {};

    const int ktmax = CAUSAL ? qt : 15;
    for (int kt = 0; kt <= ktmax; ++kt) {
        __syncthreads();
        #pragma unroll
        for (int i = 0; i < 2; ++i) {
            const int r = i * 32 + r0;
            const uint4 kv = *(const uint4*)(K + qkbase + (size_t)(kt * 64 + r) * 1024 + s0 * 8);
            *(uint4*)((char*)Ks + r * 128 + ((s0 ^ (r & 7)) << 4)) = kv;
            const uint4 vv = *(const uint4*)(Vt + vtbase + (size_t)r * 1024 + kt * 64 + s0 * 8);
            *(uint4*)((char*)Vs + r * 128 + ((s0 ^ (r & 7)) << 4)) = vv;
        }
        __syncthreads();

        floatx4 sa[4] = {};
        #pragma unroll
        for (int ks = 0; ks < 2; ++ks) {
            #pragma unroll
            for (int m = 0; m < 4; ++m) {
                const int rr = m * 16 + qx;
                const int sl = ks * 4 + g;
                const bf16x8 kf = *(const bf16x8*)((char*)Ks + rr * 128 + ((sl ^ (rr & 7)) << 4));
                sa[m] = __builtin_amdgcn_mfma_f32_16x16x32_bf16(kf, qf[ks], sa[m], 0, 0, 0);
            }
        }

        float p[4][4];
        float mx = -1e30f;
        #pragma unroll
        for (int m = 0; m < 4; ++m)
            #pragma unroll
            for (int r = 0; r < 4; ++r) {
                float v = sa[m][r] * SCL;
                if (CAUSAL && kt == qt) {
                    const int kl = m * 16 + g * 4 + r;
                    if (kl > qr) v = -1e30f;
                }
                p[m][r] = v;
                mx = fmaxf(mx, v);
            }
        mx = fmaxf(mx, __shfl_xor(mx, 16));
        mx = fmaxf(mx, __shfl_xor(mx, 32));

        const float mn = fmaxf(m_i, mx);
        const float al = exp2f(m_i - mn);
        m_i = mn;
        float rs = 0.f;
        #pragma unroll
        for (int m = 0; m < 4; ++m)
            #pragma unroll
            for (int r = 0; r < 4; ++r) { p[m][r] = exp2f(p[m][r] - mn); rs += p[m][r]; }
        rs += __shfl_xor(rs, 16);
        rs += __shfl_xor(rs, 32);
        l_i = l_i * al + rs;
        #pragma unroll
        for (int n = 0; n < 4; ++n) o_acc[n] *= al;

        #pragma unroll
        for (int m = 0; m < 4; ++m) {
            uint2 pk;
            pk.x = pk2bf(p[m][0], p[m][1]);
            pk.y = pk2bf(p[m][2], p[m][3]);
            *(uint2*)((char*)Ps + qr * 128 + ((m * 32 + g * 8) ^ swzq)) = pk;
        }

        #pragma unroll
        for (int ks2 = 0; ks2 < 2; ++ks2) {
            const bf16x8 pf = *(const bf16x8*)((char*)Ps + qr * 128 + ((ks2 * 64 + g * 16) ^ swzq));
            #pragma unroll
            for (int n = 0; n < 4; ++n) {
                const int rv = n * 16 + qx;
                const int sl = ks2 * 4 + g;
                const bf16x8 vf = *(const bf16x8*)((char*)Vs + rv * 128 + ((sl ^ (rv & 7)) << 4));
                o_acc[n] = __builtin_amdgcn_mfma_f32_16x16x32_bf16(vf, pf, o_acc[n], 0, 0, 0);
            }
        }
    }

    const float inv = 1.f / l_i;
    #pragma unroll
    for (int n = 0; n < 4; ++n) {
        uint2 ov;
        ov.x = pk2bf(o_acc[n][0] * inv, o_acc[n][1] * inv);
        ov.y = pk2bf(o_acc[n][2] * inv, o_acc[n][3] * inv);
        *(uint2*)((char*)Ps + qr * 128 + ((n * 32 + g * 8) ^ swzq)) = ov;
    }
    const int orow = wv * 16 + (lane >> 2);
    const int swzo = (orow & 7) << 4;
    #pragma unroll
    for (int i = 0; i < 2; ++i) {
        const int cb = ((lane & 3) * 2 + i) * 16;
        const uint4 ov = *(const uint4*)((char*)Ps + orow * 128 + (cb ^ swzo));
        *(uint4*)(O + qkbase + (size_t)(q0 + orow) * 1024 + cb / 2) = ov;
    }
}

// ---------------------------------------------------------------------------
// LayerNorm, bf16 in/out, fp32 stats. One block (256) per row of 1024.
// ---------------------------------------------------------------------------
__global__ __launch_bounds__(256) void ln_bf16_kernel(
        const u16* __restrict__ X, const float* __restrict__ g,
        const float* __restrict__ bta, u16* __restrict__ Y)
{
    __shared__ float red[4];
    const int row = blockIdx.x, tid = threadIdx.x;
    const int wave = tid >> 6, lane = tid & 63;

    const uint2 u = *(const uint2*)(X + (size_t)row * 1024 + tid * 4);
    const float x0 = bflo(u.x), x1 = bfhi(u.x), x2 = bflo(u.y), x3 = bfhi(u.y);

    float s = x0 + x1 + x2 + x3;
    #pragma unroll
    for (int off = 32; off; off >>= 1) s += __shfl_xor(s, off);
    if (lane == 0) red[wave] = s;
    __syncthreads();
    const float mu = (red[0] + red[1] + red[2] + red[3]) * (1.f / 1024.f);
    __syncthreads();

    const float d0 = x0 - mu, d1 = x1 - mu, d2 = x2 - mu, d3 = x3 - mu;
    float s2 = d0 * d0 + d1 * d1 + d2 * d2 + d3 * d3;
    #pragma unroll
    for (int off = 32; off; off >>= 1) s2 += __shfl_xor(s2, off);
    if (lane == 0) red[wave] = s2;
    __syncthreads();
    const float var = (red[0] + red[1] + red[2] + red[3]) * (1.f / 1024.f);
    const float rs = rsqrtf(var + 1e-5f);

    const float4 gg = ((const float4*)g)[tid];
    const float4 bb = ((const float4*)bta)[tid];
    ushort4 o;
    o.x = f2bf(d0 * rs * gg.x + bb.x);
    o.y = f2bf(d1 * rs * gg.y + bb.y);
    o.z = f2bf(d2 * rs * gg.z + bb.z);
    o.w = f2bf(d3 * rs * gg.w + bb.w);
    *(ushort4*)(Y + (size_t)row * 1024 + tid * 4) = o;
}

// fp32 in-place LayerNorm (final output)
__global__ __launch_bounds__(256) void ln_kernel(
        const float* X, const float* __restrict__ g,
        const float* __restrict__ bta, float* Y)
{
    __shared__ float red[4];
    const int row = blockIdx.x;
    const int tid = threadIdx.x;
    const int wave = tid >> 6, lane = tid & 63;

    const float4 v = ((const float4*)(X + (size_t)row * 1024))[tid];

    float s = v.x + v.y + v.z + v.w;
    #pragma unroll
    for (int off = 32; off; off >>= 1) s += __shfl_xor(s, off);
    if (lane == 0) red[wave] = s;
    __syncthreads();
    const float mu = (red[0] + red[1] + red[2] + red[3]) * (1.f / 1024.f);
    __syncthreads();

    const float dx = v.x - mu, dy = v.y - mu, dz = v.z - mu, dw = v.w - mu;
    float s2 = dx * dx + dy * dy + dz * dz + dw * dw;
    #pragma unroll
    for (int off = 32; off; off >>= 1) s2 += __shfl_xor(s2, off);
    if (lane == 0) red[wave] = s2;
    __syncthreads();
    const float var = (red[0] + red[1] + red[2] + red[3]) * (1.f / 1024.f);
    const float rs = rsqrtf(var + 1e-5f);

    const float4 gg = ((const float4*)g)[tid];
    const float4 bb = ((const float4*)bta)[tid];
    float4 o;
    o.x = dx * rs * gg.x + bb.x;
    o.y = dy * rs * gg.y + bb.y;
    o.z = dz * rs * gg.z + bb.z;
    o.w = dw * rs * gg.w + bb.w;
    ((float4*)(Y + (size_t)row * 1024))[tid] = o;
}

// ---------------------------------------------------------------------------
extern "C" void kernel_launch(void* const* d_in, const int* in_sizes, int n_in,
                              void* d_out, int out_size, void* d_ws, size_t ws_size,
                              hipStream_t stream)
{
    const float* tgt    = (const float*)d_in[0];
    const float* mem    = (const float*)d_in[1];
    const float* sa_wq  = (const float*)d_in[3];
    const float* sa_bq  = (const float*)d_in[4];
    const float* sa_wk  = (const float*)d_in[5];
    const float* sa_bk  = (const float*)d_in[6];
    const float* sa_wv  = (const float*)d_in[7];
    const float* sa_bv  = (const float*)d_in[8];
    const float* sa_wo  = (const float*)d_in[9];
    const float* sa_bo  = (const float*)d_in[10];
    const float* ca_wq  = (const float*)d_in[11];
    const float* ca_bq  = (const float*)d_in[12];
    const float* ca_wk  = (const float*)d_in[13];
    const float* ca_bk  = (const float*)d_in[14];
    const float* ca_wv  = (const float*)d_in[15];
    const float* ca_bv  = (const float*)d_in[16];
    const float* ca_wo  = (const float*)d_in[17];
    const float* ca_bo  = (const float*)d_in[18];
    const float* ffn_w1 = (const float*)d_in[19];
    const float* ffn_b1 = (const float*)d_in[20];
    const float* ffn_w2 = (const float*)d_in[21];
    const float* ffn_b2 = (const float*)d_in[22];
    const float* ln1_g  = (const float*)d_in[23];
    const float* ln1_b  = (const float*)d_in[24];
    const float* ln2_g  = (const float*)d_in[25];
    const float* ln2_b  = (const float*)d_in[26];
    const float* ln3_g  = (const float*)d_in[27];
    const float* ln3_b  = (const float*)d_in[28];

    float* out = (float*)d_out;
    u16* wsb = (u16*)d_ws;
    const size_t M1 = 1024 * 1024;

    // weights (bf16, transposed [N][K]): 32 MB.
    u16* Wsq = wsb + 0 * M1;
    u16* Wsk = wsb + 1 * M1;
    u16* Wsv = wsb + 2 * M1;
    u16* Wso = wsb + 3 * M1;
    u16* Wcq = wsb + 4 * M1;
    u16* Wck = wsb + 5 * M1;
    u16* Wcv = wsb + 6 * M1;
    u16* Wco = wsb + 7 * M1;
    u16* Wf1 = wsb + 8 * M1;    // [4096][1024]
    u16* Wf2 = wsb + 12 * M1;   // [1024][4096]

    // activation slots (bf16, 4M elems each): 48 MB
    u16* sl = wsb + 16 * M1;
    u16* s0 = sl + 0 * 4 * M1;
    u16* s1 = sl + 4 * M1;
    u16* s2 = sl + 8 * M1;
    u16* s3 = sl + 12 * M1;
    u16* s4 = sl + 16 * M1;
    u16* s5 = sl + 20 * M1;
    u16* H  = s0;               // FFN hidden [4096][4096] aliases s0..s3 (dead)

    // f32 bias concat buffers (after slots; +20 KB)
    float* biasQKV = (float*)(wsb + 40 * M1);   // [3072]
    float* biasKV  = biasQKV + 3072;            // [2048]

    const dim3 blk(256);
    const dim3 gqkv(24, 32);    // N=3072 fused QKV (BN=128)
    const dim3 gkv(16, 32);     // N=2048 fused KV (BN=128)
    const dim3 g1(16, 32);      // N=1024 GEMM (BN=64)
    const dim3 g4(32, 32);      // N=4096 GEMM FFN1 (BN=128)
    const dim3 ga(64, 16);      // attention
    const dim3 gln(4096);

    // ---- weight/bias prep ----
    TrwB tb;
    tb.w[0] = sa_wq; tb.o[0] = Wsq;
    tb.w[1] = sa_wk; tb.o[1] = Wsk;
    tb.w[2] = sa_wv; tb.o[2] = Wsv;
    tb.w[3] = sa_wo; tb.o[3] = Wso;
    tb.w[4] = ca_wq; tb.o[4] = Wcq;
    tb.w[5] = ca_wk; tb.o[5] = Wck;
    tb.w[6] = ca_wv; tb.o[6] = Wcv;
    tb.w[7] = ca_wo; tb.o[7] = Wco;
    trw8_kernel<<<dim3(16, 16, 8), blk, 0, stream>>>(tb);
    trw_kernel<<<dim3(64, 16), blk, 0, stream>>>(ffn_w1, Wf1, 1024, 4096);
    trw_kernel<<<dim3(16, 64), blk, 0, stream>>>(ffn_w2, Wf2, 4096, 1024);
    bcat_kernel<<<12, blk, 0, stream>>>(sa_bq, sa_bk, sa_bv, biasQKV, 3072);
    bcat_kernel<<<8, blk, 0, stream>>>(ca_bk, ca_bv, ca_bv, biasKV, 2048);
    cvt_kernel<<<2048, blk, 0, stream>>>(tgt, s0, 1024 * 1024);
    cvt_kernel<<<2048, blk, 0, stream>>>(mem, s1, 1024 * 1024);

    // ---- self-attention ----
    // fused QKV: Q->s2, K->s3, Vt->s4
    gemm_mfma<5, 4><<<gqkv, blk, 0, stream>>>(s0, Wsq, biasQKV, nullptr,
                                              s2, s3, s4, 3072, 1024);
    fattn_mfma<1><<<ga, blk, 0, stream>>>(s2, s3, s4, s5);
    gemm_mfma<2, 2><<<g1, blk, 0, stream>>>(s5, Wso, sa_bo, s0, s2, nullptr, nullptr, 1024, 1024);
    ln_bf16_kernel<<<gln, blk, 0, stream>>>(s2, ln1_g, ln1_b, s3);     // x1 = s3

    // ---- cross-attention ----
    gemm_mfma<0, 2><<<g1, blk, 0, stream>>>(s3, Wcq, ca_bq, nullptr, s2, nullptr, nullptr, 1024, 1024);
    // fused KV from memory: K->s4, Vt->s5
    gemm_mfma<6, 4><<<gkv, blk, 0, stream>>>(s1, Wck, biasKV, nullptr,
                                             s4, s5, nullptr, 2048, 1024);
    fattn_mfma<0><<<ga, blk, 0, stream>>>(s2, s4, s5, s0);
    gemm_mfma<2, 2><<<g1, blk, 0, stream>>>(s0, Wco, ca_bo, s3, s2, nullptr, nullptr, 1024, 1024);
    ln_bf16_kernel<<<gln, blk, 0, stream>>>(s2, ln2_g, ln2_b, s4);     // x2 = s4

    // ---- FFN ----
    gemm_mfma<1, 4><<<g4, blk, 0, stream>>>(s4, Wf1, ffn_b1, nullptr, H, nullptr, nullptr, 4096, 1024);
    gemm_mfma<3, 2><<<g1, blk, 0, stream>>>(H, Wf2, ffn_b2, s4, out, nullptr, nullptr, 1024, 4096);
    ln_kernel<<<gln, blk, 0, stream>>>(out, ln3_g, ln3_b, out);
}